// Round 3
// baseline (545.688 us; speedup 1.0000x reference)
//
#include <hip/hip_runtime.h>
#include <hip/hip_bf16.h>

#define H 128
#define ND 4000
#define NPN 19000
#define NCN 1000
#define NLAYERS 2
#define NB 30000
#define E_DP 200000
#define E_PP 300000
#define E_CP 150000

typedef __bf16 bf16_t;
typedef bf16_t bf16x8 __attribute__((ext_vector_type(8)));
typedef float f32x4 __attribute__((ext_vector_type(4)));

static __device__ __forceinline__ float wred_sum(float v) {
#pragma unroll
  for (int off = 32; off; off >>= 1) v += __shfl_xor(v, off);
  return v;
}
static __device__ __forceinline__ float wred_max(float v) {
#pragma unroll
  for (int off = 32; off; off >>= 1) v = fmaxf(v, __shfl_xor(v, off));
  return v;
}
static __device__ __forceinline__ float bflo(unsigned u) { return __uint_as_float(u << 16); }
static __device__ __forceinline__ float bfhi(unsigned u) { return __uint_as_float(u & 0xffff0000u); }
static __device__ __forceinline__ unsigned packbf(float v0, float v1) {
  union { bf16_t b; unsigned short u; } a, b;
  a.b = (bf16_t)v0; b.b = (bf16_t)v1;
  return (unsigned)a.u | ((unsigned)b.u << 16);
}

// async global->LDS, 16B per lane (guide §5: the 874-TF m97 staging path)
#define GLDS16(gp, lp) \
  __builtin_amdgcn_global_load_lds((__attribute__((address_space(1))) void*)(gp), \
                                   (__attribute__((address_space(3))) void*)(lp), 16, 0, 0)

// ================= bf16 MFMA GEMM (global_load_lds staging) =================
// A [M,K] bf16 row-major, Bt [N,K] bf16, C [M,N] bf16.
// BM=BN=128, BK=32, 256 thr (4 waves 2x2), 16x16x32 MFMA, 4x4 frags/wave.
// LDS content [128 rows][64B] holds source chunk (c ^ ((r>>1)&3)) at col c
// -> achieved by pre-swizzling the GLOBAL source chunk, LDS dest stays
// lane-linear (As + t*16) as global_load_lds requires (m104/m173).
__device__ __forceinline__ void mfma_gemm_body(
    const bf16_t* __restrict__ A, const bf16_t* __restrict__ Bt, bf16_t* __restrict__ C,
    int M, int N, int K,
    const float* __restrict__ b1, const float* __restrict__ b2, const float* __restrict__ b3,
    int do_relu, int m0, int n0)
{
  __shared__ char As[128 * 64];
  __shared__ char Bs[128 * 64];
  const int t = threadIdx.x;
  const int lane = t & 63;
  const int wid = t >> 6;
  const int wr = wid >> 1, wc = wid & 1;
  f32x4 acc[4][4];
#pragma unroll
  for (int mi = 0; mi < 4; ++mi)
#pragma unroll
    for (int ni = 0; ni < 4; ++ni) acc[mi][ni] = (f32x4){0.f, 0.f, 0.f, 0.f};

  // staging: thread t -> rows sr / sr+64, source chunk pre-swizzled
  const int sr = t >> 2;
  const int sc = t & 3;
  const int csrc = ((sc ^ ((sr >> 1) & 3)) << 4);  // swz(r) == swz(r+64)
  int ra0 = m0 + sr;      if (ra0 >= M) ra0 = M - 1;
  int ra1 = m0 + 64 + sr; if (ra1 >= M) ra1 = M - 1;
  const char* gA0 = (const char*)A + (size_t)ra0 * K * 2 + csrc;
  const char* gA1 = (const char*)A + (size_t)ra1 * K * 2 + csrc;
  const char* gB0 = (const char*)Bt + (size_t)(n0 + sr) * K * 2 + csrc;
  const char* gB1 = (const char*)Bt + (size_t)(n0 + 64 + sr) * K * 2 + csrc;
  char* lA0 = As + t * 16;          // == row sr, chunk sc (lane-linear)
  char* lA1 = As + 4096 + t * 16;
  char* lB0 = Bs + t * 16;
  char* lB1 = Bs + 4096 + t * 16;

  int aoff[4], boff[4];
#pragma unroll
  for (int mi = 0; mi < 4; ++mi) {
    int r = wr * 64 + mi * 16 + (lane & 15);
    aoff[mi] = r * 64 + ((((lane >> 4)) ^ ((r >> 1) & 3)) << 4);
  }
#pragma unroll
  for (int ni = 0; ni < 4; ++ni) {
    int r = wc * 64 + ni * 16 + (lane & 15);
    boff[ni] = r * 64 + ((((lane >> 4)) ^ ((r >> 1) & 3)) << 4);
  }

  for (int k0 = 0; k0 < K; k0 += 32) {
    const size_t kb = (size_t)k0 * 2;
    __syncthreads();                      // all waves done reading prev tile
    GLDS16(gA0 + kb, lA0);
    GLDS16(gA1 + kb, lA1);
    GLDS16(gB0 + kb, lB0);
    GLDS16(gB1 + kb, lB1);
    __syncthreads();                      // compiler drains vmcnt before barrier
    bf16x8 av[4], bv[4];
#pragma unroll
    for (int mi = 0; mi < 4; ++mi) av[mi] = *(const bf16x8*)(As + aoff[mi]);
#pragma unroll
    for (int ni = 0; ni < 4; ++ni) bv[ni] = *(const bf16x8*)(Bs + boff[ni]);
#pragma unroll
    for (int mi = 0; mi < 4; ++mi)
#pragma unroll
      for (int ni = 0; ni < 4; ++ni)
        acc[mi][ni] = __builtin_amdgcn_mfma_f32_16x16x32_bf16(av[mi], bv[ni], acc[mi][ni], 0, 0, 0);
  }

  // epilogue: C/D layout col=lane&15, row=(lane>>4)*4+reg  [m89]
  const int col0 = lane & 15;
  const int rsub = (lane >> 4) * 4;
#pragma unroll
  for (int mi = 0; mi < 4; ++mi) {
#pragma unroll
    for (int ni = 0; ni < 4; ++ni) {
      int c = n0 + wc * 64 + ni * 16 + col0;
      float bb = b1 ? b1[c] : 0.f;
      if (b2) bb += b2[c];
      if (b3) bb += b3[c];
#pragma unroll
      for (int rg = 0; rg < 4; ++rg) {
        int r = m0 + wr * 64 + mi * 16 + rsub + rg;
        if (r < M) {
          float v = acc[mi][ni][rg] + bb;
          if (do_relu) v = fmaxf(v, 0.f);
          C[(size_t)r * N + c] = (bf16_t)v;
        }
      }
    }
  }
}

__global__ __launch_bounds__(256) void k_gemm_bf(
    const bf16_t* __restrict__ A, const bf16_t* __restrict__ Bt, bf16_t* __restrict__ C,
    int M, int N, int K, const float* __restrict__ bias, int do_relu)
{
  mfma_gemm_body(A, Bt, C, M, N, K, bias, nullptr, nullptr, do_relu, blockIdx.x * 128, blockIdx.y * 128);
}

// 3 dst-side GAT GEMM jobs (protein K=384, drug K=128, cell K=128), N=128, relu
struct GJob { const bf16_t* A; const bf16_t* Bt; bf16_t* C; int M; int K;
              const float *b1, *b2, *b3; };
struct Gemm3 { GJob j[3]; };
__global__ __launch_bounds__(256) void k_gemm_g3(Gemm3 g) {
  const GJob& jb = g.j[blockIdx.y];
  int m0 = blockIdx.x * 128;
  if (m0 >= jb.M) return;
  mfma_gemm_body(jb.A, jb.Bt, jb.C, jb.M, H, jb.K, jb.b1, jb.b2, jb.b3, 1, m0, 0);
}

// ================= conversions =================
__global__ __launch_bounds__(256) void k_conv_emb(
    const float* __restrict__ xd, const float* __restrict__ xp, const float* __restrict__ xc,
    bf16_t* __restrict__ od, bf16_t* __restrict__ op, bf16_t* __restrict__ oc)
{
  int i = blockIdx.x * 256 + threadIdx.x;
  const int SD = ND * H, SP = NPN * H, SC = NCN * H;
  if (i < SD) od[i] = (bf16_t)xd[i];
  else if (i < SD + SP) op[i - SD] = (bf16_t)xp[i - SD];
  else if (i < SD + SP + SC) oc[i - SD - SP] = (bf16_t)xc[i - SD - SP];
}

// transpose-convert with K-offset into a wider Bt: dst[n*Kfull+koff+k] = bf16(src[k*N+n])
struct TC { const float* src[12]; bf16_t* dst[12]; int Ksub[12]; int N[12]; int Kfull[12]; int koff[12]; };
__global__ __launch_bounds__(256) void k_tconv(TC a) {
  int m = blockIdx.y;
  int i = blockIdx.x * 256 + threadIdx.x;
  int Ks = a.Ksub[m], N = a.N[m];
  if (i >= Ks * N) return;
  int n = i / Ks, k = i - n * Ks;
  a.dst[m][(size_t)n * a.Kfull[m] + a.koff[m] + k] = (bf16_t)a.src[m][(size_t)k * N + n];
}

// ---------------- wv = W @ a (10 matvecs/layer: 5 src + 5 dst) ----------------
struct Wd10 { const float* W[10]; const float* a[10]; float* o[10]; };
__global__ __launch_bounds__(128) void k_wd10(Wd10 g) {
  int m = blockIdx.x;
  int k = threadIdx.x;
  const float* Wp = g.W[m];
  const float* av = g.a[m];
  float s = 0.f;
#pragma unroll 4
  for (int j = 0; j < H; ++j) s = fmaf(Wp[k * H + j], av[j], s);
  g.o[m][k] = s;
}

// ---------------- row dot (bf16 X, fp32 v): node scores ----------------
struct Rd10 { const bf16_t* X[10]; const float* v[10]; float* out[10]; int M[10]; };
__global__ __launch_bounds__(256) void k_rowdot10(Rd10 a) {
  int seg = blockIdx.y;
  int row = blockIdx.x * 4 + (threadIdx.x >> 6);
  if (row >= a.M[seg]) return;
  int lane = threadIdx.x & 63;
  unsigned u = *(const unsigned*)(a.X[seg] + (size_t)row * H + lane * 2);
  const float* v = a.v[seg];
  float s = bflo(u) * v[2 * lane] + bfhi(u) * v[2 * lane + 1];
  s = wred_sum(s);
  if (!lane) a.out[seg][row] = s;
}

// ---------------- CSR build ----------------
struct CsrArgs {
  const int* src[5]; const int* dst[5];
  int E[5]; int loopbase[5]; int n[5];
  int* cnt[5]; int* cur[5]; int* starts[5]; int* csr[5];
};
__global__ __launch_bounds__(256) void k_count5(CsrArgs a) {
  int rel = blockIdx.y;
  int e = blockIdx.x * 256 + threadIdx.x;
  if (e >= a.E[rel]) return;
  int d = (e >= a.loopbase[rel]) ? (e - a.loopbase[rel]) : a.dst[rel][e];
  atomicAdd(&a.cnt[rel][d], 1);
}
__global__ __launch_bounds__(256) void k_scan5(CsrArgs a) {
  int rel = blockIdx.x;
  int n = a.n[rel];
  const int* cnt = a.cnt[rel];
  int* st = a.starts[rel];
  int* cu = a.cur[rel];
  __shared__ int part[256];
  int t = threadIdx.x;
  int stripe = (n + 255) / 256;
  int lo = t * stripe;
  int hi = lo + stripe; if (hi > n) hi = n;
  int s = 0;
  for (int i = lo; i < hi; ++i) s += cnt[i];
  part[t] = s;
  __syncthreads();
  if (t == 0) {
    int run = 0;
    for (int i = 0; i < 256; ++i) { int v = part[i]; part[i] = run; run += v; }
  }
  __syncthreads();
  int run = part[t];
  for (int i = lo; i < hi; ++i) { st[i] = run; cu[i] = run; run += cnt[i]; }
  if (lo < n && hi == n) st[n] = run;
}
__global__ __launch_bounds__(256) void k_fill5(CsrArgs a) {
  int rel = blockIdx.y;
  int e = blockIdx.x * 256 + threadIdx.x;
  if (e >= a.E[rel]) return;
  int d, s;
  if (e >= a.loopbase[rel]) { d = e - a.loopbase[rel]; s = d; }
  else { d = a.dst[rel][e]; s = a.src[rel][e]; }
  int pos = atomicAdd(&a.cur[rel][d], 1);
  a.csr[rel][pos] = s;
}

// ---------------- GAT aggregate on RAW x (aggregate-then-transform) ----------------
// y[rel][d] = sum_e softmax(lrelu(ss[src]+sd[d])) * x_src[src]
// One wave per (dst,rel). Pass1: max. Pass2: accumulate p*x and p (denom),
// normalize at end. 16 lanes/edge (16B chunk each), 4 edge-groups, unroll 4
// -> 16 edges in flight per wave.
struct Agg5 {
  const int* csr[5]; const int* starts[5];
  const float* ss[5]; const float* sd[5];
  const bf16_t* xs[5];
  bf16_t* y[5]; int ystride[5]; int ycoff[5]; int ndst[5];
};
__global__ __launch_bounds__(256) void k_agg5(Agg5 a) {
  int rel = blockIdx.y;
  int d = blockIdx.x * 4 + (threadIdx.x >> 6);
  if (d >= a.ndst[rel]) return;
  int lane = threadIdx.x & 63;
  int g = lane >> 4, j16 = lane & 15;
  bf16_t* yrow = a.y[rel] + (size_t)d * a.ystride[rel] + a.ycoff[rel];
  int s0 = a.starts[rel][d];
  int deg = a.starts[rel][d + 1] - s0;
  if (!deg) {
    if (g == 0) *(uint4*)(yrow + j16 * 8) = make_uint4(0u, 0u, 0u, 0u);
    return;
  }
  const int* cs = a.csr[rel] + s0;
  const float* ssp = a.ss[rel];
  const bf16_t* xsp = a.xs[rel];
  float sdv = a.sd[rel][d];
  // pass 1: max (lane-strided)
  float m = -3.0e38f;
  for (int i = lane; i < deg; i += 64) {
    float e = ssp[cs[i]] + sdv; e = e > 0.f ? e : 0.2f * e;
    m = fmaxf(m, e);
  }
  m = wred_max(m);
  // pass 2: accumulate p*x + p
  float acc[8] = {0.f, 0.f, 0.f, 0.f, 0.f, 0.f, 0.f, 0.f};
  float ps = 0.f;
  for (int b = 0; b < deg; b += 16) {
#pragma unroll
    for (int u = 0; u < 4; ++u) {
      int i = b + u * 4 + g;
      float p = 0.f;
      uint4 U = make_uint4(0u, 0u, 0u, 0u);
      if (i < deg) {
        int s = cs[i];
        float e = ssp[s] + sdv; e = e > 0.f ? e : 0.2f * e;
        p = __expf(e - m);
        U = *(const uint4*)(xsp + (size_t)s * H + j16 * 8);
      }
      ps += p;
      acc[0] = fmaf(p, bflo(U.x), acc[0]); acc[1] = fmaf(p, bfhi(U.x), acc[1]);
      acc[2] = fmaf(p, bflo(U.y), acc[2]); acc[3] = fmaf(p, bfhi(U.y), acc[3]);
      acc[4] = fmaf(p, bflo(U.z), acc[4]); acc[5] = fmaf(p, bfhi(U.z), acc[5]);
      acc[6] = fmaf(p, bflo(U.w), acc[6]); acc[7] = fmaf(p, bfhi(U.w), acc[7]);
    }
  }
#pragma unroll
  for (int e = 0; e < 8; ++e) {
    acc[e] += __shfl_xor(acc[e], 16);
    acc[e] += __shfl_xor(acc[e], 32);
  }
  ps += __shfl_xor(ps, 16);
  ps += __shfl_xor(ps, 32);
  if (g == 0) {
    float inv = 1.f / ps;
    uint4 O;
    O.x = packbf(acc[0] * inv, acc[1] * inv);
    O.y = packbf(acc[2] * inv, acc[3] * inv);
    O.z = packbf(acc[4] * inv, acc[5] * inv);
    O.w = packbf(acc[6] * inv, acc[7] * inv);
    *(uint4*)(yrow + j16 * 8) = O;
  }
}

// ---------------- readout ----------------
__global__ __launch_bounds__(256) void k_invnorm(
    const bf16_t* __restrict__ xd, const bf16_t* __restrict__ xc,
    float* __restrict__ invd, float* __restrict__ invc)
{
  int row = blockIdx.x * 4 + (threadIdx.x >> 6);
  if (row >= ND + NCN) return;
  int lane = threadIdx.x & 63;
  const bf16_t* x = (row < ND) ? xd + (size_t)row * H : xc + (size_t)(row - ND) * H;
  unsigned u = *(const unsigned*)(x + lane * 2);
  float av = bflo(u), bv = bfhi(u);
  float s = wred_sum(av * av + bv * bv);
  if (!lane) {
    float nv = fmaxf(sqrtf(s), 1e-12f);
    if (row < ND) invd[row] = 1.f / nv; else invc[row - ND] = 1.f / nv;
  }
}
__global__ __launch_bounds__(256) void k_make_hid(
    const bf16_t* __restrict__ xd, const bf16_t* __restrict__ xc,
    const float* __restrict__ invd, const float* __restrict__ invc,
    const int* __restrict__ d1, const int* __restrict__ d2, const int* __restrict__ ce,
    bf16_t* __restrict__ hid, int c0, int cn)
{
  int gid = blockIdx.x * 256 + threadIdx.x;   // one 16B chunk (8 feats)
  if (gid >= cn * 48) return;
  int i = gid / 48, c16 = gid - i * 48;
  int gi = c0 + i;
  int sel = c16 >> 4;
  int jb = (c16 & 15) * 8;
  int rrow; const bf16_t* xs; float sc;
  if (sel == 0)      { rrow = d1[gi]; xs = xd; sc = invd[rrow]; }
  else if (sel == 1) { rrow = d2[gi]; xs = xd; sc = invd[rrow]; }
  else               { rrow = ce[gi]; xs = xc; sc = invc[rrow]; }
  uint4 U = *(const uint4*)(xs + (size_t)rrow * H + jb);
  uint4 O;
  O.x = packbf(bflo(U.x) * sc, bfhi(U.x) * sc);
  O.y = packbf(bflo(U.y) * sc, bfhi(U.y) * sc);
  O.z = packbf(bflo(U.z) * sc, bfhi(U.z) * sc);
  O.w = packbf(bflo(U.w) * sc, bfhi(U.w) * sc);
  *(uint4*)(hid + (size_t)i * 384 + c16 * 8) = O;
}
__global__ __launch_bounds__(256) void k_mlp3(
    const bf16_t* __restrict__ h2, const float* __restrict__ W3, const float* __restrict__ b3,
    float* __restrict__ out, int cn, int c0)
{
  int row = blockIdx.x * 4 + (threadIdx.x >> 6);
  if (row >= cn) return;
  int lane = threadIdx.x & 63;
  uint2 U = *(const uint2*)(h2 + (size_t)row * 256 + lane * 4);
  float v0 = bflo(U.x), v1 = bfhi(U.x), v2 = bflo(U.y), v3 = bfhi(U.y);
  const float* w = W3 + 8 * lane;
  float4 wa = *(const float4*)w;
  float4 wb = *(const float4*)(w + 4);
  float o0 = v0 * wa.x + v1 * wa.z + v2 * wb.x + v3 * wb.z;
  float o1 = v0 * wa.y + v1 * wa.w + v2 * wb.y + v3 * wb.w;
  o0 = wred_sum(o0);
  o1 = wred_sum(o1);
  if (!lane) {
    out[(size_t)(c0 + row) * 2]     = o0 + b3[0];
    out[(size_t)(c0 + row) * 2 + 1] = o1 + b3[1];
  }
}

// ================= host =================
extern "C" void kernel_launch(void* const* d_in, const int* in_sizes, int n_in,
                              void* d_out, int out_size, void* d_ws, size_t ws_size,
                              hipStream_t stream)
{
  (void)in_sizes; (void)n_in; (void)out_size;
  const float* drug_emb    = (const float*)d_in[0];
  const float* protein_emb = (const float*)d_in[1];
  const float* cell_emb    = (const float*)d_in[2];
  // internal rel order: 0=dp, 1=pp, 2=cp, 3=rdp, 4=rcp
  const int base_idx[5] = {3, 11, 15, 7, 19};
  const float *W_[5], *as_[5], *ad_[5], *b_[5];
  for (int r = 0; r < 5; ++r) {
    W_[r]  = (const float*)d_in[base_idx[r]];
    as_[r] = (const float*)d_in[base_idx[r] + 1];
    ad_[r] = (const float*)d_in[base_idx[r] + 2];
    b_[r]  = (const float*)d_in[base_idx[r] + 3];
  }
  const float* W1 = (const float*)d_in[23]; const float* b1 = (const float*)d_in[24];
  const float* W2 = (const float*)d_in[25]; const float* b2 = (const float*)d_in[26];
  const float* W3 = (const float*)d_in[27]; const float* b3 = (const float*)d_in[28];
  const int* src_dp = (const int*)d_in[29]; const int* dst_dp = (const int*)d_in[30];
  const int* src_pp = (const int*)d_in[31]; const int* dst_pp = (const int*)d_in[32];
  const int* src_cp = (const int*)d_in[33]; const int* dst_cp = (const int*)d_in[34];
  const int* drug1  = (const int*)d_in[35]; const int* drug2  = (const int*)d_in[36];
  const int* cellb  = (const int*)d_in[37];
  float* out = (float*)d_out;

  char* wsb = (char*)d_ws;
  size_t off = 0;
  auto alloc = [&](size_t bytes) -> void* {
    void* p = wsb + off;
    off += (bytes + 255) & ~(size_t)255;
    return p;
  };
  bf16_t* xdb[2] = {(bf16_t*)alloc((size_t)ND * H * 2),  (bf16_t*)alloc((size_t)ND * H * 2)};
  bf16_t* xpb[2] = {(bf16_t*)alloc((size_t)NPN * H * 2), (bf16_t*)alloc((size_t)NPN * H * 2)};
  bf16_t* xcb[2] = {(bf16_t*)alloc((size_t)NCN * H * 2), (bf16_t*)alloc((size_t)NCN * H * 2)};
  const int Msrc[5] = {ND, NPN, NCN, NPN, NPN};
  const int Mdst[5] = {NPN, NPN, NPN, ND, NCN};
  const int Erel[5] = {E_DP, E_PP + NPN, E_CP, E_DP, E_CP};
  bf16_t* yp = (bf16_t*)alloc((size_t)NPN * 384 * 2);   // [19000][3*128], col slice per rel
  bf16_t* yd = (bf16_t*)alloc((size_t)ND * H * 2);
  bf16_t* yc = (bf16_t*)alloc((size_t)NCN * H * 2);
  bf16_t* Wtp = (bf16_t*)alloc((size_t)NLAYERS * 128 * 384 * 2);  // [l][N=128][K=384]
  bf16_t* Wtd = (bf16_t*)alloc((size_t)NLAYERS * 128 * 128 * 2);
  bf16_t* Wtc = (bf16_t*)alloc((size_t)NLAYERS * 128 * 128 * 2);
  bf16_t* W1t = (bf16_t*)alloc((size_t)768 * 384 * 2);
  bf16_t* W2t = (bf16_t*)alloc((size_t)256 * 768 * 2);
  float* wvb = (float*)alloc(10 * H * 4);
  float* ssb[5]; for (int r = 0; r < 5; ++r) ssb[r] = (float*)alloc((size_t)Msrc[r] * 4);
  float* sdb[5]; for (int r = 0; r < 5; ++r) sdb[r] = (float*)alloc((size_t)Mdst[r] * 4);
  int* cnt_all = (int*)alloc(62000 * 4);
  int* cur_all = (int*)alloc(62000 * 4);
  int* st_all  = (int*)alloc((62000 + 5) * 4);
  int *cntb[5], *curb[5], *stb[5];
  { int o = 0, o2 = 0;
    for (int r = 0; r < 5; ++r) {
      cntb[r] = cnt_all + o; curb[r] = cur_all + o; stb[r] = st_all + o2;
      o += Mdst[r]; o2 += Mdst[r] + 1;
    } }
  int* csrb[5]; for (int r = 0; r < 5; ++r) csrb[r] = (int*)alloc((size_t)Erel[r] * 4);
  float* invd = (float*)alloc(ND * 4);
  float* invc = (float*)alloc(NCN * 4);
  size_t fixed_end = off;
  size_t avail = ws_size > fixed_end ? ws_size - fixed_end : 0;
  long long cmax = (long long)avail / 2816;
  int CH = cmax > NB ? NB : (int)cmax;
  CH &= ~255;
  if (CH < 256) CH = 256;
  bf16_t* hid = (bf16_t*)alloc((size_t)CH * 384 * 2);
  bf16_t* h1  = (bf16_t*)alloc((size_t)CH * 768 * 2);
  bf16_t* h2  = (bf16_t*)alloc((size_t)CH * 256 * 2);

  // conversions
  k_conv_emb<<<(ND * H + NPN * H + NCN * H + 255) / 256, 256, 0, stream>>>(
      drug_emb, protein_emb, cell_emb, xdb[0], xpb[0], xcb[0]);
  TC tc;
  for (int l = 0; l < 2; ++l) {
    for (int r = 0; r < 3; ++r) {   // protein rels -> Wtp with k-offset r*128
      int m = l * 3 + r;
      tc.src[m] = W_[r] + (size_t)l * H * H;
      tc.dst[m] = Wtp + (size_t)l * 128 * 384;
      tc.Ksub[m] = 128; tc.N[m] = 128; tc.Kfull[m] = 384; tc.koff[m] = r * 128;
    }
    tc.src[6 + l] = W_[3] + (size_t)l * H * H; tc.dst[6 + l] = Wtd + (size_t)l * 128 * 128;
    tc.Ksub[6 + l] = 128; tc.N[6 + l] = 128; tc.Kfull[6 + l] = 128; tc.koff[6 + l] = 0;
    tc.src[8 + l] = W_[4] + (size_t)l * H * H; tc.dst[8 + l] = Wtc + (size_t)l * 128 * 128;
    tc.Ksub[8 + l] = 128; tc.N[8 + l] = 128; tc.Kfull[8 + l] = 128; tc.koff[8 + l] = 0;
  }
  tc.src[10] = W1; tc.dst[10] = W1t; tc.Ksub[10] = 384; tc.N[10] = 768; tc.Kfull[10] = 384; tc.koff[10] = 0;
  tc.src[11] = W2; tc.dst[11] = W2t; tc.Ksub[11] = 768; tc.N[11] = 256; tc.Kfull[11] = 768; tc.koff[11] = 0;
  k_tconv<<<dim3((768 * 384 + 255) / 256, 12), 256, 0, stream>>>(tc);

  // CSR build
  hipMemsetAsync(cnt_all, 0, 62000 * 4, stream);
  CsrArgs ca;
  const int* srcA[5] = {src_dp, src_pp, src_cp, dst_dp, dst_cp};
  const int* dstA[5] = {dst_dp, dst_pp, dst_cp, src_dp, src_cp};
  const int loopb[5] = {0x7fffffff, E_PP, 0x7fffffff, 0x7fffffff, 0x7fffffff};
  for (int r = 0; r < 5; ++r) {
    ca.src[r] = srcA[r]; ca.dst[r] = dstA[r]; ca.E[r] = Erel[r];
    ca.loopbase[r] = loopb[r]; ca.n[r] = Mdst[r];
    ca.cnt[r] = cntb[r]; ca.cur[r] = curb[r]; ca.starts[r] = stb[r]; ca.csr[r] = csrb[r];
  }
  dim3 egrid((E_PP + NPN + 255) / 256, 5);
  k_count5<<<egrid, 256, 0, stream>>>(ca);
  k_scan5<<<5, 256, 0, stream>>>(ca);
  k_fill5<<<egrid, 256, 0, stream>>>(ca);

  int cur = 0;
  for (int l = 0; l < NLAYERS; ++l) {
    int nxt = 1 - cur;
    const bf16_t* xsrc[5] = {xdb[cur], xpb[cur], xcb[cur], xpb[cur], xpb[cur]};
    const bf16_t* xdst[5] = {xpb[cur], xpb[cur], xpb[cur], xdb[cur], xcb[cur]};
    // node scores: ss = x_src . (W@a_src), sd = x_dst . (W@a_dst)
    Wd10 wg;
    for (int r = 0; r < 5; ++r) {
      wg.W[r] = W_[r] + (size_t)l * H * H; wg.a[r] = as_[r] + l * H; wg.o[r] = wvb + r * H;
      wg.W[5 + r] = W_[r] + (size_t)l * H * H; wg.a[5 + r] = ad_[r] + l * H; wg.o[5 + r] = wvb + (5 + r) * H;
    }
    k_wd10<<<10, 128, 0, stream>>>(wg);
    Rd10 ra;
    for (int r = 0; r < 5; ++r) {
      ra.X[r] = xsrc[r]; ra.v[r] = wvb + r * H; ra.out[r] = ssb[r]; ra.M[r] = Msrc[r];
      ra.X[5 + r] = xdst[r]; ra.v[5 + r] = wvb + (5 + r) * H; ra.out[5 + r] = sdb[r]; ra.M[5 + r] = Mdst[r];
    }
    k_rowdot10<<<dim3((NPN + 3) / 4, 10), 256, 0, stream>>>(ra);
    // aggregate raw x
    Agg5 aa;
    bf16_t* yptr[5] = {yp, yp, yp, yd, yc};
    const int ystr[5] = {384, 384, 384, 128, 128};
    const int ycof[5] = {0, 128, 256, 0, 0};
    for (int r = 0; r < 5; ++r) {
      aa.csr[r] = csrb[r]; aa.starts[r] = stb[r]; aa.ss[r] = ssb[r]; aa.sd[r] = sdb[r];
      aa.xs[r] = xsrc[r]; aa.y[r] = yptr[r]; aa.ystride[r] = ystr[r]; aa.ycoff[r] = ycof[r];
      aa.ndst[r] = Mdst[r];
    }
    k_agg5<<<dim3((NPN + 3) / 4, 5), 256, 0, stream>>>(aa);
    // dst-side transform: x_next = relu(y @ W + bias)
    Gemm3 g3;
    g3.j[0] = {yp, Wtp + (size_t)l * 128 * 384, xpb[nxt], NPN, 384,
               b_[0] + l * H, b_[1] + l * H, b_[2] + l * H};
    g3.j[1] = {yd, Wtd + (size_t)l * 128 * 128, xdb[nxt], ND, 128,
               b_[3] + l * H, nullptr, nullptr};
    g3.j[2] = {yc, Wtc + (size_t)l * 128 * 128, xcb[nxt], NCN, 128,
               b_[4] + l * H, nullptr, nullptr};
    k_gemm_g3<<<dim3((NPN + 127) / 128, 3), 256, 0, stream>>>(g3);
    cur = nxt;
  }

  k_invnorm<<<(ND + NCN + 3) / 4, 256, 0, stream>>>(xdb[cur], xcb[cur], invd, invc);
  for (int c0 = 0; c0 < NB; c0 += CH) {
    int cn = (NB - c0 < CH) ? (NB - c0) : CH;
    k_make_hid<<<((size_t)cn * 48 + 255) / 256, 256, 0, stream>>>(
        xdb[cur], xcb[cur], invd, invc, drug1, drug2, cellb, hid, c0, cn);
    k_gemm_bf<<<dim3((cn + 127) / 128, 6), 256, 0, stream>>>(hid, W1t, h1, cn, 768, 384, b1, 1);
    k_gemm_bf<<<dim3((cn + 127) / 128, 2), 256, 0, stream>>>(h1, W2t, h2, cn, 256, 768, b2, 1);
    k_mlp3<<<(cn + 3) / 4, 256, 0, stream>>>(h2, W3, b3, out, cn, c0);
  }
}

// Round 4
// 537.980 us; speedup vs baseline: 1.0143x; 1.0143x over previous
//
#include <hip/hip_runtime.h>
#include <hip/hip_bf16.h>

#define H 128
#define ND 4000
#define NPN 19000
#define NCN 1000
#define NLAYERS 2
#define NB 30000
#define E_DP 200000
#define E_PP 300000
#define E_CP 150000

typedef __bf16 bf16_t;
typedef bf16_t bf16x8 __attribute__((ext_vector_type(8)));
typedef float f32x4 __attribute__((ext_vector_type(4)));

static __device__ __forceinline__ float wred_sum(float v) {
#pragma unroll
  for (int off = 32; off; off >>= 1) v += __shfl_xor(v, off);
  return v;
}
static __device__ __forceinline__ float wred_max(float v) {
#pragma unroll
  for (int off = 32; off; off >>= 1) v = fmaxf(v, __shfl_xor(v, off));
  return v;
}
static __device__ __forceinline__ float bflo(unsigned u) { return __uint_as_float(u << 16); }
static __device__ __forceinline__ float bfhi(unsigned u) { return __uint_as_float(u & 0xffff0000u); }
static __device__ __forceinline__ unsigned packbf(float v0, float v1) {
  union { bf16_t b; unsigned short u; } a, b;
  a.b = (bf16_t)v0; b.b = (bf16_t)v1;
  return (unsigned)a.u | ((unsigned)b.u << 16);
}

// async global->LDS, 16B per lane
#define GLDS16(gp, lp) \
  __builtin_amdgcn_global_load_lds((__attribute__((address_space(1))) void*)(gp), \
                                   (__attribute__((address_space(3))) void*)(lp), 16, 0, 0)

// ================= bf16 MFMA GEMM (global_load_lds staging) =================
__device__ __forceinline__ void mfma_gemm_body(
    const bf16_t* __restrict__ A, const bf16_t* __restrict__ Bt, bf16_t* __restrict__ C,
    int M, int N, int K,
    const float* __restrict__ b1, const float* __restrict__ b2, const float* __restrict__ b3,
    int do_relu, int m0, int n0)
{
  __shared__ char As[128 * 64];
  __shared__ char Bs[128 * 64];
  const int t = threadIdx.x;
  const int lane = t & 63;
  const int wid = t >> 6;
  const int wr = wid >> 1, wc = wid & 1;
  f32x4 acc[4][4];
#pragma unroll
  for (int mi = 0; mi < 4; ++mi)
#pragma unroll
    for (int ni = 0; ni < 4; ++ni) acc[mi][ni] = (f32x4){0.f, 0.f, 0.f, 0.f};

  const int sr = t >> 2;
  const int sc = t & 3;
  const int csrc = ((sc ^ ((sr >> 1) & 3)) << 4);
  int ra0 = m0 + sr;      if (ra0 >= M) ra0 = M - 1;
  int ra1 = m0 + 64 + sr; if (ra1 >= M) ra1 = M - 1;
  const char* gA0 = (const char*)A + (size_t)ra0 * K * 2 + csrc;
  const char* gA1 = (const char*)A + (size_t)ra1 * K * 2 + csrc;
  const char* gB0 = (const char*)Bt + (size_t)(n0 + sr) * K * 2 + csrc;
  const char* gB1 = (const char*)Bt + (size_t)(n0 + 64 + sr) * K * 2 + csrc;
  char* lA0 = As + t * 16;
  char* lA1 = As + 4096 + t * 16;
  char* lB0 = Bs + t * 16;
  char* lB1 = Bs + 4096 + t * 16;

  int aoff[4], boff[4];
#pragma unroll
  for (int mi = 0; mi < 4; ++mi) {
    int r = wr * 64 + mi * 16 + (lane & 15);
    aoff[mi] = r * 64 + ((((lane >> 4)) ^ ((r >> 1) & 3)) << 4);
  }
#pragma unroll
  for (int ni = 0; ni < 4; ++ni) {
    int r = wc * 64 + ni * 16 + (lane & 15);
    boff[ni] = r * 64 + ((((lane >> 4)) ^ ((r >> 1) & 3)) << 4);
  }

  for (int k0 = 0; k0 < K; k0 += 32) {
    const size_t kb = (size_t)k0 * 2;
    __syncthreads();
    GLDS16(gA0 + kb, lA0);
    GLDS16(gA1 + kb, lA1);
    GLDS16(gB0 + kb, lB0);
    GLDS16(gB1 + kb, lB1);
    __syncthreads();
    bf16x8 av[4], bv[4];
#pragma unroll
    for (int mi = 0; mi < 4; ++mi) av[mi] = *(const bf16x8*)(As + aoff[mi]);
#pragma unroll
    for (int ni = 0; ni < 4; ++ni) bv[ni] = *(const bf16x8*)(Bs + boff[ni]);
#pragma unroll
    for (int mi = 0; mi < 4; ++mi)
#pragma unroll
      for (int ni = 0; ni < 4; ++ni)
        acc[mi][ni] = __builtin_amdgcn_mfma_f32_16x16x32_bf16(av[mi], bv[ni], acc[mi][ni], 0, 0, 0);
  }

  const int col0 = lane & 15;
  const int rsub = (lane >> 4) * 4;
#pragma unroll
  for (int mi = 0; mi < 4; ++mi) {
#pragma unroll
    for (int ni = 0; ni < 4; ++ni) {
      int c = n0 + wc * 64 + ni * 16 + col0;
      float bb = b1 ? b1[c] : 0.f;
      if (b2) bb += b2[c];
      if (b3) bb += b3[c];
#pragma unroll
      for (int rg = 0; rg < 4; ++rg) {
        int r = m0 + wr * 64 + mi * 16 + rsub + rg;
        if (r < M) {
          float v = acc[mi][ni][rg] + bb;
          if (do_relu) v = fmaxf(v, 0.f);
          C[(size_t)r * N + c] = (bf16_t)v;
        }
      }
    }
  }
}

__global__ __launch_bounds__(256) void k_gemm_bf(
    const bf16_t* __restrict__ A, const bf16_t* __restrict__ Bt, bf16_t* __restrict__ C,
    int M, int N, int K, const float* __restrict__ bias, int do_relu)
{
  mfma_gemm_body(A, Bt, C, M, N, K, bias, nullptr, nullptr, do_relu, blockIdx.x * 128, blockIdx.y * 128);
}

struct GJob { const bf16_t* A; const bf16_t* Bt; bf16_t* C; int M; int K;
              const float *b1, *b2, *b3; };
struct Gemm3 { GJob j[3]; };
__global__ __launch_bounds__(256) void k_gemm_g3(Gemm3 g) {
  const GJob& jb = g.j[blockIdx.y];
  int m0 = blockIdx.x * 128;
  if (m0 >= jb.M) return;
  mfma_gemm_body(jb.A, jb.Bt, jb.C, jb.M, H, jb.K, jb.b1, jb.b2, jb.b3, 1, m0, 0);
}

// ================= conversions =================
__global__ __launch_bounds__(256) void k_conv_emb(
    const float* __restrict__ xd, const float* __restrict__ xp, const float* __restrict__ xc,
    bf16_t* __restrict__ od, bf16_t* __restrict__ op, bf16_t* __restrict__ oc)
{
  int i = blockIdx.x * 256 + threadIdx.x;
  const int SD = ND * H, SP = NPN * H, SC = NCN * H;
  if (i < SD) od[i] = (bf16_t)xd[i];
  else if (i < SD + SP) op[i - SD] = (bf16_t)xp[i - SD];
  else if (i < SD + SP + SC) oc[i - SD - SP] = (bf16_t)xc[i - SD - SP];
}

// LDS-tiled transpose-convert: dst[n*Kfull+koff+k] = bf16(src[k*N+n])
struct TC { const float* src[12]; bf16_t* dst[12]; int Ksub[12]; int N[12]; int Kfull[12]; int koff[12]; };
__global__ __launch_bounds__(256) void k_tconv2(TC a) {
  int m = blockIdx.z;
  int Ks = a.Ksub[m], N = a.N[m];
  int tx = blockIdx.x * 32;   // n dim
  int ty = blockIdx.y * 32;   // k dim
  if (tx >= N || ty >= Ks) return;
  __shared__ float tile[32][33];
  int c = threadIdx.x & 31, rr = threadIdx.x >> 5;
  const float* src = a.src[m];
#pragma unroll
  for (int kk = rr; kk < 32; kk += 8)
    if (ty + kk < Ks && tx + c < N) tile[kk][c] = src[(size_t)(ty + kk) * N + tx + c];
  __syncthreads();
  bf16_t* dst = a.dst[m];
  int Kf = a.Kfull[m], ko = a.koff[m];
#pragma unroll
  for (int nn = rr; nn < 32; nn += 8)
    if (tx + nn < N && ty + c < Ks)
      dst[(size_t)(tx + nn) * Kf + ko + ty + c] = (bf16_t)tile[c][nn];
}

// ---------------- wv = W @ a (10 matvecs/layer: 5 src + 5 dst) ----------------
struct Wd10 { const float* W[10]; const float* a[10]; float* o[10]; };
__global__ __launch_bounds__(128) void k_wd10(Wd10 g) {
  int m = blockIdx.x;
  int k = threadIdx.x;
  const float* Wp = g.W[m];
  const float* av = g.a[m];
  float s = 0.f;
#pragma unroll 4
  for (int j = 0; j < H; ++j) s = fmaf(Wp[k * H + j], av[j], s);
  g.o[m][k] = s;
}

// ---------------- fused node scores: each row computes all its dots ----------------
// wv layout: [0..4]=W@a_src per rel, [5..9]=W@a_dst per rel
struct Sc { const bf16_t* xd; const bf16_t* xp; const bf16_t* xc; const float* wv;
            float* ss[5]; float* sd[5]; };
__global__ __launch_bounds__(256) void k_scores(Sc S) {
  int row = blockIdx.x * 4 + (threadIdx.x >> 6);
  if (row >= ND + NPN + NCN) return;
  int lane = threadIdx.x & 63;
  const bf16_t* x;
  int idx, cls;
  if (row < ND) { x = S.xd; idx = row; cls = 0; }
  else if (row < ND + NPN) { x = S.xp; idx = row - ND; cls = 1; }
  else { x = S.xc; idx = row - ND - NPN; cls = 2; }
  unsigned u = *(const unsigned*)(x + (size_t)idx * H + lane * 2);
  float x0 = bflo(u), x1 = bfhi(u);
  const float* wv = S.wv;
#define DOT(vi, outp) { const float* v = wv + (vi) * H; \
    float s = x0 * v[2 * lane] + x1 * v[2 * lane + 1]; s = wred_sum(s); \
    if (!lane) (outp)[idx] = s; }
  if (cls == 0) {
    DOT(0, S.ss[0]); DOT(8, S.sd[3]);
  } else if (cls == 1) {
    DOT(1, S.ss[1]); DOT(3, S.ss[3]); DOT(4, S.ss[4]);
    DOT(5, S.sd[0]); DOT(6, S.sd[1]); DOT(7, S.sd[2]);
  } else {
    DOT(2, S.ss[2]); DOT(9, S.sd[4]);
  }
#undef DOT
}

// ---------------- graph build: LDS-bucketed partition + local CSR fill ----------------
// P1: stream edges; histogram cnt; partition packed (dst<<16|src) into dst-range
// buckets with LDS buffering, flushed in >=256B contiguous chunks.
struct Part {
  const int* src[5]; const int* dst[5];
  int E[5]; int loopbase[5]; int shift[5]; int nb[5]; int cap[5]; int sb[5]; int cntoff[5];
  unsigned* stage; int* gcur; int* cnt;
};
__global__ __launch_bounds__(256) void k_part(Part P) {
  const int r = blockIdx.y;
  const int t = threadIdx.x;
  const int E = P.E[r], loopb = P.loopbase[r], sh = P.shift[r];
  const int nb = P.nb[r], cap = P.cap[r];
  const int* srcp = P.src[r];
  const int* dstp = P.dst[r];
  unsigned* stg = P.stage + P.sb[r];
  int* gc = P.gcur + r * 32;
  int* cnt = P.cnt + P.cntoff[r];
  __shared__ unsigned lbuf[32][320];
  __shared__ int lcnt[32], fb[32], fn[32];
  if (t < 32) lcnt[t] = 0;
  __syncthreads();
  int chunk = (E + gridDim.x - 1) / gridDim.x;
  int e0 = blockIdx.x * chunk;
  int e1 = e0 + chunk; if (e1 > E) e1 = E;
  for (int base = e0; base < e1; base += 256) {
    int e = base + t;
    if (e < e1) {
      int d, s;
      if (e >= loopb) { d = e - loopb; s = d; }
      else { d = dstp[e]; s = srcp[e]; }
      atomicAdd(&cnt[d], 1);
      int b = d >> sh;
      int lp = atomicAdd(&lcnt[b], 1);
      unsigned key = ((unsigned)d << 16) | (unsigned)s;
      if (lp < 320) lbuf[b][lp] = key;
      else { int gp = atomicAdd(&gc[b], 1); if (gp < cap) stg[b * cap + gp] = key; }
    }
    __syncthreads();
    if (t < nb) {
      int n = lcnt[t]; if (n > 320) n = 320;
      if (n >= 64) { fn[t] = n; fb[t] = atomicAdd(&gc[t], n); } else fn[t] = 0;
    }
    __syncthreads();
    for (int b = 0; b < nb; ++b) {
      int n = fn[b];
      if (n) {
        int fbb = fb[b];
        if (fbb + n <= cap)
          for (int i = t; i < n; i += 256) stg[b * cap + fbb + i] = lbuf[b][i];
      }
    }
    __syncthreads();
    if (t < nb && fn[t]) lcnt[t] = 0;
    __syncthreads();
  }
  // final flush
  if (t < nb) {
    int n = lcnt[t]; if (n > 320) n = 320;
    if (n > 0) { fn[t] = n; fb[t] = atomicAdd(&gc[t], n); } else fn[t] = 0;
  }
  __syncthreads();
  for (int b = 0; b < nb; ++b) {
    int n = fn[b];
    if (n) {
      int fbb = fb[b];
      if (fbb + n <= cap)
        for (int i = t; i < n; i += 256) stg[b * cap + fbb + i] = lbuf[b][i];
    }
  }
}

struct Scan { const int* cnt[5]; int* st[5]; int n[5]; };
__global__ __launch_bounds__(256) void k_scan5(Scan a) {
  int rel = blockIdx.x;
  int n = a.n[rel];
  const int* cnt = a.cnt[rel];
  int* st = a.st[rel];
  __shared__ int part[256];
  int t = threadIdx.x;
  int stripe = (n + 255) / 256;
  int lo = t * stripe;
  int hi = lo + stripe; if (hi > n) hi = n;
  int s = 0;
  for (int i = lo; i < hi; ++i) s += cnt[i];
  part[t] = s;
  __syncthreads();
  if (t == 0) {
    int run = 0;
    for (int i = 0; i < 256; ++i) { int v = part[i]; part[i] = run; run += v; }
  }
  __syncthreads();
  int run = part[t];
  for (int i = lo; i < hi; ++i) { st[i] = run; run += cnt[i]; }
  if (lo < n && hi == n) st[n] = run;
}

// P2: one block per bucket; segment cursors in LDS; scatter confined to bucket window.
struct Fill {
  const unsigned* stage; const int* gcur;
  int sb[5]; int cap[5]; int shift[5]; int ndst[5]; int bb[6];
  const int* starts[5]; int* csr[5];
};
__global__ __launch_bounds__(256) void k_csrfill(Fill F) {
  int bid = blockIdx.x;
  int r = 0;
  while (r < 4 && bid >= F.bb[r + 1]) ++r;
  int lb = bid - F.bb[r];
  int dst0 = lb << F.shift[r];
  int nseg = (1 << F.shift[r]);
  if (dst0 + nseg > F.ndst[r]) nseg = F.ndst[r] - dst0;
  if (nseg <= 0) return;
  __shared__ int cur[1024];
  int t = threadIdx.x;
  const int* st = F.starts[r];
  for (int i = t; i < nseg; i += 256) cur[i] = st[dst0 + i];
  __syncthreads();
  int n = F.gcur[r * 32 + lb];
  if (n > F.cap[r]) n = F.cap[r];
  const unsigned* base = F.stage + F.sb[r] + (size_t)lb * F.cap[r];
  int* csr = F.csr[r];
  for (int i = t; i < n; i += 256) {
    unsigned u = base[i];
    int d = (int)(u >> 16) - dst0;
    int s = (int)(u & 0xffffu);
    int pos = atomicAdd(&cur[d], 1);
    csr[pos] = s;
  }
}

// ---------------- GAT aggregate on RAW x (aggregate-then-transform) ----------------
struct Agg5 {
  const int* csr[5]; const int* starts[5];
  const float* ss[5]; const float* sd[5];
  const bf16_t* xs[5];
  bf16_t* y[5]; int ystride[5]; int ycoff[5]; int ndst[5];
};
__global__ __launch_bounds__(256) void k_agg5(Agg5 a) {
  int rel = blockIdx.y;
  int d = blockIdx.x * 4 + (threadIdx.x >> 6);
  if (d >= a.ndst[rel]) return;
  int lane = threadIdx.x & 63;
  int g = lane >> 4, j16 = lane & 15;
  bf16_t* yrow = a.y[rel] + (size_t)d * a.ystride[rel] + a.ycoff[rel];
  int s0 = a.starts[rel][d];
  int deg = a.starts[rel][d + 1] - s0;
  if (!deg) {
    if (g == 0) *(uint4*)(yrow + j16 * 8) = make_uint4(0u, 0u, 0u, 0u);
    return;
  }
  const int* cs = a.csr[rel] + s0;
  const float* ssp = a.ss[rel];
  const bf16_t* xsp = a.xs[rel];
  float sdv = a.sd[rel][d];
  float m = -3.0e38f;
  for (int i = lane; i < deg; i += 64) {
    float e = ssp[cs[i]] + sdv; e = e > 0.f ? e : 0.2f * e;
    m = fmaxf(m, e);
  }
  m = wred_max(m);
  float acc[8] = {0.f, 0.f, 0.f, 0.f, 0.f, 0.f, 0.f, 0.f};
  float ps = 0.f;
  for (int b = 0; b < deg; b += 16) {
#pragma unroll
    for (int u = 0; u < 4; ++u) {
      int i = b + u * 4 + g;
      float p = 0.f;
      uint4 U = make_uint4(0u, 0u, 0u, 0u);
      if (i < deg) {
        int s = cs[i];
        float e = ssp[s] + sdv; e = e > 0.f ? e : 0.2f * e;
        p = __expf(e - m);
        U = *(const uint4*)(xsp + (size_t)s * H + j16 * 8);
      }
      ps += p;
      acc[0] = fmaf(p, bflo(U.x), acc[0]); acc[1] = fmaf(p, bfhi(U.x), acc[1]);
      acc[2] = fmaf(p, bflo(U.y), acc[2]); acc[3] = fmaf(p, bfhi(U.y), acc[3]);
      acc[4] = fmaf(p, bflo(U.z), acc[4]); acc[5] = fmaf(p, bfhi(U.z), acc[5]);
      acc[6] = fmaf(p, bflo(U.w), acc[6]); acc[7] = fmaf(p, bfhi(U.w), acc[7]);
    }
  }
#pragma unroll
  for (int e = 0; e < 8; ++e) {
    acc[e] += __shfl_xor(acc[e], 16);
    acc[e] += __shfl_xor(acc[e], 32);
  }
  ps += __shfl_xor(ps, 16);
  ps += __shfl_xor(ps, 32);
  if (g == 0) {
    float inv = 1.f / ps;
    uint4 O;
    O.x = packbf(acc[0] * inv, acc[1] * inv);
    O.y = packbf(acc[2] * inv, acc[3] * inv);
    O.z = packbf(acc[4] * inv, acc[5] * inv);
    O.w = packbf(acc[6] * inv, acc[7] * inv);
    *(uint4*)(yrow + j16 * 8) = O;
  }
}

// ---------------- readout ----------------
__global__ __launch_bounds__(256) void k_invnorm(
    const bf16_t* __restrict__ xd, const bf16_t* __restrict__ xc,
    float* __restrict__ invd, float* __restrict__ invc)
{
  int row = blockIdx.x * 4 + (threadIdx.x >> 6);
  if (row >= ND + NCN) return;
  int lane = threadIdx.x & 63;
  const bf16_t* x = (row < ND) ? xd + (size_t)row * H : xc + (size_t)(row - ND) * H;
  unsigned u = *(const unsigned*)(x + lane * 2);
  float av = bflo(u), bv = bfhi(u);
  float s = wred_sum(av * av + bv * bv);
  if (!lane) {
    float nv = fmaxf(sqrtf(s), 1e-12f);
    if (row < ND) invd[row] = 1.f / nv; else invc[row - ND] = 1.f / nv;
  }
}
__global__ __launch_bounds__(256) void k_make_hid(
    const bf16_t* __restrict__ xd, const bf16_t* __restrict__ xc,
    const float* __restrict__ invd, const float* __restrict__ invc,
    const int* __restrict__ d1, const int* __restrict__ d2, const int* __restrict__ ce,
    bf16_t* __restrict__ hid, int c0, int cn)
{
  int gid = blockIdx.x * 256 + threadIdx.x;
  if (gid >= cn * 48) return;
  int i = gid / 48, c16 = gid - i * 48;
  int gi = c0 + i;
  int sel = c16 >> 4;
  int jb = (c16 & 15) * 8;
  int rrow; const bf16_t* xs; float sc;
  if (sel == 0)      { rrow = d1[gi]; xs = xd; sc = invd[rrow]; }
  else if (sel == 1) { rrow = d2[gi]; xs = xd; sc = invd[rrow]; }
  else               { rrow = ce[gi]; xs = xc; sc = invc[rrow]; }
  uint4 U = *(const uint4*)(xs + (size_t)rrow * H + jb);
  uint4 O;
  O.x = packbf(bflo(U.x) * sc, bfhi(U.x) * sc);
  O.y = packbf(bflo(U.y) * sc, bfhi(U.y) * sc);
  O.z = packbf(bflo(U.z) * sc, bfhi(U.z) * sc);
  O.w = packbf(bflo(U.w) * sc, bfhi(U.w) * sc);
  *(uint4*)(hid + (size_t)i * 384 + c16 * 8) = O;
}
__global__ __launch_bounds__(256) void k_mlp3(
    const bf16_t* __restrict__ h2, const float* __restrict__ W3, const float* __restrict__ b3,
    float* __restrict__ out, int cn, int c0)
{
  int row = blockIdx.x * 4 + (threadIdx.x >> 6);
  if (row >= cn) return;
  int lane = threadIdx.x & 63;
  uint2 U = *(const uint2*)(h2 + (size_t)row * 256 + lane * 4);
  float v0 = bflo(U.x), v1 = bfhi(U.x), v2 = bflo(U.y), v3 = bfhi(U.y);
  const float* w = W3 + 8 * lane;
  float4 wa = *(const float4*)w;
  float4 wb = *(const float4*)(w + 4);
  float o0 = v0 * wa.x + v1 * wa.z + v2 * wb.x + v3 * wb.z;
  float o1 = v0 * wa.y + v1 * wa.w + v2 * wb.y + v3 * wb.w;
  o0 = wred_sum(o0);
  o1 = wred_sum(o1);
  if (!lane) {
    out[(size_t)(c0 + row) * 2]     = o0 + b3[0];
    out[(size_t)(c0 + row) * 2 + 1] = o1 + b3[1];
  }
}

// ================= host =================
extern "C" void kernel_launch(void* const* d_in, const int* in_sizes, int n_in,
                              void* d_out, int out_size, void* d_ws, size_t ws_size,
                              hipStream_t stream)
{
  (void)in_sizes; (void)n_in; (void)out_size;
  const float* drug_emb    = (const float*)d_in[0];
  const float* protein_emb = (const float*)d_in[1];
  const float* cell_emb    = (const float*)d_in[2];
  // internal rel order: 0=dp, 1=pp, 2=cp, 3=rdp, 4=rcp
  const int base_idx[5] = {3, 11, 15, 7, 19};
  const float *W_[5], *as_[5], *ad_[5], *b_[5];
  for (int r = 0; r < 5; ++r) {
    W_[r]  = (const float*)d_in[base_idx[r]];
    as_[r] = (const float*)d_in[base_idx[r] + 1];
    ad_[r] = (const float*)d_in[base_idx[r] + 2];
    b_[r]  = (const float*)d_in[base_idx[r] + 3];
  }
  const float* W1 = (const float*)d_in[23]; const float* b1 = (const float*)d_in[24];
  const float* W2 = (const float*)d_in[25]; const float* b2 = (const float*)d_in[26];
  const float* W3 = (const float*)d_in[27]; const float* b3 = (const float*)d_in[28];
  const int* src_dp = (const int*)d_in[29]; const int* dst_dp = (const int*)d_in[30];
  const int* src_pp = (const int*)d_in[31]; const int* dst_pp = (const int*)d_in[32];
  const int* src_cp = (const int*)d_in[33]; const int* dst_cp = (const int*)d_in[34];
  const int* drug1  = (const int*)d_in[35]; const int* drug2  = (const int*)d_in[36];
  const int* cellb  = (const int*)d_in[37];
  float* out = (float*)d_out;

  char* wsb = (char*)d_ws;
  size_t off = 0;
  auto alloc = [&](size_t bytes) -> void* {
    void* p = wsb + off;
    off += (bytes + 255) & ~(size_t)255;
    return p;
  };
  bf16_t* xdb[2] = {(bf16_t*)alloc((size_t)ND * H * 2),  (bf16_t*)alloc((size_t)ND * H * 2)};
  bf16_t* xpb[2] = {(bf16_t*)alloc((size_t)NPN * H * 2), (bf16_t*)alloc((size_t)NPN * H * 2)};
  bf16_t* xcb[2] = {(bf16_t*)alloc((size_t)NCN * H * 2), (bf16_t*)alloc((size_t)NCN * H * 2)};
  const int Msrc[5] = {ND, NPN, NCN, NPN, NPN};
  const int Mdst[5] = {NPN, NPN, NPN, ND, NCN};
  const int Erel[5] = {E_DP, E_PP + NPN, E_CP, E_DP, E_CP};
  bf16_t* yp = (bf16_t*)alloc((size_t)NPN * 384 * 2);
  bf16_t* yd = (bf16_t*)alloc((size_t)ND * H * 2);
  bf16_t* yc = (bf16_t*)alloc((size_t)NCN * H * 2);
  bf16_t* Wtp = (bf16_t*)alloc((size_t)NLAYERS * 128 * 384 * 2);
  bf16_t* Wtd = (bf16_t*)alloc((size_t)NLAYERS * 128 * 128 * 2);
  bf16_t* Wtc = (bf16_t*)alloc((size_t)NLAYERS * 128 * 128 * 2);
  bf16_t* W1t = (bf16_t*)alloc((size_t)768 * 384 * 2);
  bf16_t* W2t = (bf16_t*)alloc((size_t)256 * 768 * 2);
  float* wvb = (float*)alloc(10 * H * 4);
  float* ssb[5]; for (int r = 0; r < 5; ++r) ssb[r] = (float*)alloc((size_t)Msrc[r] * 4);
  float* sdb[5]; for (int r = 0; r < 5; ++r) sdb[r] = (float*)alloc((size_t)Mdst[r] * 4);
  int* cnt_all = (int*)alloc(62000 * 4);
  int* st_all  = (int*)alloc((62000 + 5) * 4);
  int* gcur    = (int*)alloc(160 * 4);
  const int bcap[5] = {11520, 18000, 8640, 6900, 5220};
  const int bnb[5]  = {19, 19, 19, 32, 32};
  const int bsh[5]  = {10, 10, 10, 7, 5};
  int bsb[5]; { int o = 0; for (int r = 0; r < 5; ++r) { bsb[r] = o; o += bnb[r] * bcap[r]; } }
  unsigned* stage = (unsigned*)alloc((size_t)(19 * (11520 + 18000 + 8640) + 32 * (6900 + 5220)) * 4);
  int *cntb[5], *stb[5];
  int cntoff[5];
  { int o = 0, o2 = 0;
    for (int r = 0; r < 5; ++r) {
      cntb[r] = cnt_all + o; stb[r] = st_all + o2; cntoff[r] = o;
      o += Mdst[r]; o2 += Mdst[r] + 1;
    } }
  int* csrb[5]; for (int r = 0; r < 5; ++r) csrb[r] = (int*)alloc((size_t)Erel[r] * 4);
  float* invd = (float*)alloc(ND * 4);
  float* invc = (float*)alloc(NCN * 4);
  size_t fixed_end = off;
  size_t avail = ws_size > fixed_end ? ws_size - fixed_end : 0;
  long long cmax = (long long)avail / 2816;
  int CH = cmax > NB ? NB : (int)cmax;
  CH &= ~255;
  if (CH < 256) CH = 256;
  bf16_t* hid = (bf16_t*)alloc((size_t)CH * 384 * 2);
  bf16_t* h1  = (bf16_t*)alloc((size_t)CH * 768 * 2);
  bf16_t* h2  = (bf16_t*)alloc((size_t)CH * 256 * 2);

  // conversions
  k_conv_emb<<<(ND * H + NPN * H + NCN * H + 255) / 256, 256, 0, stream>>>(
      drug_emb, protein_emb, cell_emb, xdb[0], xpb[0], xcb[0]);
  TC tc;
  for (int l = 0; l < 2; ++l) {
    for (int r = 0; r < 3; ++r) {
      int m = l * 3 + r;
      tc.src[m] = W_[r] + (size_t)l * H * H;
      tc.dst[m] = Wtp + (size_t)l * 128 * 384;
      tc.Ksub[m] = 128; tc.N[m] = 128; tc.Kfull[m] = 384; tc.koff[m] = r * 128;
    }
    tc.src[6 + l] = W_[3] + (size_t)l * H * H; tc.dst[6 + l] = Wtd + (size_t)l * 128 * 128;
    tc.Ksub[6 + l] = 128; tc.N[6 + l] = 128; tc.Kfull[6 + l] = 128; tc.koff[6 + l] = 0;
    tc.src[8 + l] = W_[4] + (size_t)l * H * H; tc.dst[8 + l] = Wtc + (size_t)l * 128 * 128;
    tc.Ksub[8 + l] = 128; tc.N[8 + l] = 128; tc.Kfull[8 + l] = 128; tc.koff[8 + l] = 0;
  }
  tc.src[10] = W1; tc.dst[10] = W1t; tc.Ksub[10] = 384; tc.N[10] = 768; tc.Kfull[10] = 384; tc.koff[10] = 0;
  tc.src[11] = W2; tc.dst[11] = W2t; tc.Ksub[11] = 768; tc.N[11] = 256; tc.Kfull[11] = 768; tc.koff[11] = 0;
  k_tconv2<<<dim3(24, 24, 12), 256, 0, stream>>>(tc);

  // graph build
  hipMemsetAsync(cnt_all, 0, 62000 * 4, stream);
  hipMemsetAsync(gcur, 0, 160 * 4, stream);
  Part pa;
  const int* srcA[5] = {src_dp, src_pp, src_cp, dst_dp, dst_cp};
  const int* dstA[5] = {dst_dp, dst_pp, dst_cp, src_dp, src_cp};
  const int loopb[5] = {0x7fffffff, E_PP, 0x7fffffff, 0x7fffffff, 0x7fffffff};
  for (int r = 0; r < 5; ++r) {
    pa.src[r] = srcA[r]; pa.dst[r] = dstA[r]; pa.E[r] = Erel[r]; pa.loopbase[r] = loopb[r];
    pa.shift[r] = bsh[r]; pa.nb[r] = bnb[r]; pa.cap[r] = bcap[r]; pa.sb[r] = bsb[r];
    pa.cntoff[r] = cntoff[r];
  }
  pa.stage = stage; pa.gcur = gcur; pa.cnt = cnt_all;
  k_part<<<dim3(32, 5), 256, 0, stream>>>(pa);
  Scan sa;
  for (int r = 0; r < 5; ++r) { sa.cnt[r] = cntb[r]; sa.st[r] = stb[r]; sa.n[r] = Mdst[r]; }
  k_scan5<<<5, 256, 0, stream>>>(sa);
  Fill fa;
  fa.stage = stage; fa.gcur = gcur;
  int bbacc = 0;
  for (int r = 0; r < 5; ++r) {
    fa.sb[r] = bsb[r]; fa.cap[r] = bcap[r]; fa.shift[r] = bsh[r]; fa.ndst[r] = Mdst[r];
    fa.bb[r] = bbacc; bbacc += bnb[r];
    fa.starts[r] = stb[r]; fa.csr[r] = csrb[r];
  }
  fa.bb[5] = bbacc;   // 121
  k_csrfill<<<bbacc, 256, 0, stream>>>(fa);

  int cur = 0;
  for (int l = 0; l < NLAYERS; ++l) {
    int nxt = 1 - cur;
    const bf16_t* xsrc[5] = {xdb[cur], xpb[cur], xcb[cur], xpb[cur], xpb[cur]};
    Wd10 wg;
    for (int r = 0; r < 5; ++r) {
      wg.W[r] = W_[r] + (size_t)l * H * H; wg.a[r] = as_[r] + l * H; wg.o[r] = wvb + r * H;
      wg.W[5 + r] = W_[r] + (size_t)l * H * H; wg.a[5 + r] = ad_[r] + l * H; wg.o[5 + r] = wvb + (5 + r) * H;
    }
    k_wd10<<<10, 128, 0, stream>>>(wg);
    Sc sc;
    sc.xd = xdb[cur]; sc.xp = xpb[cur]; sc.xc = xcb[cur]; sc.wv = wvb;
    for (int r = 0; r < 5; ++r) { sc.ss[r] = ssb[r]; sc.sd[r] = sdb[r]; }
    k_scores<<<(ND + NPN + NCN + 3) / 4, 256, 0, stream>>>(sc);
    Agg5 aa;
    bf16_t* yptr[5] = {yp, yp, yp, yd, yc};
    const int ystr[5] = {384, 384, 384, 128, 128};
    const int ycof[5] = {0, 128, 256, 0, 0};
    for (int r = 0; r < 5; ++r) {
      aa.csr[r] = csrb[r]; aa.starts[r] = stb[r]; aa.ss[r] = ssb[r]; aa.sd[r] = sdb[r];
      aa.xs[r] = xsrc[r]; aa.y[r] = yptr[r]; aa.ystride[r] = ystr[r]; aa.ycoff[r] = ycof[r];
      aa.ndst[r] = Mdst[r];
    }
    k_agg5<<<dim3((NPN + 3) / 4, 5), 256, 0, stream>>>(aa);
    Gemm3 g3;
    g3.j[0] = {yp, Wtp + (size_t)l * 128 * 384, xpb[nxt], NPN, 384,
               b_[0] + l * H, b_[1] + l * H, b_[2] + l * H};
    g3.j[1] = {yd, Wtd + (size_t)l * 128 * 128, xdb[nxt], ND, 128,
               b_[3] + l * H, nullptr, nullptr};
    g3.j[2] = {yc, Wtc + (size_t)l * 128 * 128, xcb[nxt], NCN, 128,
               b_[4] + l * H, nullptr, nullptr};
    k_gemm_g3<<<dim3((NPN + 127) / 128, 3), 256, 0, stream>>>(g3);
    cur = nxt;
  }

  k_invnorm<<<(ND + NCN + 3) / 4, 256, 0, stream>>>(xdb[cur], xcb[cur], invd, invc);
  for (int c0 = 0; c0 < NB; c0 += CH) {
    int cn = (NB - c0 < CH) ? (NB - c0) : CH;
    k_make_hid<<<((size_t)cn * 48 + 255) / 256, 256, 0, stream>>>(
        xdb[cur], xcb[cur], invd, invc, drug1, drug2, cellb, hid, c0, cn);
    k_gemm_bf<<<dim3((cn + 127) / 128, 6), 256, 0, stream>>>(hid, W1t, h1, cn, 768, 384, b1, 1);
    k_gemm_bf<<<dim3((cn + 127) / 128, 2), 256, 0, stream>>>(h1, W2t, h2, cn, 256, 768, b2, 1);
    k_mlp3<<<(cn + 3) / 4, 256, 0, stream>>>(h2, W3, b3, out, cn, c0);
  }
}

// Round 5
// 484.699 us; speedup vs baseline: 1.1258x; 1.1099x over previous
//
#include <hip/hip_runtime.h>
#include <hip/hip_bf16.h>

#define H 128
#define ND 4000
#define NPN 19000
#define NCN 1000
#define NLAYERS 2
#define NB 30000
#define E_DP 200000
#define E_PP 300000
#define E_CP 150000

typedef __bf16 bf16_t;
typedef bf16_t bf16x8 __attribute__((ext_vector_type(8)));
typedef float f32x4 __attribute__((ext_vector_type(4)));

static __device__ __forceinline__ float wred_sum(float v) {
#pragma unroll
  for (int off = 32; off; off >>= 1) v += __shfl_xor(v, off);
  return v;
}
static __device__ __forceinline__ float bflo(unsigned u) { return __uint_as_float(u << 16); }
static __device__ __forceinline__ float bfhi(unsigned u) { return __uint_as_float(u & 0xffff0000u); }
static __device__ __forceinline__ unsigned packbf(float v0, float v1) {
  union { bf16_t b; unsigned short u; } a, b;
  a.b = (bf16_t)v0; b.b = (bf16_t)v1;
  return (unsigned)a.u | ((unsigned)b.u << 16);
}

// async global->LDS, 16B per lane
#define GLDS16(gp, lp) \
  __builtin_amdgcn_global_load_lds((__attribute__((address_space(1))) void*)(gp), \
                                   (__attribute__((address_space(3))) void*)(lp), 16, 0, 0)

// ================= bf16 MFMA GEMM (global_load_lds staging) =================
// A [M,K] bf16 (lda=K), Bt [N,ldb] bf16 (uses cols 0..K of each row), C [M,N] OutT.
template <typename OutT>
__device__ __forceinline__ void mfma_gemm_body(
    const bf16_t* __restrict__ A, const bf16_t* __restrict__ Bt, OutT* __restrict__ C,
    int M, int N, int K, int ldb,
    const float* __restrict__ b1, const float* __restrict__ b2, const float* __restrict__ b3,
    int do_relu, int m0, int n0)
{
  __shared__ char As[128 * 64];
  __shared__ char Bs[128 * 64];
  const int t = threadIdx.x;
  const int lane = t & 63;
  const int wid = t >> 6;
  const int wr = wid >> 1, wc = wid & 1;
  f32x4 acc[4][4];
#pragma unroll
  for (int mi = 0; mi < 4; ++mi)
#pragma unroll
    for (int ni = 0; ni < 4; ++ni) acc[mi][ni] = (f32x4){0.f, 0.f, 0.f, 0.f};

  const int sr = t >> 2;
  const int sc = t & 3;
  const int csrc = ((sc ^ ((sr >> 1) & 3)) << 4);
  int ra0 = m0 + sr;      if (ra0 >= M) ra0 = M - 1;
  int ra1 = m0 + 64 + sr; if (ra1 >= M) ra1 = M - 1;
  const char* gA0 = (const char*)A + (size_t)ra0 * K * 2 + csrc;
  const char* gA1 = (const char*)A + (size_t)ra1 * K * 2 + csrc;
  const char* gB0 = (const char*)Bt + (size_t)(n0 + sr) * ldb * 2 + csrc;
  const char* gB1 = (const char*)Bt + (size_t)(n0 + 64 + sr) * ldb * 2 + csrc;
  char* lA0 = As + t * 16;
  char* lA1 = As + 4096 + t * 16;
  char* lB0 = Bs + t * 16;
  char* lB1 = Bs + 4096 + t * 16;

  int aoff[4], boff[4];
#pragma unroll
  for (int mi = 0; mi < 4; ++mi) {
    int r = wr * 64 + mi * 16 + (lane & 15);
    aoff[mi] = r * 64 + ((((lane >> 4)) ^ ((r >> 1) & 3)) << 4);
  }
#pragma unroll
  for (int ni = 0; ni < 4; ++ni) {
    int r = wc * 64 + ni * 16 + (lane & 15);
    boff[ni] = r * 64 + ((((lane >> 4)) ^ ((r >> 1) & 3)) << 4);
  }

  for (int k0 = 0; k0 < K; k0 += 32) {
    const size_t kb = (size_t)k0 * 2;
    __syncthreads();
    GLDS16(gA0 + kb, lA0);
    GLDS16(gA1 + kb, lA1);
    GLDS16(gB0 + kb, lB0);
    GLDS16(gB1 + kb, lB1);
    __syncthreads();
    bf16x8 av[4], bv[4];
#pragma unroll
    for (int mi = 0; mi < 4; ++mi) av[mi] = *(const bf16x8*)(As + aoff[mi]);
#pragma unroll
    for (int ni = 0; ni < 4; ++ni) bv[ni] = *(const bf16x8*)(Bs + boff[ni]);
#pragma unroll
    for (int mi = 0; mi < 4; ++mi)
#pragma unroll
      for (int ni = 0; ni < 4; ++ni)
        acc[mi][ni] = __builtin_amdgcn_mfma_f32_16x16x32_bf16(av[mi], bv[ni], acc[mi][ni], 0, 0, 0);
  }

  const int col0 = lane & 15;
  const int rsub = (lane >> 4) * 4;
#pragma unroll
  for (int mi = 0; mi < 4; ++mi) {
#pragma unroll
    for (int ni = 0; ni < 4; ++ni) {
      int c = n0 + wc * 64 + ni * 16 + col0;
      float bb = b1 ? b1[c] : 0.f;
      if (b2) bb += b2[c];
      if (b3) bb += b3[c];
#pragma unroll
      for (int rg = 0; rg < 4; ++rg) {
        int r = m0 + wr * 64 + mi * 16 + rsub + rg;
        if (r < M) {
          float v = acc[mi][ni][rg] + bb;
          if (do_relu) v = fmaxf(v, 0.f);
          C[(size_t)r * N + c] = (OutT)v;
        }
      }
    }
  }
}

__global__ __launch_bounds__(256) void k_gemm_bf(
    const bf16_t* __restrict__ A, const bf16_t* __restrict__ Bt, bf16_t* __restrict__ C,
    int M, int N, int K, const float* __restrict__ bias, int do_relu)
{
  mfma_gemm_body<bf16_t>(A, Bt, C, M, N, K, K, bias, nullptr, nullptr, do_relu,
                         blockIdx.x * 128, blockIdx.y * 128);
}

// 3 dst-side GAT GEMM jobs (protein K=384, drug K=128, cell K=128), N=128, relu
struct GJob { const bf16_t* A; const bf16_t* Bt; bf16_t* C; int M; int K;
              const float *b1, *b2, *b3; };
struct Gemm3 { GJob j[3]; };
__global__ __launch_bounds__(256) void k_gemm_g3(Gemm3 g) {
  const GJob& jb = g.j[blockIdx.y];
  int m0 = blockIdx.x * 128;
  if (m0 >= jb.M) return;
  mfma_gemm_body<bf16_t>(jb.A, jb.Bt, jb.C, jb.M, H, jb.K, jb.K, jb.b1, jb.b2, jb.b3, 1, m0, 0);
}

// head slice GEMMs: P = xn @ W1[koff:koff+128, :]  (f32 out, N=768, K=128, ldb=384)
struct PJob { const bf16_t* A; float* C; int M; };
struct GemmPS { PJob j[3]; const bf16_t* Bt; };
__global__ __launch_bounds__(256) void k_gemm_ps(GemmPS g) {
  const PJob& jb = g.j[blockIdx.y];
  int mt = blockIdx.x / 6, nt = blockIdx.x - mt * 6;
  int m0 = mt * 128;
  if (m0 >= jb.M) return;
  mfma_gemm_body<float>(jb.A, g.Bt + blockIdx.y * 128, jb.C, jb.M, 768, 128, 384,
                        nullptr, nullptr, nullptr, 0, m0, nt * 128);
}

// ================= conversions =================
__global__ __launch_bounds__(256) void k_conv_emb(
    const float* __restrict__ xd, const float* __restrict__ xp, const float* __restrict__ xc,
    bf16_t* __restrict__ od, bf16_t* __restrict__ op, bf16_t* __restrict__ oc)
{
  int i = blockIdx.x * 256 + threadIdx.x;
  const int SD = ND * H, SP = NPN * H, SC = NCN * H;
  if (i < SD) od[i] = (bf16_t)xd[i];
  else if (i < SD + SP) op[i - SD] = (bf16_t)xp[i - SD];
  else if (i < SD + SP + SC) oc[i - SD - SP] = (bf16_t)xc[i - SD - SP];
}

// LDS-tiled transpose-convert: dst[n*Kfull+koff+k] = bf16(src[k*N+n])
struct TC { const float* src[12]; bf16_t* dst[12]; int Ksub[12]; int N[12]; int Kfull[12]; int koff[12]; };
__global__ __launch_bounds__(256) void k_tconv2(TC a) {
  int m = blockIdx.z;
  int Ks = a.Ksub[m], N = a.N[m];
  int tx = blockIdx.x * 32;   // n dim
  int ty = blockIdx.y * 32;   // k dim
  if (tx >= N || ty >= Ks) return;
  __shared__ float tile[32][33];
  int c = threadIdx.x & 31, rr = threadIdx.x >> 5;
#pragma unroll
  for (int kk = rr; kk < 32; kk += 8)
    if (ty + kk < Ks && tx + c < N) tile[kk][c] = a.src[m][(size_t)(ty + kk) * N + tx + c];
  __syncthreads();
  bf16_t* dst = a.dst[m];
  int Kf = a.Kfull[m], ko = a.koff[m];
#pragma unroll
  for (int nn = rr; nn < 32; nn += 8)
    if (tx + nn < N && ty + c < Ks)
      dst[(size_t)(tx + nn) * Kf + ko + ty + c] = (bf16_t)tile[c][nn];
}

// ---------------- wv = W @ a : both layers, 20 matvecs ----------------
struct Wd20 { const float* W[20]; const float* a[20]; float* o[20]; };
__global__ __launch_bounds__(128) void k_wd20(Wd20 g) {
  int m = blockIdx.x;
  int k = threadIdx.x;
  const float* Wp = g.W[m];
  const float* av = g.a[m];
  float s = 0.f;
#pragma unroll 4
  for (int j = 0; j < H; ++j) s = fmaf(Wp[k * H + j], av[j], s);
  g.o[m][k] = s;
}

// ---------------- fused node scores ----------------
struct Sc { const bf16_t* xd; const bf16_t* xp; const bf16_t* xc; const float* wv;
            float* ss[5]; float* sd[5]; };
__global__ __launch_bounds__(256) void k_scores(Sc S) {
  int row = blockIdx.x * 4 + (threadIdx.x >> 6);
  if (row >= ND + NPN + NCN) return;
  int lane = threadIdx.x & 63;
  const bf16_t* x;
  int idx, cls;
  if (row < ND) { x = S.xd; idx = row; cls = 0; }
  else if (row < ND + NPN) { x = S.xp; idx = row - ND; cls = 1; }
  else { x = S.xc; idx = row - ND - NPN; cls = 2; }
  unsigned u = *(const unsigned*)(x + (size_t)idx * H + lane * 2);
  float x0 = bflo(u), x1 = bfhi(u);
  const float* wv = S.wv;
#define DOT(vi, outp) { const float* v = wv + (vi) * H; \
    float s = x0 * v[2 * lane] + x1 * v[2 * lane + 1]; s = wred_sum(s); \
    if (!lane) (outp)[idx] = s; }
  if (cls == 0) {
    DOT(0, S.ss[0]); DOT(8, S.sd[3]);
  } else if (cls == 1) {
    DOT(1, S.ss[1]); DOT(3, S.ss[3]); DOT(4, S.ss[4]);
    DOT(5, S.sd[0]); DOT(6, S.sd[1]); DOT(7, S.sd[2]);
  } else {
    DOT(2, S.ss[2]); DOT(9, S.sd[4]);
  }
#undef DOT
}

// ---------------- CSR build (simple, R3-proven) ----------------
struct CsrArgs {
  const int* src[5]; const int* dst[5];
  int E[5]; int loopbase[5]; int n[5];
  int* cnt[5]; int* cur[5]; int* starts[5]; int* csr[5];
};
__global__ __launch_bounds__(256) void k_count5(CsrArgs a) {
  int rel = blockIdx.y;
  int e = blockIdx.x * 256 + threadIdx.x;
  if (e >= a.E[rel]) return;
  int d = (e >= a.loopbase[rel]) ? (e - a.loopbase[rel]) : a.dst[rel][e];
  atomicAdd(&a.cnt[rel][d], 1);
}
__global__ __launch_bounds__(256) void k_scan5(CsrArgs a) {
  int rel = blockIdx.x;
  int n = a.n[rel];
  const int* cnt = a.cnt[rel];
  int* st = a.starts[rel];
  int* cu = a.cur[rel];
  __shared__ int part[256];
  int t = threadIdx.x;
  int stripe = (n + 255) / 256;
  int lo = t * stripe;
  int hi = lo + stripe; if (hi > n) hi = n;
  int s = 0;
  for (int i = lo; i < hi; ++i) s += cnt[i];
  part[t] = s;
  __syncthreads();
  if (t == 0) {
    int run = 0;
    for (int i = 0; i < 256; ++i) { int v = part[i]; part[i] = run; run += v; }
  }
  __syncthreads();
  int run = part[t];
  for (int i = lo; i < hi; ++i) { st[i] = run; cu[i] = run; run += cnt[i]; }
  if (lo < n && hi == n) st[n] = run;
}
__global__ __launch_bounds__(256) void k_fill5(CsrArgs a) {
  int rel = blockIdx.y;
  int e = blockIdx.x * 256 + threadIdx.x;
  if (e >= a.E[rel]) return;
  int d, s;
  if (e >= a.loopbase[rel]) { d = e - a.loopbase[rel]; s = d; }
  else { d = a.dst[rel][e]; s = a.src[rel][e]; }
  int pos = atomicAdd(&a.cur[rel][d], 1);
  a.csr[rel][pos] = s;
}

// ---------------- GAT aggregate on RAW x; no max pass (shift-invariant) ----------------
struct Agg5 {
  const int* csr[5]; const int* starts[5];
  const float* ss[5]; const float* sd[5];
  const bf16_t* xs[5];
  bf16_t* y[5]; int ystride[5]; int ycoff[5]; int ndst[5];
};
__global__ __launch_bounds__(256) void k_agg5(Agg5 a) {
  int rel = blockIdx.y;
  int d = blockIdx.x * 4 + (threadIdx.x >> 6);
  if (d >= a.ndst[rel]) return;
  int lane = threadIdx.x & 63;
  int g = lane >> 4, j16 = lane & 15;
  bf16_t* yrow = a.y[rel] + (size_t)d * a.ystride[rel] + a.ycoff[rel];
  int s0 = a.starts[rel][d];
  int deg = a.starts[rel][d + 1] - s0;
  if (!deg) {
    if (g == 0) *(uint4*)(yrow + j16 * 8) = make_uint4(0u, 0u, 0u, 0u);
    return;
  }
  const int* cs = a.csr[rel] + s0;
  const float* ssp = a.ss[rel];
  const bf16_t* xsp = a.xs[rel];
  float sdv = a.sd[rel][d];
  float acc[8] = {0.f, 0.f, 0.f, 0.f, 0.f, 0.f, 0.f, 0.f};
  float ps = 0.f;
  for (int b = 0; b < deg; b += 16) {
#pragma unroll
    for (int u = 0; u < 4; ++u) {
      int i = b + u * 4 + g;
      float p = 0.f;
      uint4 U = make_uint4(0u, 0u, 0u, 0u);
      if (i < deg) {
        int s = cs[i];
        float e = ssp[s] + sdv; e = e > 0.f ? e : 0.2f * e;
        p = __expf(e);
        U = *(const uint4*)(xsp + (size_t)s * H + j16 * 8);
      }
      ps += p;
      acc[0] = fmaf(p, bflo(U.x), acc[0]); acc[1] = fmaf(p, bfhi(U.x), acc[1]);
      acc[2] = fmaf(p, bflo(U.y), acc[2]); acc[3] = fmaf(p, bfhi(U.y), acc[3]);
      acc[4] = fmaf(p, bflo(U.z), acc[4]); acc[5] = fmaf(p, bfhi(U.z), acc[5]);
      acc[6] = fmaf(p, bflo(U.w), acc[6]); acc[7] = fmaf(p, bfhi(U.w), acc[7]);
    }
  }
#pragma unroll
  for (int e = 0; e < 8; ++e) {
    acc[e] += __shfl_xor(acc[e], 16);
    acc[e] += __shfl_xor(acc[e], 32);
  }
  ps += __shfl_xor(ps, 16);
  ps += __shfl_xor(ps, 32);
  if (g == 0) {
    float inv = 1.f / ps;
    uint4 O;
    O.x = packbf(acc[0] * inv, acc[1] * inv);
    O.y = packbf(acc[2] * inv, acc[3] * inv);
    O.z = packbf(acc[4] * inv, acc[5] * inv);
    O.w = packbf(acc[6] * inv, acc[7] * inv);
    *(uint4*)(yrow + j16 * 8) = O;
  }
}

// ---------------- readout ----------------
// normalize rows -> bf16 tables xdn/xcn
__global__ __launch_bounds__(256) void k_normw(
    const bf16_t* __restrict__ xd, const bf16_t* __restrict__ xc,
    bf16_t* __restrict__ xdn, bf16_t* __restrict__ xcn)
{
  int row = blockIdx.x * 4 + (threadIdx.x >> 6);
  if (row >= ND + NCN) return;
  int lane = threadIdx.x & 63;
  const bf16_t* x; bf16_t* o;
  if (row < ND) { x = xd + (size_t)row * H; o = xdn + (size_t)row * H; }
  else { x = xc + (size_t)(row - ND) * H; o = xcn + (size_t)(row - ND) * H; }
  unsigned u = ((const unsigned*)x)[lane];
  float av = bflo(u), bv = bfhi(u);
  float s = wred_sum(av * av + bv * bv);
  s = __shfl(s, 0);
  float inv = 1.f / fmaxf(sqrtf(s), 1e-12f);
  ((unsigned*)o)[lane] = packbf(av * inv, bv * inv);
}

// h1 = relu(Pa[d1] + Pb[d2] + Pc[ce] + b1)  (tables f32, out bf16)
__global__ __launch_bounds__(256) void k_pairsum(
    const float* __restrict__ Pa, const float* __restrict__ Pb, const float* __restrict__ Pc,
    const float* __restrict__ b1,
    const int* __restrict__ d1, const int* __restrict__ d2, const int* __restrict__ ce,
    bf16_t* __restrict__ h1, int c0, int cn)
{
  int gid = blockIdx.x * 256 + threadIdx.x;   // one 8-elem chunk of a 768 row
  if (gid >= cn * 96) return;
  int i = gid / 96, c = gid - i * 96;
  int gi = c0 + i;
  int ra = d1[gi], rb = d2[gi], rc = ce[gi];
  const float4* pa = (const float4*)(Pa + (size_t)ra * 768 + c * 8);
  const float4* pb = (const float4*)(Pb + (size_t)rb * 768 + c * 8);
  const float4* pc = (const float4*)(Pc + (size_t)rc * 768 + c * 8);
  const float4* bb = (const float4*)(b1 + c * 8);
  float4 s0 = pa[0], s1 = pa[1];
  float4 t0 = pb[0], t1 = pb[1];
  float4 u0 = pc[0], u1 = pc[1];
  float4 v0 = bb[0], v1 = bb[1];
  float o0 = fmaxf(s0.x + t0.x + u0.x + v0.x, 0.f);
  float o1 = fmaxf(s0.y + t0.y + u0.y + v0.y, 0.f);
  float o2 = fmaxf(s0.z + t0.z + u0.z + v0.z, 0.f);
  float o3 = fmaxf(s0.w + t0.w + u0.w + v0.w, 0.f);
  float o4 = fmaxf(s1.x + t1.x + u1.x + v1.x, 0.f);
  float o5 = fmaxf(s1.y + t1.y + u1.y + v1.y, 0.f);
  float o6 = fmaxf(s1.z + t1.z + u1.z + v1.z, 0.f);
  float o7 = fmaxf(s1.w + t1.w + u1.w + v1.w, 0.f);
  uint4 O;
  O.x = packbf(o0, o1); O.y = packbf(o2, o3); O.z = packbf(o4, o5); O.w = packbf(o6, o7);
  *(uint4*)(h1 + (size_t)i * 768 + c * 8) = O;
}

__global__ __launch_bounds__(256) void k_mlp3(
    const bf16_t* __restrict__ h2, const float* __restrict__ W3, const float* __restrict__ b3,
    float* __restrict__ out, int cn, int c0)
{
  int row = blockIdx.x * 4 + (threadIdx.x >> 6);
  if (row >= cn) return;
  int lane = threadIdx.x & 63;
  uint2 U = *(const uint2*)(h2 + (size_t)row * 256 + lane * 4);
  float v0 = bflo(U.x), v1 = bfhi(U.x), v2 = bflo(U.y), v3 = bfhi(U.y);
  const float* w = W3 + 8 * lane;
  float4 wa = *(const float4*)w;
  float4 wb = *(const float4*)(w + 4);
  float o0 = v0 * wa.x + v1 * wa.z + v2 * wb.x + v3 * wb.z;
  float o1 = v0 * wa.y + v1 * wa.w + v2 * wb.y + v3 * wb.w;
  o0 = wred_sum(o0);
  o1 = wred_sum(o1);
  if (!lane) {
    out[(size_t)(c0 + row) * 2]     = o0 + b3[0];
    out[(size_t)(c0 + row) * 2 + 1] = o1 + b3[1];
  }
}

// ================= host =================
extern "C" void kernel_launch(void* const* d_in, const int* in_sizes, int n_in,
                              void* d_out, int out_size, void* d_ws, size_t ws_size,
                              hipStream_t stream)
{
  (void)in_sizes; (void)n_in; (void)out_size;
  const float* drug_emb    = (const float*)d_in[0];
  const float* protein_emb = (const float*)d_in[1];
  const float* cell_emb    = (const float*)d_in[2];
  // internal rel order: 0=dp, 1=pp, 2=cp, 3=rdp, 4=rcp
  const int base_idx[5] = {3, 11, 15, 7, 19};
  const float *W_[5], *as_[5], *ad_[5], *b_[5];
  for (int r = 0; r < 5; ++r) {
    W_[r]  = (const float*)d_in[base_idx[r]];
    as_[r] = (const float*)d_in[base_idx[r] + 1];
    ad_[r] = (const float*)d_in[base_idx[r] + 2];
    b_[r]  = (const float*)d_in[base_idx[r] + 3];
  }
  const float* W1 = (const float*)d_in[23]; const float* b1 = (const float*)d_in[24];
  const float* W2 = (const float*)d_in[25]; const float* b2 = (const float*)d_in[26];
  const float* W3 = (const float*)d_in[27]; const float* b3 = (const float*)d_in[28];
  const int* src_dp = (const int*)d_in[29]; const int* dst_dp = (const int*)d_in[30];
  const int* src_pp = (const int*)d_in[31]; const int* dst_pp = (const int*)d_in[32];
  const int* src_cp = (const int*)d_in[33]; const int* dst_cp = (const int*)d_in[34];
  const int* drug1  = (const int*)d_in[35]; const int* drug2  = (const int*)d_in[36];
  const int* cellb  = (const int*)d_in[37];
  float* out = (float*)d_out;

  char* wsb = (char*)d_ws;
  size_t off = 0;
  auto alloc = [&](size_t bytes) -> void* {
    void* p = wsb + off;
    off += (bytes + 255) & ~(size_t)255;
    return p;
  };
  bf16_t* xdb[2] = {(bf16_t*)alloc((size_t)ND * H * 2),  (bf16_t*)alloc((size_t)ND * H * 2)};
  bf16_t* xpb[2] = {(bf16_t*)alloc((size_t)NPN * H * 2), (bf16_t*)alloc((size_t)NPN * H * 2)};
  bf16_t* xcb[2] = {(bf16_t*)alloc((size_t)NCN * H * 2), (bf16_t*)alloc((size_t)NCN * H * 2)};
  const int Msrc[5] = {ND, NPN, NCN, NPN, NPN};
  const int Mdst[5] = {NPN, NPN, NPN, ND, NCN};
  const int Erel[5] = {E_DP, E_PP + NPN, E_CP, E_DP, E_CP};
  bf16_t* yp = (bf16_t*)alloc((size_t)NPN * 384 * 2);
  bf16_t* yd = (bf16_t*)alloc((size_t)ND * H * 2);
  bf16_t* yc = (bf16_t*)alloc((size_t)NCN * H * 2);
  bf16_t* Wtp = (bf16_t*)alloc((size_t)NLAYERS * 128 * 384 * 2);
  bf16_t* Wtd = (bf16_t*)alloc((size_t)NLAYERS * 128 * 128 * 2);
  bf16_t* Wtc = (bf16_t*)alloc((size_t)NLAYERS * 128 * 128 * 2);
  bf16_t* W1t = (bf16_t*)alloc((size_t)768 * 384 * 2);
  bf16_t* W2t = (bf16_t*)alloc((size_t)256 * 768 * 2);
  float* wvb = (float*)alloc(20 * H * 4);
  float* ssb[5]; for (int r = 0; r < 5; ++r) ssb[r] = (float*)alloc((size_t)Msrc[r] * 4);
  float* sdb[5]; for (int r = 0; r < 5; ++r) sdb[r] = (float*)alloc((size_t)Mdst[r] * 4);
  int* cnt_all = (int*)alloc(62000 * 4);
  int* cur_all = (int*)alloc(62000 * 4);
  int* st_all  = (int*)alloc((62000 + 5) * 4);
  int *cntb[5], *curb[5], *stb[5];
  { int o = 0, o2 = 0;
    for (int r = 0; r < 5; ++r) {
      cntb[r] = cnt_all + o; curb[r] = cur_all + o; stb[r] = st_all + o2;
      o += Mdst[r]; o2 += Mdst[r] + 1;
    } }
  int* csrb[5]; for (int r = 0; r < 5; ++r) csrb[r] = (int*)alloc((size_t)Erel[r] * 4);
  bf16_t* xdn = (bf16_t*)alloc((size_t)ND * H * 2);
  bf16_t* xcn = (bf16_t*)alloc((size_t)NCN * H * 2);
  float* P1a = (float*)alloc((size_t)ND * 768 * 4);
  float* P1b = (float*)alloc((size_t)ND * 768 * 4);
  float* P1c = (float*)alloc((size_t)NCN * 768 * 4);
  size_t fixed_end = off;
  size_t avail = ws_size > fixed_end ? ws_size - fixed_end : 0;
  long long cmax = (long long)avail / 2048;
  int CH = cmax > NB ? NB : (int)cmax;
  CH &= ~255;
  if (CH < 256) CH = 256;
  bf16_t* h1 = (bf16_t*)alloc((size_t)CH * 768 * 2);
  bf16_t* h2 = (bf16_t*)alloc((size_t)CH * 256 * 2);

  // conversions
  k_conv_emb<<<(ND * H + NPN * H + NCN * H + 255) / 256, 256, 0, stream>>>(
      drug_emb, protein_emb, cell_emb, xdb[0], xpb[0], xcb[0]);
  TC tc;
  for (int l = 0; l < 2; ++l) {
    for (int r = 0; r < 3; ++r) {
      int m = l * 3 + r;
      tc.src[m] = W_[r] + (size_t)l * H * H;
      tc.dst[m] = Wtp + (size_t)l * 128 * 384;
      tc.Ksub[m] = 128; tc.N[m] = 128; tc.Kfull[m] = 384; tc.koff[m] = r * 128;
    }
    tc.src[6 + l] = W_[3] + (size_t)l * H * H; tc.dst[6 + l] = Wtd + (size_t)l * 128 * 128;
    tc.Ksub[6 + l] = 128; tc.N[6 + l] = 128; tc.Kfull[6 + l] = 128; tc.koff[6 + l] = 0;
    tc.src[8 + l] = W_[4] + (size_t)l * H * H; tc.dst[8 + l] = Wtc + (size_t)l * 128 * 128;
    tc.Ksub[8 + l] = 128; tc.N[8 + l] = 128; tc.Kfull[8 + l] = 128; tc.koff[8 + l] = 0;
  }
  tc.src[10] = W1; tc.dst[10] = W1t; tc.Ksub[10] = 384; tc.N[10] = 768; tc.Kfull[10] = 384; tc.koff[10] = 0;
  tc.src[11] = W2; tc.dst[11] = W2t; tc.Ksub[11] = 768; tc.N[11] = 256; tc.Kfull[11] = 768; tc.koff[11] = 0;
  k_tconv2<<<dim3(24, 24, 12), 256, 0, stream>>>(tc);

  // wv for both layers (independent of x)
  Wd20 wg;
  for (int l = 0; l < 2; ++l)
    for (int r = 0; r < 5; ++r) {
      int m = l * 10 + r;
      wg.W[m] = W_[r] + (size_t)l * H * H; wg.a[m] = as_[r] + l * H; wg.o[m] = wvb + m * H;
      int m2 = l * 10 + 5 + r;
      wg.W[m2] = W_[r] + (size_t)l * H * H; wg.a[m2] = ad_[r] + l * H; wg.o[m2] = wvb + m2 * H;
    }
  k_wd20<<<20, 128, 0, stream>>>(wg);

  // CSR build
  hipMemsetAsync(cnt_all, 0, 62000 * 4, stream);
  CsrArgs ca;
  const int* srcA[5] = {src_dp, src_pp, src_cp, dst_dp, dst_cp};
  const int* dstA[5] = {dst_dp, dst_pp, dst_cp, src_dp, src_cp};
  const int loopb[5] = {0x7fffffff, E_PP, 0x7fffffff, 0x7fffffff, 0x7fffffff};
  for (int r = 0; r < 5; ++r) {
    ca.src[r] = srcA[r]; ca.dst[r] = dstA[r]; ca.E[r] = Erel[r];
    ca.loopbase[r] = loopb[r]; ca.n[r] = Mdst[r];
    ca.cnt[r] = cntb[r]; ca.cur[r] = curb[r]; ca.starts[r] = stb[r]; ca.csr[r] = csrb[r];
  }
  dim3 egrid((E_PP + NPN + 255) / 256, 5);
  k_count5<<<egrid, 256, 0, stream>>>(ca);
  k_scan5<<<5, 256, 0, stream>>>(ca);
  k_fill5<<<egrid, 256, 0, stream>>>(ca);

  int cur = 0;
  for (int l = 0; l < NLAYERS; ++l) {
    int nxt = 1 - cur;
    const bf16_t* xsrc[5] = {xdb[cur], xpb[cur], xcb[cur], xpb[cur], xpb[cur]};
    Sc sc;
    sc.xd = xdb[cur]; sc.xp = xpb[cur]; sc.xc = xcb[cur]; sc.wv = wvb + l * 10 * H;
    for (int r = 0; r < 5; ++r) { sc.ss[r] = ssb[r]; sc.sd[r] = sdb[r]; }
    k_scores<<<(ND + NPN + NCN + 3) / 4, 256, 0, stream>>>(sc);
    Agg5 aa;
    bf16_t* yptr[5] = {yp, yp, yp, yd, yc};
    const int ystr[5] = {384, 384, 384, 128, 128};
    const int ycof[5] = {0, 128, 256, 0, 0};
    for (int r = 0; r < 5; ++r) {
      aa.csr[r] = csrb[r]; aa.starts[r] = stb[r]; aa.ss[r] = ssb[r]; aa.sd[r] = sdb[r];
      aa.xs[r] = xsrc[r]; aa.y[r] = yptr[r]; aa.ystride[r] = ystr[r]; aa.ycoff[r] = ycof[r];
      aa.ndst[r] = Mdst[r];
    }
    k_agg5<<<dim3((NPN + 3) / 4, 5), 256, 0, stream>>>(aa);
    Gemm3 g3;
    g3.j[0] = {yp, Wtp + (size_t)l * 128 * 384, xpb[nxt], NPN, 384,
               b_[0] + l * H, b_[1] + l * H, b_[2] + l * H};
    g3.j[1] = {yd, Wtd + (size_t)l * 128 * 128, xdb[nxt], ND, 128,
               b_[3] + l * H, nullptr, nullptr};
    g3.j[2] = {yc, Wtc + (size_t)l * 128 * 128, xcb[nxt], NCN, 128,
               b_[4] + l * H, nullptr, nullptr};
    k_gemm_g3<<<dim3((NPN + 127) / 128, 3), 256, 0, stream>>>(g3);
    cur = nxt;
  }

  // head: normalized tables -> slice GEMMs -> pair gather-add -> MLP
  k_normw<<<(ND + NCN + 3) / 4, 256, 0, stream>>>(xdb[cur], xcb[cur], xdn, xcn);
  GemmPS ps;
  ps.Bt = W1t;
  ps.j[0] = {xdn, P1a, ND};
  ps.j[1] = {xdn, P1b, ND};
  ps.j[2] = {xcn, P1c, NCN};
  k_gemm_ps<<<dim3(32 * 6, 3), 256, 0, stream>>>(ps);
  for (int c0 = 0; c0 < NB; c0 += CH) {
    int cn = (NB - c0 < CH) ? (NB - c0) : CH;
    k_pairsum<<<((size_t)cn * 96 + 255) / 256, 256, 0, stream>>>(
        P1a, P1b, P1c, b1, drug1, drug2, cellb, h1, c0, cn);
    k_gemm_bf<<<dim3((cn + 127) / 128, 2), 256, 0, stream>>>(h1, W2t, h2, cn, 256, 768, b2, 1);
    k_mlp3<<<(cn + 3) / 4, 256, 0, stream>>>(h2, W3, b3, out, cn, c0);
  }
}

// Round 6
// 443.138 us; speedup vs baseline: 1.2314x; 1.0938x over previous
//
#include <hip/hip_runtime.h>
#include <hip/hip_bf16.h>

#define H 128
#define ND 4000
#define NPN 19000
#define NCN 1000
#define NLAYERS 2
#define NB 30000
#define E_DP 200000
#define E_PP 300000
#define E_CP 150000

typedef __bf16 bf16_t;
typedef bf16_t bf16x8 __attribute__((ext_vector_type(8)));
typedef float f32x4 __attribute__((ext_vector_type(4)));
typedef unsigned short u16;

static __device__ __forceinline__ float wred_sum(float v) {
#pragma unroll
  for (int off = 32; off; off >>= 1) v += __shfl_xor(v, off);
  return v;
}
static __device__ __forceinline__ float bflo(unsigned u) { return __uint_as_float(u << 16); }
static __device__ __forceinline__ float bfhi(unsigned u) { return __uint_as_float(u & 0xffff0000u); }
static __device__ __forceinline__ unsigned packbf(float v0, float v1) {
  union { bf16_t b; unsigned short u; } a, b;
  a.b = (bf16_t)v0; b.b = (bf16_t)v1;
  return (unsigned)a.u | ((unsigned)b.u << 16);
}

// async global->LDS, 16B per lane
#define GLDS16(gp, lp) \
  __builtin_amdgcn_global_load_lds((__attribute__((address_space(1))) void*)(gp), \
                                   (__attribute__((address_space(3))) void*)(lp), 16, 0, 0)

// ================= MFMA GEMM core (fills acc; epilogue is per-kernel) =================
// A [M,K] bf16 (lda=K), Bt rows at stride ldb, uses cols 0..K. 128x128 tile, BK=32.
__device__ __forceinline__ void mfma_core(
    const bf16_t* __restrict__ A, const bf16_t* __restrict__ Bt,
    int M, int K, int ldb, int m0, int n0, f32x4 (&acc)[4][4])
{
  __shared__ char As[128 * 64];
  __shared__ char Bs[128 * 64];
  const int t = threadIdx.x;
  const int lane = t & 63;
#pragma unroll
  for (int mi = 0; mi < 4; ++mi)
#pragma unroll
    for (int ni = 0; ni < 4; ++ni) acc[mi][ni] = (f32x4){0.f, 0.f, 0.f, 0.f};

  const int wid = t >> 6;
  const int wr = wid >> 1, wc = wid & 1;
  const int sr = t >> 2;
  const int sc = t & 3;
  const int csrc = ((sc ^ ((sr >> 1) & 3)) << 4);
  int ra0 = m0 + sr;      if (ra0 >= M) ra0 = M - 1;
  int ra1 = m0 + 64 + sr; if (ra1 >= M) ra1 = M - 1;
  const char* gA0 = (const char*)A + (size_t)ra0 * K * 2 + csrc;
  const char* gA1 = (const char*)A + (size_t)ra1 * K * 2 + csrc;
  const char* gB0 = (const char*)Bt + (size_t)(n0 + sr) * ldb * 2 + csrc;
  const char* gB1 = (const char*)Bt + (size_t)(n0 + 64 + sr) * ldb * 2 + csrc;
  char* lA0 = As + t * 16;
  char* lA1 = As + 4096 + t * 16;
  char* lB0 = Bs + t * 16;
  char* lB1 = Bs + 4096 + t * 16;

  int aoff[4], boff[4];
#pragma unroll
  for (int mi = 0; mi < 4; ++mi) {
    int r = wr * 64 + mi * 16 + (lane & 15);
    aoff[mi] = r * 64 + ((((lane >> 4)) ^ ((r >> 1) & 3)) << 4);
  }
#pragma unroll
  for (int ni = 0; ni < 4; ++ni) {
    int r = wc * 64 + ni * 16 + (lane & 15);
    boff[ni] = r * 64 + ((((lane >> 4)) ^ ((r >> 1) & 3)) << 4);
  }

  for (int k0 = 0; k0 < K; k0 += 32) {
    const size_t kb = (size_t)k0 * 2;
    __syncthreads();
    GLDS16(gA0 + kb, lA0);
    GLDS16(gA1 + kb, lA1);
    GLDS16(gB0 + kb, lB0);
    GLDS16(gB1 + kb, lB1);
    __syncthreads();
    bf16x8 av[4], bv[4];
#pragma unroll
    for (int mi = 0; mi < 4; ++mi) av[mi] = *(const bf16x8*)(As + aoff[mi]);
#pragma unroll
    for (int ni = 0; ni < 4; ++ni) bv[ni] = *(const bf16x8*)(Bs + boff[ni]);
#pragma unroll
    for (int mi = 0; mi < 4; ++mi)
#pragma unroll
      for (int ni = 0; ni < 4; ++ni)
        acc[mi][ni] = __builtin_amdgcn_mfma_f32_16x16x32_bf16(av[mi], bv[ni], acc[mi][ni], 0, 0, 0);
  }
}

// --- GAT dst-side transform: C = relu(y @ Wt + biases), bf16 out, N=128 ---
struct GJob { const bf16_t* A; const bf16_t* Bt; bf16_t* C; int M; int K;
              const float *b1, *b2, *b3; };
struct Gemm3 { GJob j[3]; };
__global__ __launch_bounds__(256) void k_gemm_g3(Gemm3 g) {
  const GJob& jb = g.j[blockIdx.y];
  int m0 = blockIdx.x * 128;
  if (m0 >= jb.M) return;
  f32x4 acc[4][4];
  mfma_core(jb.A, jb.Bt, jb.M, jb.K, jb.K, m0, 0, acc);
  const int t = threadIdx.x, lane = t & 63, wid = t >> 6;
  const int wr = wid >> 1, wc = wid & 1;
  const int col0 = lane & 15, rsub = (lane >> 4) * 4;
#pragma unroll
  for (int mi = 0; mi < 4; ++mi) {
#pragma unroll
    for (int ni = 0; ni < 4; ++ni) {
      int c = wc * 64 + ni * 16 + col0;
      float bb = jb.b1[c];
      if (jb.b2) bb += jb.b2[c];
      if (jb.b3) bb += jb.b3[c];
#pragma unroll
      for (int rg = 0; rg < 4; ++rg) {
        int r = m0 + wr * 64 + mi * 16 + rsub + rg;
        if (r < jb.M) jb.C[(size_t)r * H + c] = (bf16_t)fmaxf(acc[mi][ni][rg] + bb, 0.f);
      }
    }
  }
}

// --- head slice GEMMs: P = (x @ W1slice) * rowscale, f32 out, N=768, K=128, ldb=384 ---
struct PJob { const bf16_t* A; float* C; int M; const float* rs; };
struct GemmPS { PJob j[3]; const bf16_t* Bt; };
__global__ __launch_bounds__(256) void k_gemm_ps(GemmPS g) {
  const PJob& jb = g.j[blockIdx.y];
  int mt = blockIdx.x / 6, nt = blockIdx.x - mt * 6;
  int m0 = mt * 128;
  if (m0 >= jb.M) return;
  int n0 = nt * 128;
  f32x4 acc[4][4];
  mfma_core(jb.A, g.Bt + blockIdx.y * 128, jb.M, 128, 384, m0, n0, acc);
  const int t = threadIdx.x, lane = t & 63, wid = t >> 6;
  const int wr = wid >> 1, wc = wid & 1;
  const int col0 = lane & 15, rsub = (lane >> 4) * 4;
#pragma unroll
  for (int mi = 0; mi < 4; ++mi) {
#pragma unroll
    for (int rg = 0; rg < 4; ++rg) {
      int r = m0 + wr * 64 + mi * 16 + rsub + rg;
      if (r < jb.M) {
        float sc = jb.rs[r];
#pragma unroll
        for (int ni = 0; ni < 4; ++ni) {
          int c = n0 + wc * 64 + ni * 16 + col0;
          jb.C[(size_t)r * 768 + c] = acc[mi][ni][rg] * sc;
        }
      }
    }
  }
}

// --- W2 GEMM with fused relu + W3 projection -> atomicAdd into out ---
__global__ __launch_bounds__(256) void k_gemm_w2o(
    const bf16_t* __restrict__ h1, const bf16_t* __restrict__ W2t,
    const float* __restrict__ b2, const float* __restrict__ W3, const float* __restrict__ b3,
    float* __restrict__ out, int cn, int c0)
{
  int m0 = blockIdx.x * 128;
  int n0 = blockIdx.y * 128;
  if (m0 >= cn) return;
  f32x4 acc[4][4];
  mfma_core(h1, W2t, cn, 768, 768, m0, n0, acc);
  const int t = threadIdx.x, lane = t & 63, wid = t >> 6;
  const int wr = wid >> 1, wc = wid & 1;
  const int col0 = lane & 15, rsub = (lane >> 4) * 4;
  float w0[4], w1[4], bb[4];
#pragma unroll
  for (int ni = 0; ni < 4; ++ni) {
    int c = n0 + wc * 64 + ni * 16 + col0;
    w0[ni] = W3[2 * c]; w1[ni] = W3[2 * c + 1]; bb[ni] = b2[c];
  }
  const int addb = (n0 == 0 && wc == 0);
#pragma unroll
  for (int mi = 0; mi < 4; ++mi) {
#pragma unroll
    for (int rg = 0; rg < 4; ++rg) {
      int r = m0 + wr * 64 + mi * 16 + rsub + rg;
      float p0 = 0.f, p1 = 0.f;
#pragma unroll
      for (int ni = 0; ni < 4; ++ni) {
        float v = fmaxf(acc[mi][ni][rg] + bb[ni], 0.f);
        p0 = fmaf(v, w0[ni], p0);
        p1 = fmaf(v, w1[ni], p1);
      }
#pragma unroll
      for (int off = 1; off < 16; off <<= 1) {
        p0 += __shfl_xor(p0, off);
        p1 += __shfl_xor(p1, off);
      }
      if (col0 == 0 && r < cn) {
        if (addb) { p0 += b3[0]; p1 += b3[1]; }
        atomicAdd(&out[(size_t)(c0 + r) * 2], p0);
        atomicAdd(&out[(size_t)(c0 + r) * 2 + 1], p1);
      }
    }
  }
}

// ================= conversions =================
__global__ __launch_bounds__(256) void k_conv_emb(
    const float* __restrict__ xd, const float* __restrict__ xp, const float* __restrict__ xc,
    bf16_t* __restrict__ od, bf16_t* __restrict__ op, bf16_t* __restrict__ oc)
{
  int i = blockIdx.x * 256 + threadIdx.x;
  const int SD = ND * H, SP = NPN * H, SC = NCN * H;
  if (i < SD) od[i] = (bf16_t)xd[i];
  else if (i < SD + SP) op[i - SD] = (bf16_t)xp[i - SD];
  else if (i < SD + SP + SC) oc[i - SD - SP] = (bf16_t)xc[i - SD - SP];
}

// LDS-tiled transpose-convert: dst[n*Kfull+koff+k] = bf16(src[k*N+n])
struct TC { const float* src[12]; bf16_t* dst[12]; int Ksub[12]; int N[12]; int Kfull[12]; int koff[12]; };
__global__ __launch_bounds__(256) void k_tconv2(TC a) {
  int m = blockIdx.z;
  int Ks = a.Ksub[m], N = a.N[m];
  int tx = blockIdx.x * 32;
  int ty = blockIdx.y * 32;
  if (tx >= N || ty >= Ks) return;
  __shared__ float tile[32][33];
  int c = threadIdx.x & 31, rr = threadIdx.x >> 5;
#pragma unroll
  for (int kk = rr; kk < 32; kk += 8)
    if (ty + kk < Ks && tx + c < N) tile[kk][c] = a.src[m][(size_t)(ty + kk) * N + tx + c];
  __syncthreads();
  bf16_t* dst = a.dst[m];
  int Kf = a.Kfull[m], ko = a.koff[m];
#pragma unroll
  for (int nn = rr; nn < 32; nn += 8)
    if (tx + nn < N && ty + c < Ks)
      dst[(size_t)(tx + nn) * Kf + ko + ty + c] = (bf16_t)tile[c][nn];
}

// ---------------- wv = W @ a : both layers, 20 matvecs ----------------
struct Wd20 { const float* W[20]; const float* a[20]; float* o[20]; };
__global__ __launch_bounds__(128) void k_wd20(Wd20 g) {
  int m = blockIdx.x;
  int k = threadIdx.x;
  const float* Wp = g.W[m];
  const float* av = g.a[m];
  float s = 0.f;
#pragma unroll 4
  for (int j = 0; j < H; ++j) s = fmaf(Wp[k * H + j], av[j], s);
  g.o[m][k] = s;
}

// ---------------- fused node scores ----------------
struct Sc { const bf16_t* xd; const bf16_t* xp; const bf16_t* xc; const float* wv;
            float* ss[5]; float* sd[5]; };
__global__ __launch_bounds__(256) void k_scores(Sc S) {
  int row = blockIdx.x * 4 + (threadIdx.x >> 6);
  if (row >= ND + NPN + NCN) return;
  int lane = threadIdx.x & 63;
  const bf16_t* x;
  int idx, cls;
  if (row < ND) { x = S.xd; idx = row; cls = 0; }
  else if (row < ND + NPN) { x = S.xp; idx = row - ND; cls = 1; }
  else { x = S.xc; idx = row - ND - NPN; cls = 2; }
  unsigned u = *(const unsigned*)(x + (size_t)idx * H + lane * 2);
  float x0 = bflo(u), x1 = bfhi(u);
  const float* wv = S.wv;
#define DOT(vi, outp) { const float* v = wv + (vi) * H; \
    float s = x0 * v[2 * lane] + x1 * v[2 * lane + 1]; s = wred_sum(s); \
    if (!lane) (outp)[idx] = s; }
  if (cls == 0) {
    DOT(0, S.ss[0]); DOT(8, S.sd[3]);
  } else if (cls == 1) {
    DOT(1, S.ss[1]); DOT(3, S.ss[3]); DOT(4, S.ss[4]);
    DOT(5, S.sd[0]); DOT(6, S.sd[1]); DOT(7, S.sd[2]);
  } else {
    DOT(2, S.ss[2]); DOT(9, S.sd[4]);
  }
#undef DOT
}

// ---------------- CSR build (u16 payload) ----------------
struct CsrArgs {
  const int* src[5]; const int* dst[5];
  int E[5]; int n[5];
  int* cnt[5]; int* cur[5]; int* starts[5]; u16* csr[5];
};
__global__ __launch_bounds__(256) void k_count5(CsrArgs a) {
  int rel = blockIdx.y;
  int e = blockIdx.x * 256 + threadIdx.x;
  if (e >= a.E[rel]) return;
  atomicAdd(&a.cnt[rel][a.dst[rel][e]], 1);
}
__global__ __launch_bounds__(1024) void k_scan5(CsrArgs a) {
  int rel = blockIdx.x;
  int n = a.n[rel];
  const int* cnt = a.cnt[rel];
  int* st = a.starts[rel];
  int* cu = a.cur[rel];
  int t = threadIdx.x;
  int stripe = (n + 1023) / 1024;
  int lo = t * stripe;
  int hi = lo + stripe; if (hi > n) hi = n;
  int s = 0;
  for (int i = lo; i < hi; ++i) s += cnt[i];
  // hierarchical inclusive scan of s over 1024 threads
  int lane = t & 63, wv = t >> 6;
  int x = s;
#pragma unroll
  for (int off = 1; off < 64; off <<= 1) {
    int y = __shfl_up(x, off);
    if (lane >= off) x += y;
  }
  __shared__ int ws[16];
  if (lane == 63) ws[wv] = x;
  __syncthreads();
  if (t == 0) {
    int run = 0;
#pragma unroll
    for (int i = 0; i < 16; ++i) { int v = ws[i]; ws[i] = run; run += v; }
  }
  __syncthreads();
  int run = ws[wv] + x - s;   // exclusive prefix of this thread
  for (int i = lo; i < hi; ++i) { st[i] = run; cu[i] = run; run += cnt[i]; }
  if (t == 1023) st[n] = ws[15] + x;
}
__global__ __launch_bounds__(256) void k_fill5(CsrArgs a) {
  int rel = blockIdx.y;
  int e = blockIdx.x * 256 + threadIdx.x;
  if (e >= a.E[rel]) return;
  int d = a.dst[rel][e];
  int s = a.src[rel][e];
  int pos = atomicAdd(&a.cur[rel][d], 1);
  a.csr[rel][pos] = (u16)s;
}

// ---------------- GAT aggregate on RAW x; analytic pp self-loop ----------------
struct Agg5 {
  const u16* csr[5]; const int* starts[5];
  const float* ss[5]; const float* sd[5];
  const bf16_t* xs[5];
  bf16_t* y[5]; int ystride[5]; int ycoff[5]; int ndst[5]; int self[5];
};
__global__ __launch_bounds__(256) void k_agg5(Agg5 a) {
  int rel = blockIdx.y;
  int d = blockIdx.x * 4 + (threadIdx.x >> 6);
  if (d >= a.ndst[rel]) return;
  int lane = threadIdx.x & 63;
  int g = lane >> 4, j16 = lane & 15;
  bf16_t* yrow = a.y[rel] + (size_t)d * a.ystride[rel] + a.ycoff[rel];
  int s0 = a.starts[rel][d];
  int deg = a.starts[rel][d + 1] - s0;
  int selfa = a.self[rel];
  if (!deg && !selfa) {
    if (g == 0) *(uint4*)(yrow + j16 * 8) = make_uint4(0u, 0u, 0u, 0u);
    return;
  }
  const u16* cs = a.csr[rel] + s0;
  const float* ssp = a.ss[rel];
  const bf16_t* xsp = a.xs[rel];
  float sdv = a.sd[rel][d];
  float acc[8] = {0.f, 0.f, 0.f, 0.f, 0.f, 0.f, 0.f, 0.f};
  float ps = 0.f;
  for (int b = 0; b < deg; b += 16) {
#pragma unroll
    for (int u = 0; u < 4; ++u) {
      int i = b + u * 4 + g;
      float p = 0.f;
      uint4 U = make_uint4(0u, 0u, 0u, 0u);
      if (i < deg) {
        int s = cs[i];
        float e = ssp[s] + sdv; e = e > 0.f ? e : 0.2f * e;
        p = __expf(e);
        U = *(const uint4*)(xsp + (size_t)s * H + j16 * 8);
      }
      ps += p;
      acc[0] = fmaf(p, bflo(U.x), acc[0]); acc[1] = fmaf(p, bfhi(U.x), acc[1]);
      acc[2] = fmaf(p, bflo(U.y), acc[2]); acc[3] = fmaf(p, bfhi(U.y), acc[3]);
      acc[4] = fmaf(p, bflo(U.z), acc[4]); acc[5] = fmaf(p, bfhi(U.z), acc[5]);
      acc[6] = fmaf(p, bflo(U.w), acc[6]); acc[7] = fmaf(p, bfhi(U.w), acc[7]);
    }
  }
  if (selfa && g == 0) {   // pp self-loop: src == dst, added once (group 0 only)
    float e = ssp[d] + sdv; e = e > 0.f ? e : 0.2f * e;
    float p = __expf(e);
    uint4 U = *(const uint4*)(xsp + (size_t)d * H + j16 * 8);
    ps += p;
    acc[0] = fmaf(p, bflo(U.x), acc[0]); acc[1] = fmaf(p, bfhi(U.x), acc[1]);
    acc[2] = fmaf(p, bflo(U.y), acc[2]); acc[3] = fmaf(p, bfhi(U.y), acc[3]);
    acc[4] = fmaf(p, bflo(U.z), acc[4]); acc[5] = fmaf(p, bfhi(U.z), acc[5]);
    acc[6] = fmaf(p, bflo(U.w), acc[6]); acc[7] = fmaf(p, bfhi(U.w), acc[7]);
  }
#pragma unroll
  for (int e = 0; e < 8; ++e) {
    acc[e] += __shfl_xor(acc[e], 16);
    acc[e] += __shfl_xor(acc[e], 32);
  }
  ps += __shfl_xor(ps, 16);
  ps += __shfl_xor(ps, 32);
  if (g == 0) {
    float inv = 1.f / ps;
    uint4 O;
    O.x = packbf(acc[0] * inv, acc[1] * inv);
    O.y = packbf(acc[2] * inv, acc[3] * inv);
    O.z = packbf(acc[4] * inv, acc[5] * inv);
    O.w = packbf(acc[6] * inv, acc[7] * inv);
    *(uint4*)(yrow + j16 * 8) = O;
  }
}

// ---------------- readout ----------------
__global__ __launch_bounds__(256) void k_invnorm(
    const bf16_t* __restrict__ xd, const bf16_t* __restrict__ xc,
    float* __restrict__ invd, float* __restrict__ invc)
{
  int row = blockIdx.x * 4 + (threadIdx.x >> 6);
  if (row >= ND + NCN) return;
  int lane = threadIdx.x & 63;
  const bf16_t* x = (row < ND) ? xd + (size_t)row * H : xc + (size_t)(row - ND) * H;
  unsigned u = ((const unsigned*)x)[lane];
  float av = bflo(u), bv = bfhi(u);
  float s = wred_sum(av * av + bv * bv);
  if (!lane) {
    float nv = fmaxf(sqrtf(s), 1e-12f);
    if (row < ND) invd[row] = 1.f / nv; else invc[row - ND] = 1.f / nv;
  }
}

// h1 = relu(Pa[d1] + Pb[d2] + Pc[ce] + b1)  (tables f32, out bf16)
__global__ __launch_bounds__(256) void k_pairsum(
    const float* __restrict__ Pa, const float* __restrict__ Pb, const float* __restrict__ Pc,
    const float* __restrict__ b1,
    const int* __restrict__ d1, const int* __restrict__ d2, const int* __restrict__ ce,
    bf16_t* __restrict__ h1, int c0, int cn)
{
  int gid = blockIdx.x * 256 + threadIdx.x;
  if (gid >= cn * 96) return;
  int i = gid / 96, c = gid - i * 96;
  int gi = c0 + i;
  int ra = d1[gi], rb = d2[gi], rc = ce[gi];
  const float4* pa = (const float4*)(Pa + (size_t)ra * 768 + c * 8);
  const float4* pb = (const float4*)(Pb + (size_t)rb * 768 + c * 8);
  const float4* pc = (const float4*)(Pc + (size_t)rc * 768 + c * 8);
  const float4* bb = (const float4*)(b1 + c * 8);
  float4 s0 = pa[0], s1 = pa[1];
  float4 t0 = pb[0], t1 = pb[1];
  float4 u0 = pc[0], u1 = pc[1];
  float4 v0 = bb[0], v1 = bb[1];
  uint4 O;
  O.x = packbf(fmaxf(s0.x + t0.x + u0.x + v0.x, 0.f), fmaxf(s0.y + t0.y + u0.y + v0.y, 0.f));
  O.y = packbf(fmaxf(s0.z + t0.z + u0.z + v0.z, 0.f), fmaxf(s0.w + t0.w + u0.w + v0.w, 0.f));
  O.z = packbf(fmaxf(s1.x + t1.x + u1.x + v1.x, 0.f), fmaxf(s1.y + t1.y + u1.y + v1.y, 0.f));
  O.w = packbf(fmaxf(s1.z + t1.z + u1.z + v1.z, 0.f), fmaxf(s1.w + t1.w + u1.w + v1.w, 0.f));
  *(uint4*)(h1 + (size_t)i * 768 + c * 8) = O;
}

// ================= host =================
extern "C" void kernel_launch(void* const* d_in, const int* in_sizes, int n_in,
                              void* d_out, int out_size, void* d_ws, size_t ws_size,
                              hipStream_t stream)
{
  (void)in_sizes; (void)n_in;
  const float* drug_emb    = (const float*)d_in[0];
  const float* protein_emb = (const float*)d_in[1];
  const float* cell_emb    = (const float*)d_in[2];
  // internal rel order: 0=dp, 1=pp, 2=cp, 3=rdp, 4=rcp
  const int base_idx[5] = {3, 11, 15, 7, 19};
  const float *W_[5], *as_[5], *ad_[5], *b_[5];
  for (int r = 0; r < 5; ++r) {
    W_[r]  = (const float*)d_in[base_idx[r]];
    as_[r] = (const float*)d_in[base_idx[r] + 1];
    ad_[r] = (const float*)d_in[base_idx[r] + 2];
    b_[r]  = (const float*)d_in[base_idx[r] + 3];
  }
  const float* W1 = (const float*)d_in[23]; const float* b1 = (const float*)d_in[24];
  const float* W2 = (const float*)d_in[25]; const float* b2 = (const float*)d_in[26];
  const float* W3 = (const float*)d_in[27]; const float* b3 = (const float*)d_in[28];
  const int* src_dp = (const int*)d_in[29]; const int* dst_dp = (const int*)d_in[30];
  const int* src_pp = (const int*)d_in[31]; const int* dst_pp = (const int*)d_in[32];
  const int* src_cp = (const int*)d_in[33]; const int* dst_cp = (const int*)d_in[34];
  const int* drug1  = (const int*)d_in[35]; const int* drug2  = (const int*)d_in[36];
  const int* cellb  = (const int*)d_in[37];
  float* out = (float*)d_out;

  char* wsb = (char*)d_ws;
  size_t off = 0;
  auto alloc = [&](size_t bytes) -> void* {
    void* p = wsb + off;
    off += (bytes + 255) & ~(size_t)255;
    return p;
  };
  bf16_t* xdb[2] = {(bf16_t*)alloc((size_t)ND * H * 2),  (bf16_t*)alloc((size_t)ND * H * 2)};
  bf16_t* xpb[2] = {(bf16_t*)alloc((size_t)NPN * H * 2), (bf16_t*)alloc((size_t)NPN * H * 2)};
  bf16_t* xcb[2] = {(bf16_t*)alloc((size_t)NCN * H * 2), (bf16_t*)alloc((size_t)NCN * H * 2)};
  const int Msrc[5] = {ND, NPN, NCN, NPN, NPN};
  const int Mdst[5] = {NPN, NPN, NPN, ND, NCN};
  const int Erel[5] = {E_DP, E_PP, E_CP, E_DP, E_CP};
  bf16_t* yp = (bf16_t*)alloc((size_t)NPN * 384 * 2);
  bf16_t* yd = (bf16_t*)alloc((size_t)ND * H * 2);
  bf16_t* yc = (bf16_t*)alloc((size_t)NCN * H * 2);
  bf16_t* Wtp = (bf16_t*)alloc((size_t)NLAYERS * 128 * 384 * 2);
  bf16_t* Wtd = (bf16_t*)alloc((size_t)NLAYERS * 128 * 128 * 2);
  bf16_t* Wtc = (bf16_t*)alloc((size_t)NLAYERS * 128 * 128 * 2);
  bf16_t* W1t = (bf16_t*)alloc((size_t)768 * 384 * 2);
  bf16_t* W2t = (bf16_t*)alloc((size_t)256 * 768 * 2);
  float* wvb = (float*)alloc(20 * H * 4);
  float* ssb[5]; for (int r = 0; r < 5; ++r) ssb[r] = (float*)alloc((size_t)Msrc[r] * 4);
  float* sdb[5]; for (int r = 0; r < 5; ++r) sdb[r] = (float*)alloc((size_t)Mdst[r] * 4);
  int* cnt_all = (int*)alloc(62000 * 4);
  int* cur_all = (int*)alloc(62000 * 4);
  int* st_all  = (int*)alloc((62000 + 5) * 4);
  int *cntb[5], *curb[5], *stb[5];
  { int o = 0, o2 = 0;
    for (int r = 0; r < 5; ++r) {
      cntb[r] = cnt_all + o; curb[r] = cur_all + o; stb[r] = st_all + o2;
      o += Mdst[r]; o2 += Mdst[r] + 1;
    } }
  u16* csrb[5]; for (int r = 0; r < 5; ++r) csrb[r] = (u16*)alloc((size_t)Erel[r] * 2);
  float* invd = (float*)alloc(ND * 4);
  float* invc = (float*)alloc(NCN * 4);
  float* P1a = (float*)alloc((size_t)ND * 768 * 4);
  float* P1b = (float*)alloc((size_t)ND * 768 * 4);
  float* P1c = (float*)alloc((size_t)NCN * 768 * 4);
  size_t fixed_end = off;
  size_t avail = ws_size > fixed_end ? ws_size - fixed_end : 0;
  long long cmax = (long long)avail / 1536;
  int CH = cmax > NB ? NB : (int)cmax;
  CH &= ~255;
  if (CH < 256) CH = 256;
  bf16_t* h1 = (bf16_t*)alloc((size_t)CH * 768 * 2);

  // zero the output (fused head accumulates into it)
  hipMemsetAsync(out, 0, (size_t)out_size * 4, stream);

  // conversions
  k_conv_emb<<<(ND * H + NPN * H + NCN * H + 255) / 256, 256, 0, stream>>>(
      drug_emb, protein_emb, cell_emb, xdb[0], xpb[0], xcb[0]);
  TC tc;
  for (int l = 0; l < 2; ++l) {
    for (int r = 0; r < 3; ++r) {
      int m = l * 3 + r;
      tc.src[m] = W_[r] + (size_t)l * H * H;
      tc.dst[m] = Wtp + (size_t)l * 128 * 384;
      tc.Ksub[m] = 128; tc.N[m] = 128; tc.Kfull[m] = 384; tc.koff[m] = r * 128;
    }
    tc.src[6 + l] = W_[3] + (size_t)l * H * H; tc.dst[6 + l] = Wtd + (size_t)l * 128 * 128;
    tc.Ksub[6 + l] = 128; tc.N[6 + l] = 128; tc.Kfull[6 + l] = 128; tc.koff[6 + l] = 0;
    tc.src[8 + l] = W_[4] + (size_t)l * H * H; tc.dst[8 + l] = Wtc + (size_t)l * 128 * 128;
    tc.Ksub[8 + l] = 128; tc.N[8 + l] = 128; tc.Kfull[8 + l] = 128; tc.koff[8 + l] = 0;
  }
  tc.src[10] = W1; tc.dst[10] = W1t; tc.Ksub[10] = 384; tc.N[10] = 768; tc.Kfull[10] = 384; tc.koff[10] = 0;
  tc.src[11] = W2; tc.dst[11] = W2t; tc.Ksub[11] = 768; tc.N[11] = 256; tc.Kfull[11] = 768; tc.koff[11] = 0;
  k_tconv2<<<dim3(24, 24, 12), 256, 0, stream>>>(tc);

  // wv for both layers
  Wd20 wg;
  for (int l = 0; l < 2; ++l)
    for (int r = 0; r < 5; ++r) {
      int m = l * 10 + r;
      wg.W[m] = W_[r] + (size_t)l * H * H; wg.a[m] = as_[r] + l * H; wg.o[m] = wvb + m * H;
      int m2 = l * 10 + 5 + r;
      wg.W[m2] = W_[r] + (size_t)l * H * H; wg.a[m2] = ad_[r] + l * H; wg.o[m2] = wvb + m2 * H;
    }
  k_wd20<<<20, 128, 0, stream>>>(wg);

  // CSR build (u16; pp WITHOUT self-loops — handled analytically in agg)
  hipMemsetAsync(cnt_all, 0, 62000 * 4, stream);
  CsrArgs ca;
  const int* srcA[5] = {src_dp, src_pp, src_cp, dst_dp, dst_cp};
  const int* dstA[5] = {dst_dp, dst_pp, dst_cp, src_dp, src_cp};
  for (int r = 0; r < 5; ++r) {
    ca.src[r] = srcA[r]; ca.dst[r] = dstA[r]; ca.E[r] = Erel[r]; ca.n[r] = Mdst[r];
    ca.cnt[r] = cntb[r]; ca.cur[r] = curb[r]; ca.starts[r] = stb[r]; ca.csr[r] = csrb[r];
  }
  dim3 egrid((E_PP + 255) / 256, 5);
  k_count5<<<egrid, 256, 0, stream>>>(ca);
  k_scan5<<<5, 1024, 0, stream>>>(ca);
  k_fill5<<<egrid, 256, 0, stream>>>(ca);

  int cur = 0;
  for (int l = 0; l < NLAYERS; ++l) {
    int nxt = 1 - cur;
    const bf16_t* xsrc[5] = {xdb[cur], xpb[cur], xcb[cur], xpb[cur], xpb[cur]};
    Sc sc;
    sc.xd = xdb[cur]; sc.xp = xpb[cur]; sc.xc = xcb[cur]; sc.wv = wvb + l * 10 * H;
    for (int r = 0; r < 5; ++r) { sc.ss[r] = ssb[r]; sc.sd[r] = sdb[r]; }
    k_scores<<<(ND + NPN + NCN + 3) / 4, 256, 0, stream>>>(sc);
    Agg5 aa;
    bf16_t* yptr[5] = {yp, yp, yp, yd, yc};
    const int ystr[5] = {384, 384, 384, 128, 128};
    const int ycof[5] = {0, 128, 256, 0, 0};
    const int selfs[5] = {0, 1, 0, 0, 0};
    for (int r = 0; r < 5; ++r) {
      aa.csr[r] = csrb[r]; aa.starts[r] = stb[r]; aa.ss[r] = ssb[r]; aa.sd[r] = sdb[r];
      aa.xs[r] = xsrc[r]; aa.y[r] = yptr[r]; aa.ystride[r] = ystr[r]; aa.ycoff[r] = ycof[r];
      aa.ndst[r] = Mdst[r]; aa.self[r] = selfs[r];
    }
    k_agg5<<<dim3((NPN + 3) / 4, 5), 256, 0, stream>>>(aa);
    Gemm3 g3;
    g3.j[0] = {yp, Wtp + (size_t)l * 128 * 384, xpb[nxt], NPN, 384,
               b_[0] + l * H, b_[1] + l * H, b_[2] + l * H};
    g3.j[1] = {yd, Wtd + (size_t)l * 128 * 128, xdb[nxt], ND, 128,
               b_[3] + l * H, nullptr, nullptr};
    g3.j[2] = {yc, Wtc + (size_t)l * 128 * 128, xcb[nxt], NCN, 128,
               b_[4] + l * H, nullptr, nullptr};
    k_gemm_g3<<<dim3((NPN + 127) / 128, 3), 256, 0, stream>>>(g3);
    cur = nxt;
  }

  // head: inv-norms -> scaled slice GEMMs (P tables) -> pair gather-add -> fused W2+W3
  k_invnorm<<<(ND + NCN + 3) / 4, 256, 0, stream>>>(xdb[cur], xcb[cur], invd, invc);
  GemmPS ps;
  ps.Bt = W1t;
  ps.j[0] = {xdb[cur], P1a, ND, invd};
  ps.j[1] = {xdb[cur], P1b, ND, invd};
  ps.j[2] = {xcb[cur], P1c, NCN, invc};
  k_gemm_ps<<<dim3(32 * 6, 3), 256, 0, stream>>>(ps);
  for (int c0 = 0; c0 < NB; c0 += CH) {
    int cn = (NB - c0 < CH) ? (NB - c0) : CH;
    k_pairsum<<<((size_t)cn * 96 + 255) / 256, 256, 0, stream>>>(
        P1a, P1b, P1c, b1, drug1, drug2, cellb, h1, c0, cn);
    k_gemm_w2o<<<dim3((cn + 127) / 128, 2), 256, 0, stream>>>(
        h1, W2t, b2, W3, b3, out, cn, c0);
  }
}

// Round 7
// 418.251 us; speedup vs baseline: 1.3047x; 1.0595x over previous
//
#include <hip/hip_runtime.h>
#include <hip/hip_bf16.h>

#define H 128
#define ND 4000
#define NPN 19000
#define NCN 1000
#define NLAYERS 2
#define NB 30000
#define E_DP 200000
#define E_PP 300000
#define E_CP 150000

typedef __bf16 bf16_t;
typedef bf16_t bf16x8 __attribute__((ext_vector_type(8)));
typedef float f32x4 __attribute__((ext_vector_type(4)));
typedef unsigned short u16;

static __device__ __forceinline__ float wred_sum(float v) {
#pragma unroll
  for (int off = 32; off; off >>= 1) v += __shfl_xor(v, off);
  return v;
}
static __device__ __forceinline__ float bflo(unsigned u) { return __uint_as_float(u << 16); }
static __device__ __forceinline__ float bfhi(unsigned u) { return __uint_as_float(u & 0xffff0000u); }
static __device__ __forceinline__ unsigned packbf(float v0, float v1) {
  union { bf16_t b; unsigned short u; } a, b;
  a.b = (bf16_t)v0; b.b = (bf16_t)v1;
  return (unsigned)a.u | ((unsigned)b.u << 16);
}

// async global->LDS, 16B per lane
#define GLDS16(gp, lp) \
  __builtin_amdgcn_global_load_lds((__attribute__((address_space(1))) void*)(gp), \
                                   (__attribute__((address_space(3))) void*)(lp), 16, 0, 0)

// ================= MFMA GEMM core (fills acc; epilogue is per-kernel) =================
__device__ __forceinline__ void mfma_core(
    const bf16_t* __restrict__ A, const bf16_t* __restrict__ Bt,
    int M, int K, int ldb, int m0, int n0, f32x4 (&acc)[4][4])
{
  __shared__ char As[128 * 64];
  __shared__ char Bs[128 * 64];
  const int t = threadIdx.x;
  const int lane = t & 63;
#pragma unroll
  for (int mi = 0; mi < 4; ++mi)
#pragma unroll
    for (int ni = 0; ni < 4; ++ni) acc[mi][ni] = (f32x4){0.f, 0.f, 0.f, 0.f};

  const int wid = t >> 6;
  const int wr = wid >> 1, wc = wid & 1;
  const int sr = t >> 2;
  const int sc = t & 3;
  const int csrc = ((sc ^ ((sr >> 1) & 3)) << 4);
  int ra0 = m0 + sr;      if (ra0 >= M) ra0 = M - 1;
  int ra1 = m0 + 64 + sr; if (ra1 >= M) ra1 = M - 1;
  const char* gA0 = (const char*)A + (size_t)ra0 * K * 2 + csrc;
  const char* gA1 = (const char*)A + (size_t)ra1 * K * 2 + csrc;
  const char* gB0 = (const char*)Bt + (size_t)(n0 + sr) * ldb * 2 + csrc;
  const char* gB1 = (const char*)Bt + (size_t)(n0 + 64 + sr) * ldb * 2 + csrc;
  char* lA0 = As + t * 16;
  char* lA1 = As + 4096 + t * 16;
  char* lB0 = Bs + t * 16;
  char* lB1 = Bs + 4096 + t * 16;

  int aoff[4], boff[4];
#pragma unroll
  for (int mi = 0; mi < 4; ++mi) {
    int r = wr * 64 + mi * 16 + (lane & 15);
    aoff[mi] = r * 64 + ((((lane >> 4)) ^ ((r >> 1) & 3)) << 4);
  }
#pragma unroll
  for (int ni = 0; ni < 4; ++ni) {
    int r = wc * 64 + ni * 16 + (lane & 15);
    boff[ni] = r * 64 + ((((lane >> 4)) ^ ((r >> 1) & 3)) << 4);
  }

  for (int k0 = 0; k0 < K; k0 += 32) {
    const size_t kb = (size_t)k0 * 2;
    __syncthreads();
    GLDS16(gA0 + kb, lA0);
    GLDS16(gA1 + kb, lA1);
    GLDS16(gB0 + kb, lB0);
    GLDS16(gB1 + kb, lB1);
    __syncthreads();
    bf16x8 av[4], bv[4];
#pragma unroll
    for (int mi = 0; mi < 4; ++mi) av[mi] = *(const bf16x8*)(As + aoff[mi]);
#pragma unroll
    for (int ni = 0; ni < 4; ++ni) bv[ni] = *(const bf16x8*)(Bs + boff[ni]);
#pragma unroll
    for (int mi = 0; mi < 4; ++mi)
#pragma unroll
      for (int ni = 0; ni < 4; ++ni)
        acc[mi][ni] = __builtin_amdgcn_mfma_f32_16x16x32_bf16(av[mi], bv[ni], acc[mi][ni], 0, 0, 0);
  }
}

// --- GAT dst-side transform: C = relu(y @ Wt + biases), bf16 out, N=128 ---
struct GJob { const bf16_t* A; const bf16_t* Bt; bf16_t* C; int M; int K;
              const float *b1, *b2, *b3; };
struct Gemm3 { GJob j[3]; };
__global__ __launch_bounds__(256) void k_gemm_g3(Gemm3 g) {
  const GJob& jb = g.j[blockIdx.y];
  int m0 = blockIdx.x * 128;
  if (m0 >= jb.M) return;
  f32x4 acc[4][4];
  mfma_core(jb.A, jb.Bt, jb.M, jb.K, jb.K, m0, 0, acc);
  const int t = threadIdx.x, lane = t & 63, wid = t >> 6;
  const int wr = wid >> 1, wc = wid & 1;
  const int col0 = lane & 15, rsub = (lane >> 4) * 4;
#pragma unroll
  for (int mi = 0; mi < 4; ++mi) {
#pragma unroll
    for (int ni = 0; ni < 4; ++ni) {
      int c = wc * 64 + ni * 16 + col0;
      float bb = jb.b1[c];
      if (jb.b2) bb += jb.b2[c];
      if (jb.b3) bb += jb.b3[c];
#pragma unroll
      for (int rg = 0; rg < 4; ++rg) {
        int r = m0 + wr * 64 + mi * 16 + rsub + rg;
        if (r < jb.M) jb.C[(size_t)r * H + c] = (bf16_t)fmaxf(acc[mi][ni][rg] + bb, 0.f);
      }
    }
  }
}

// --- head slice GEMMs: P = (x @ W1slice) * rowscale, f32 out, N=768, K=128, ldb=384 ---
struct PJob { const bf16_t* A; float* C; int M; const float* rs; };
struct GemmPS { PJob j[3]; const bf16_t* Bt; };
__global__ __launch_bounds__(256) void k_gemm_ps(GemmPS g) {
  const PJob& jb = g.j[blockIdx.y];
  int mt = blockIdx.x / 6, nt = blockIdx.x - mt * 6;
  int m0 = mt * 128;
  if (m0 >= jb.M) return;
  int n0 = nt * 128;
  f32x4 acc[4][4];
  mfma_core(jb.A, g.Bt + blockIdx.y * 128, jb.M, 128, 384, m0, n0, acc);
  const int t = threadIdx.x, lane = t & 63, wid = t >> 6;
  const int wr = wid >> 1, wc = wid & 1;
  const int col0 = lane & 15, rsub = (lane >> 4) * 4;
#pragma unroll
  for (int mi = 0; mi < 4; ++mi) {
#pragma unroll
    for (int rg = 0; rg < 4; ++rg) {
      int r = m0 + wr * 64 + mi * 16 + rsub + rg;
      if (r < jb.M) {
        float sc = jb.rs[r];
#pragma unroll
        for (int ni = 0; ni < 4; ++ni) {
          int c = n0 + wc * 64 + ni * 16 + col0;
          jb.C[(size_t)r * 768 + c] = acc[mi][ni][rg] * sc;
        }
      }
    }
  }
}

// --- fused head: A-tile = relu(Pa[d1]+Pb[d2]+Pc[ce]+b1) built in-kernel;
//     GEMM vs W2t; epilogue fuses relu + W3 -> atomicAdd into out ---
__global__ __launch_bounds__(256) void k_w2head(
    const float* __restrict__ Pa, const float* __restrict__ Pb, const float* __restrict__ Pc,
    const float* __restrict__ b1,
    const int* __restrict__ d1, const int* __restrict__ d2, const int* __restrict__ ce,
    const bf16_t* __restrict__ W2t, const float* __restrict__ b2,
    const float* __restrict__ W3, const float* __restrict__ b3,
    float* __restrict__ out, int cn)
{
  __shared__ char As[128 * 64];
  __shared__ char Bs[128 * 64];
  const int t = threadIdx.x;
  const int lane = t & 63;
  const int m0 = blockIdx.x * 128;
  const int n0 = blockIdx.y * 128;
  if (m0 >= cn) return;
  f32x4 acc[4][4];
#pragma unroll
  for (int mi = 0; mi < 4; ++mi)
#pragma unroll
    for (int ni = 0; ni < 4; ++ni) acc[mi][ni] = (f32x4){0.f, 0.f, 0.f, 0.f};

  // A staging role: row = t>>1 (0..127), half h = t&1 (16 f32 = two 16B bf16 chunks)
  const int arow = t >> 1;
  const int ah = t & 1;
  int gr = m0 + arow; if (gr >= cn) gr = cn - 1;
  const float* pa = Pa + (size_t)d1[gr] * 768 + ah * 16;
  const float* pb = Pb + (size_t)d2[gr] * 768 + ah * 16;
  const float* pc = Pc + (size_t)ce[gr] * 768 + ah * 16;
  const int swz = (arow >> 1) & 3;
  char* la0 = As + arow * 64 + (((ah * 2)     ^ swz) << 4);
  char* la1 = As + arow * 64 + (((ah * 2 + 1) ^ swz) << 4);

  // B staging (global_load_lds, as mfma_core)
  const int sr = t >> 2;
  const int sc = t & 3;
  const int csrc = ((sc ^ ((sr >> 1) & 3)) << 4);
  const char* gB0 = (const char*)W2t + (size_t)(n0 + sr) * 768 * 2 + csrc;
  const char* gB1 = (const char*)W2t + (size_t)(n0 + 64 + sr) * 768 * 2 + csrc;
  char* lB0 = Bs + t * 16;
  char* lB1 = Bs + 4096 + t * 16;

  const int wid = t >> 6;
  const int wr = wid >> 1, wc = wid & 1;
  int aoff[4], boff[4];
#pragma unroll
  for (int mi = 0; mi < 4; ++mi) {
    int r = wr * 64 + mi * 16 + (lane & 15);
    aoff[mi] = r * 64 + ((((lane >> 4)) ^ ((r >> 1) & 3)) << 4);
  }
#pragma unroll
  for (int ni = 0; ni < 4; ++ni) {
    int r = wc * 64 + ni * 16 + (lane & 15);
    boff[ni] = r * 64 + ((((lane >> 4)) ^ ((r >> 1) & 3)) << 4);
  }

  for (int k0 = 0; k0 < 768; k0 += 32) {
    // gather + combine the A slice for this k-step (16 f32 per thread)
    const float4* qa = (const float4*)(pa + k0);
    const float4* qb = (const float4*)(pb + k0);
    const float4* qc = (const float4*)(pc + k0);
    const float4* qb1 = (const float4*)(b1 + k0 + ah * 16);
    float4 A0 = qa[0], A1 = qa[1], A2 = qa[2], A3 = qa[3];
    float4 B0 = qb[0], B1 = qb[1], B2 = qb[2], B3 = qb[3];
    float4 C0 = qc[0], C1 = qc[1], C2 = qc[2], C3 = qc[3];
    float4 D0 = qb1[0], D1 = qb1[1], D2 = qb1[2], D3 = qb1[3];
    uint4 P0, P1;
    P0.x = packbf(fmaxf(A0.x + B0.x + C0.x + D0.x, 0.f), fmaxf(A0.y + B0.y + C0.y + D0.y, 0.f));
    P0.y = packbf(fmaxf(A0.z + B0.z + C0.z + D0.z, 0.f), fmaxf(A0.w + B0.w + C0.w + D0.w, 0.f));
    P0.z = packbf(fmaxf(A1.x + B1.x + C1.x + D1.x, 0.f), fmaxf(A1.y + B1.y + C1.y + D1.y, 0.f));
    P0.w = packbf(fmaxf(A1.z + B1.z + C1.z + D1.z, 0.f), fmaxf(A1.w + B1.w + C1.w + D1.w, 0.f));
    P1.x = packbf(fmaxf(A2.x + B2.x + C2.x + D2.x, 0.f), fmaxf(A2.y + B2.y + C2.y + D2.y, 0.f));
    P1.y = packbf(fmaxf(A2.z + B2.z + C2.z + D2.z, 0.f), fmaxf(A2.w + B2.w + C2.w + D2.w, 0.f));
    P1.z = packbf(fmaxf(A3.x + B3.x + C3.x + D3.x, 0.f), fmaxf(A3.y + B3.y + C3.y + D3.y, 0.f));
    P1.w = packbf(fmaxf(A3.z + B3.z + C3.z + D3.z, 0.f), fmaxf(A3.w + B3.w + C3.w + D3.w, 0.f));
    __syncthreads();                         // all waves done reading prev tile
    GLDS16(gB0 + (size_t)k0 * 2, lB0);
    GLDS16(gB1 + (size_t)k0 * 2, lB1);
    *(uint4*)la0 = P0;
    *(uint4*)la1 = P1;
    __syncthreads();
    bf16x8 av[4], bv[4];
#pragma unroll
    for (int mi = 0; mi < 4; ++mi) av[mi] = *(const bf16x8*)(As + aoff[mi]);
#pragma unroll
    for (int ni = 0; ni < 4; ++ni) bv[ni] = *(const bf16x8*)(Bs + boff[ni]);
#pragma unroll
    for (int mi = 0; mi < 4; ++mi)
#pragma unroll
      for (int ni = 0; ni < 4; ++ni)
        acc[mi][ni] = __builtin_amdgcn_mfma_f32_16x16x32_bf16(av[mi], bv[ni], acc[mi][ni], 0, 0, 0);
  }

  const int col0 = lane & 15, rsub = (lane >> 4) * 4;
  float w0[4], w1[4], bb[4];
#pragma unroll
  for (int ni = 0; ni < 4; ++ni) {
    int c = n0 + wc * 64 + ni * 16 + col0;
    w0[ni] = W3[2 * c]; w1[ni] = W3[2 * c + 1]; bb[ni] = b2[c];
  }
  const int addb = (n0 == 0 && wc == 0);
#pragma unroll
  for (int mi = 0; mi < 4; ++mi) {
#pragma unroll
    for (int rg = 0; rg < 4; ++rg) {
      int r = m0 + wr * 64 + mi * 16 + rsub + rg;
      float p0 = 0.f, p1 = 0.f;
#pragma unroll
      for (int ni = 0; ni < 4; ++ni) {
        float v = fmaxf(acc[mi][ni][rg] + bb[ni], 0.f);
        p0 = fmaf(v, w0[ni], p0);
        p1 = fmaf(v, w1[ni], p1);
      }
#pragma unroll
      for (int off = 1; off < 16; off <<= 1) {
        p0 += __shfl_xor(p0, off);
        p1 += __shfl_xor(p1, off);
      }
      if (col0 == 0 && r < cn) {
        if (addb) { p0 += b3[0]; p1 += b3[1]; }
        atomicAdd(&out[(size_t)r * 2], p0);
        atomicAdd(&out[(size_t)r * 2 + 1], p1);
      }
    }
  }
}

// ================= conversions =================
__global__ __launch_bounds__(256) void k_conv_emb(
    const float* __restrict__ xd, const float* __restrict__ xp, const float* __restrict__ xc,
    bf16_t* __restrict__ od, bf16_t* __restrict__ op, bf16_t* __restrict__ oc)
{
  int i = blockIdx.x * 256 + threadIdx.x;
  const int SD = ND * H, SP = NPN * H, SC = NCN * H;
  if (i < SD) od[i] = (bf16_t)xd[i];
  else if (i < SD + SP) op[i - SD] = (bf16_t)xp[i - SD];
  else if (i < SD + SP + SC) oc[i - SD - SP] = (bf16_t)xc[i - SD - SP];
}

// LDS-tiled transpose-convert: dst[n*Kfull+koff+k] = bf16(src[k*N+n])
struct TC { const float* src[12]; bf16_t* dst[12]; int Ksub[12]; int N[12]; int Kfull[12]; int koff[12]; };
__global__ __launch_bounds__(256) void k_tconv2(TC a) {
  int m = blockIdx.z;
  int Ks = a.Ksub[m], N = a.N[m];
  int tx = blockIdx.x * 32;
  int ty = blockIdx.y * 32;
  if (tx >= N || ty >= Ks) return;
  __shared__ float tile[32][33];
  int c = threadIdx.x & 31, rr = threadIdx.x >> 5;
#pragma unroll
  for (int kk = rr; kk < 32; kk += 8)
    if (ty + kk < Ks && tx + c < N) tile[kk][c] = a.src[m][(size_t)(ty + kk) * N + tx + c];
  __syncthreads();
  bf16_t* dst = a.dst[m];
  int Kf = a.Kfull[m], ko = a.koff[m];
#pragma unroll
  for (int nn = rr; nn < 32; nn += 8)
    if (tx + nn < N && ty + c < Ks)
      dst[(size_t)(tx + nn) * Kf + ko + ty + c] = (bf16_t)tile[c][nn];
}

// ---------------- wv = W @ a : both layers, 20 matvecs ----------------
struct Wd20 { const float* W[20]; const float* a[20]; float* o[20]; };
__global__ __launch_bounds__(128) void k_wd20(Wd20 g) {
  int m = blockIdx.x;
  int k = threadIdx.x;
  const float* Wp = g.W[m];
  const float* av = g.a[m];
  float s = 0.f;
#pragma unroll 4
  for (int j = 0; j < H; ++j) s = fmaf(Wp[k * H + j], av[j], s);
  g.o[m][k] = s;
}

// ---------------- fused node scores ----------------
struct Sc { const bf16_t* xd; const bf16_t* xp; const bf16_t* xc; const float* wv;
            float* ss[5]; float* sd[5]; };
__global__ __launch_bounds__(256) void k_scores(Sc S) {
  int row = blockIdx.x * 4 + (threadIdx.x >> 6);
  if (row >= ND + NPN + NCN) return;
  int lane = threadIdx.x & 63;
  const bf16_t* x;
  int idx, cls;
  if (row < ND) { x = S.xd; idx = row; cls = 0; }
  else if (row < ND + NPN) { x = S.xp; idx = row - ND; cls = 1; }
  else { x = S.xc; idx = row - ND - NPN; cls = 2; }
  unsigned u = *(const unsigned*)(x + (size_t)idx * H + lane * 2);
  float x0 = bflo(u), x1 = bfhi(u);
  const float* wv = S.wv;
#define DOT(vi, outp) { const float* v = wv + (vi) * H; \
    float s = x0 * v[2 * lane] + x1 * v[2 * lane + 1]; s = wred_sum(s); \
    if (!lane) (outp)[idx] = s; }
  if (cls == 0) {
    DOT(0, S.ss[0]); DOT(8, S.sd[3]);
  } else if (cls == 1) {
    DOT(1, S.ss[1]); DOT(3, S.ss[3]); DOT(4, S.ss[4]);
    DOT(5, S.sd[0]); DOT(6, S.sd[1]); DOT(7, S.sd[2]);
  } else {
    DOT(2, S.ss[2]); DOT(9, S.sd[4]);
  }
#undef DOT
}

// ---------------- CSR build (u16 payload, 4-edge ILP) ----------------
struct CsrArgs {
  const int* src[5]; const int* dst[5];
  int E[5]; int n[5];
  int* cnt[5]; int* cur[5]; int* starts[5]; u16* csr[5];
};
__global__ __launch_bounds__(256) void k_count5(CsrArgs a) {
  int rel = blockIdx.y;
  int E = a.E[rel];
  const int* dst = a.dst[rel];
  int* cnt = a.cnt[rel];
  int e0 = blockIdx.x * 1024 + threadIdx.x;
#pragma unroll
  for (int u = 0; u < 4; ++u) {
    int e = e0 + u * 256;
    if (e < E) atomicAdd(&cnt[dst[e]], 1);
  }
}
__global__ __launch_bounds__(1024) void k_scan5(CsrArgs a) {
  int rel = blockIdx.x;
  int n = a.n[rel];
  const int* cnt = a.cnt[rel];
  int* st = a.starts[rel];
  int* cu = a.cur[rel];
  int t = threadIdx.x;
  int stripe = (n + 1023) / 1024;
  int lo = t * stripe;
  int hi = lo + stripe; if (hi > n) hi = n;
  int s = 0;
  for (int i = lo; i < hi; ++i) s += cnt[i];
  int lane = t & 63, wv = t >> 6;
  int x = s;
#pragma unroll
  for (int off = 1; off < 64; off <<= 1) {
    int y = __shfl_up(x, off);
    if (lane >= off) x += y;
  }
  __shared__ int ws[16];
  if (lane == 63) ws[wv] = x;
  __syncthreads();
  if (t == 0) {
    int run = 0;
#pragma unroll
    for (int i = 0; i < 16; ++i) { int v = ws[i]; ws[i] = run; run += v; }
  }
  __syncthreads();
  int run = ws[wv] + x - s;
  for (int i = lo; i < hi; ++i) { st[i] = run; cu[i] = run; run += cnt[i]; }
  if (t == 1023) st[n] = ws[15] + x;
}
__global__ __launch_bounds__(256) void k_fill5(CsrArgs a) {
  int rel = blockIdx.y;
  int E = a.E[rel];
  const int* dst = a.dst[rel];
  const int* src = a.src[rel];
  int* cur = a.cur[rel];
  u16* csr = a.csr[rel];
  int e0 = blockIdx.x * 1024 + threadIdx.x;
#pragma unroll
  for (int u = 0; u < 4; ++u) {
    int e = e0 + u * 256;
    if (e < E) {
      int pos = atomicAdd(&cur[dst[e]], 1);
      csr[pos] = (u16)src[e];
    }
  }
}

// ---------------- GAT aggregate on RAW x; analytic pp self-loop ----------------
struct Agg5 {
  const u16* csr[5]; const int* starts[5];
  const float* ss[5]; const float* sd[5];
  const bf16_t* xs[5];
  bf16_t* y[5]; int ystride[5]; int ycoff[5]; int ndst[5]; int self[5];
};
__global__ __launch_bounds__(256) void k_agg5(Agg5 a) {
  int rel = blockIdx.y;
  int d = blockIdx.x * 4 + (threadIdx.x >> 6);
  if (d >= a.ndst[rel]) return;
  int lane = threadIdx.x & 63;
  int g = lane >> 4, j16 = lane & 15;
  bf16_t* yrow = a.y[rel] + (size_t)d * a.ystride[rel] + a.ycoff[rel];
  int s0 = a.starts[rel][d];
  int deg = a.starts[rel][d + 1] - s0;
  int selfa = a.self[rel];
  if (!deg && !selfa) {
    if (g == 0) *(uint4*)(yrow + j16 * 8) = make_uint4(0u, 0u, 0u, 0u);
    return;
  }
  const u16* cs = a.csr[rel] + s0;
  const float* ssp = a.ss[rel];
  const bf16_t* xsp = a.xs[rel];
  float sdv = a.sd[rel][d];
  float acc[8] = {0.f, 0.f, 0.f, 0.f, 0.f, 0.f, 0.f, 0.f};
  float ps = 0.f;
  for (int b = 0; b < deg; b += 16) {
#pragma unroll
    for (int u = 0; u < 4; ++u) {
      int i = b + u * 4 + g;
      float p = 0.f;
      uint4 U = make_uint4(0u, 0u, 0u, 0u);
      if (i < deg) {
        int s = cs[i];
        float e = ssp[s] + sdv; e = e > 0.f ? e : 0.2f * e;
        p = __expf(e);
        U = *(const uint4*)(xsp + (size_t)s * H + j16 * 8);
      }
      ps += p;
      acc[0] = fmaf(p, bflo(U.x), acc[0]); acc[1] = fmaf(p, bfhi(U.x), acc[1]);
      acc[2] = fmaf(p, bflo(U.y), acc[2]); acc[3] = fmaf(p, bfhi(U.y), acc[3]);
      acc[4] = fmaf(p, bflo(U.z), acc[4]); acc[5] = fmaf(p, bfhi(U.z), acc[5]);
      acc[6] = fmaf(p, bflo(U.w), acc[6]); acc[7] = fmaf(p, bfhi(U.w), acc[7]);
    }
  }
  if (selfa && g == 0) {
    float e = ssp[d] + sdv; e = e > 0.f ? e : 0.2f * e;
    float p = __expf(e);
    uint4 U = *(const uint4*)(xsp + (size_t)d * H + j16 * 8);
    ps += p;
    acc[0] = fmaf(p, bflo(U.x), acc[0]); acc[1] = fmaf(p, bfhi(U.x), acc[1]);
    acc[2] = fmaf(p, bflo(U.y), acc[2]); acc[3] = fmaf(p, bfhi(U.y), acc[3]);
    acc[4] = fmaf(p, bflo(U.z), acc[4]); acc[5] = fmaf(p, bfhi(U.z), acc[5]);
    acc[6] = fmaf(p, bflo(U.w), acc[6]); acc[7] = fmaf(p, bfhi(U.w), acc[7]);
  }
#pragma unroll
  for (int e = 0; e < 8; ++e) {
    acc[e] += __shfl_xor(acc[e], 16);
    acc[e] += __shfl_xor(acc[e], 32);
  }
  ps += __shfl_xor(ps, 16);
  ps += __shfl_xor(ps, 32);
  if (g == 0) {
    float inv = 1.f / ps;
    uint4 O;
    O.x = packbf(acc[0] * inv, acc[1] * inv);
    O.y = packbf(acc[2] * inv, acc[3] * inv);
    O.z = packbf(acc[4] * inv, acc[5] * inv);
    O.w = packbf(acc[6] * inv, acc[7] * inv);
    *(uint4*)(yrow + j16 * 8) = O;
  }
}

// ---------------- readout ----------------
__global__ __launch_bounds__(256) void k_invnorm(
    const bf16_t* __restrict__ xd, const bf16_t* __restrict__ xc,
    float* __restrict__ invd, float* __restrict__ invc)
{
  int row = blockIdx.x * 4 + (threadIdx.x >> 6);
  if (row >= ND + NCN) return;
  int lane = threadIdx.x & 63;
  const bf16_t* x = (row < ND) ? xd + (size_t)row * H : xc + (size_t)(row - ND) * H;
  unsigned u = ((const unsigned*)x)[lane];
  float av = bflo(u), bv = bfhi(u);
  float s = wred_sum(av * av + bv * bv);
  if (!lane) {
    float nv = fmaxf(sqrtf(s), 1e-12f);
    if (row < ND) invd[row] = 1.f / nv; else invc[row - ND] = 1.f / nv;
  }
}

// ================= host =================
extern "C" void kernel_launch(void* const* d_in, const int* in_sizes, int n_in,
                              void* d_out, int out_size, void* d_ws, size_t ws_size,
                              hipStream_t stream)
{
  (void)in_sizes; (void)n_in;
  const float* drug_emb    = (const float*)d_in[0];
  const float* protein_emb = (const float*)d_in[1];
  const float* cell_emb    = (const float*)d_in[2];
  // internal rel order: 0=dp, 1=pp, 2=cp, 3=rdp, 4=rcp
  const int base_idx[5] = {3, 11, 15, 7, 19};
  const float *W_[5], *as_[5], *ad_[5], *b_[5];
  for (int r = 0; r < 5; ++r) {
    W_[r]  = (const float*)d_in[base_idx[r]];
    as_[r] = (const float*)d_in[base_idx[r] + 1];
    ad_[r] = (const float*)d_in[base_idx[r] + 2];
    b_[r]  = (const float*)d_in[base_idx[r] + 3];
  }
  const float* W1 = (const float*)d_in[23]; const float* b1 = (const float*)d_in[24];
  const float* W2 = (const float*)d_in[25]; const float* b2 = (const float*)d_in[26];
  const float* W3 = (const float*)d_in[27]; const float* b3 = (const float*)d_in[28];
  const int* src_dp = (const int*)d_in[29]; const int* dst_dp = (const int*)d_in[30];
  const int* src_pp = (const int*)d_in[31]; const int* dst_pp = (const int*)d_in[32];
  const int* src_cp = (const int*)d_in[33]; const int* dst_cp = (const int*)d_in[34];
  const int* drug1  = (const int*)d_in[35]; const int* drug2  = (const int*)d_in[36];
  const int* cellb  = (const int*)d_in[37];
  float* out = (float*)d_out;

  char* wsb = (char*)d_ws;
  size_t off = 0;
  auto alloc = [&](size_t bytes) -> void* {
    void* p = wsb + off;
    off += (bytes + 255) & ~(size_t)255;
    return p;
  };
  bf16_t* xdb[2] = {(bf16_t*)alloc((size_t)ND * H * 2),  (bf16_t*)alloc((size_t)ND * H * 2)};
  bf16_t* xpb[2] = {(bf16_t*)alloc((size_t)NPN * H * 2), (bf16_t*)alloc((size_t)NPN * H * 2)};
  bf16_t* xcb[2] = {(bf16_t*)alloc((size_t)NCN * H * 2), (bf16_t*)alloc((size_t)NCN * H * 2)};
  const int Msrc[5] = {ND, NPN, NCN, NPN, NPN};
  const int Mdst[5] = {NPN, NPN, NPN, ND, NCN};
  const int Erel[5] = {E_DP, E_PP, E_CP, E_DP, E_CP};
  bf16_t* yp = (bf16_t*)alloc((size_t)NPN * 384 * 2);
  bf16_t* yd = (bf16_t*)alloc((size_t)ND * H * 2);
  bf16_t* yc = (bf16_t*)alloc((size_t)NCN * H * 2);
  bf16_t* Wtp = (bf16_t*)alloc((size_t)NLAYERS * 128 * 384 * 2);
  bf16_t* Wtd = (bf16_t*)alloc((size_t)NLAYERS * 128 * 128 * 2);
  bf16_t* Wtc = (bf16_t*)alloc((size_t)NLAYERS * 128 * 128 * 2);
  bf16_t* W1t = (bf16_t*)alloc((size_t)768 * 384 * 2);
  bf16_t* W2t = (bf16_t*)alloc((size_t)256 * 768 * 2);
  float* wvb = (float*)alloc(20 * H * 4);
  float* ssb[5]; for (int r = 0; r < 5; ++r) ssb[r] = (float*)alloc((size_t)Msrc[r] * 4);
  float* sdb[5]; for (int r = 0; r < 5; ++r) sdb[r] = (float*)alloc((size_t)Mdst[r] * 4);
  int* cnt_all = (int*)alloc(62000 * 4);
  int* cur_all = (int*)alloc(62000 * 4);
  int* st_all  = (int*)alloc((62000 + 5) * 4);
  int *cntb[5], *curb[5], *stb[5];
  { int o = 0, o2 = 0;
    for (int r = 0; r < 5; ++r) {
      cntb[r] = cnt_all + o; curb[r] = cur_all + o; stb[r] = st_all + o2;
      o += Mdst[r]; o2 += Mdst[r] + 1;
    } }
  u16* csrb[5]; for (int r = 0; r < 5; ++r) csrb[r] = (u16*)alloc((size_t)Erel[r] * 2);
  float* invd = (float*)alloc(ND * 4);
  float* invc = (float*)alloc(NCN * 4);
  float* P1a = (float*)alloc((size_t)ND * 768 * 4);
  float* P1b = (float*)alloc((size_t)ND * 768 * 4);
  float* P1c = (float*)alloc((size_t)NCN * 768 * 4);
  (void)ws_size;

  // zero the output (fused head accumulates into it)
  hipMemsetAsync(out, 0, (size_t)out_size * 4, stream);

  // conversions
  k_conv_emb<<<(ND * H + NPN * H + NCN * H + 255) / 256, 256, 0, stream>>>(
      drug_emb, protein_emb, cell_emb, xdb[0], xpb[0], xcb[0]);
  TC tc;
  for (int l = 0; l < 2; ++l) {
    for (int r = 0; r < 3; ++r) {
      int m = l * 3 + r;
      tc.src[m] = W_[r] + (size_t)l * H * H;
      tc.dst[m] = Wtp + (size_t)l * 128 * 384;
      tc.Ksub[m] = 128; tc.N[m] = 128; tc.Kfull[m] = 384; tc.koff[m] = r * 128;
    }
    tc.src[6 + l] = W_[3] + (size_t)l * H * H; tc.dst[6 + l] = Wtd + (size_t)l * 128 * 128;
    tc.Ksub[6 + l] = 128; tc.N[6 + l] = 128; tc.Kfull[6 + l] = 128; tc.koff[6 + l] = 0;
    tc.src[8 + l] = W_[4] + (size_t)l * H * H; tc.dst[8 + l] = Wtc + (size_t)l * 128 * 128;
    tc.Ksub[8 + l] = 128; tc.N[8 + l] = 128; tc.Kfull[8 + l] = 128; tc.koff[8 + l] = 0;
  }
  tc.src[10] = W1; tc.dst[10] = W1t; tc.Ksub[10] = 384; tc.N[10] = 768; tc.Kfull[10] = 384; tc.koff[10] = 0;
  tc.src[11] = W2; tc.dst[11] = W2t; tc.Ksub[11] = 768; tc.N[11] = 256; tc.Kfull[11] = 768; tc.koff[11] = 0;
  k_tconv2<<<dim3(24, 24, 12), 256, 0, stream>>>(tc);

  // wv for both layers
  Wd20 wg;
  for (int l = 0; l < 2; ++l)
    for (int r = 0; r < 5; ++r) {
      int m = l * 10 + r;
      wg.W[m] = W_[r] + (size_t)l * H * H; wg.a[m] = as_[r] + l * H; wg.o[m] = wvb + m * H;
      int m2 = l * 10 + 5 + r;
      wg.W[m2] = W_[r] + (size_t)l * H * H; wg.a[m2] = ad_[r] + l * H; wg.o[m2] = wvb + m2 * H;
    }
  k_wd20<<<20, 128, 0, stream>>>(wg);

  // CSR build (u16; pp WITHOUT self-loops — handled analytically in agg)
  hipMemsetAsync(cnt_all, 0, 62000 * 4, stream);
  CsrArgs ca;
  const int* srcA[5] = {src_dp, src_pp, src_cp, dst_dp, dst_cp};
  const int* dstA[5] = {dst_dp, dst_pp, dst_cp, src_dp, src_cp};
  for (int r = 0; r < 5; ++r) {
    ca.src[r] = srcA[r]; ca.dst[r] = dstA[r]; ca.E[r] = Erel[r]; ca.n[r] = Mdst[r];
    ca.cnt[r] = cntb[r]; ca.cur[r] = curb[r]; ca.starts[r] = stb[r]; ca.csr[r] = csrb[r];
  }
  dim3 egrid((E_PP + 1023) / 1024, 5);
  k_count5<<<egrid, 256, 0, stream>>>(ca);
  k_scan5<<<5, 1024, 0, stream>>>(ca);
  k_fill5<<<egrid, 256, 0, stream>>>(ca);

  int cur = 0;
  for (int l = 0; l < NLAYERS; ++l) {
    int nxt = 1 - cur;
    const bf16_t* xsrc[5] = {xdb[cur], xpb[cur], xcb[cur], xpb[cur], xpb[cur]};
    Sc sc;
    sc.xd = xdb[cur]; sc.xp = xpb[cur]; sc.xc = xcb[cur]; sc.wv = wvb + l * 10 * H;
    for (int r = 0; r < 5; ++r) { sc.ss[r] = ssb[r]; sc.sd[r] = sdb[r]; }
    k_scores<<<(ND + NPN + NCN + 3) / 4, 256, 0, stream>>>(sc);
    Agg5 aa;
    bf16_t* yptr[5] = {yp, yp, yp, yd, yc};
    const int ystr[5] = {384, 384, 384, 128, 128};
    const int ycof[5] = {0, 128, 256, 0, 0};
    const int selfs[5] = {0, 1, 0, 0, 0};
    for (int r = 0; r < 5; ++r) {
      aa.csr[r] = csrb[r]; aa.starts[r] = stb[r]; aa.ss[r] = ssb[r]; aa.sd[r] = sdb[r];
      aa.xs[r] = xsrc[r]; aa.y[r] = yptr[r]; aa.ystride[r] = ystr[r]; aa.ycoff[r] = ycof[r];
      aa.ndst[r] = Mdst[r]; aa.self[r] = selfs[r];
    }
    k_agg5<<<dim3((NPN + 3) / 4, 5), 256, 0, stream>>>(aa);
    Gemm3 g3;
    g3.j[0] = {yp, Wtp + (size_t)l * 128 * 384, xpb[nxt], NPN, 384,
               b_[0] + l * H, b_[1] + l * H, b_[2] + l * H};
    g3.j[1] = {yd, Wtd + (size_t)l * 128 * 128, xdb[nxt], ND, 128,
               b_[3] + l * H, nullptr, nullptr};
    g3.j[2] = {yc, Wtc + (size_t)l * 128 * 128, xcb[nxt], NCN, 128,
               b_[4] + l * H, nullptr, nullptr};
    k_gemm_g3<<<dim3((NPN + 127) / 128, 3), 256, 0, stream>>>(g3);
    cur = nxt;
  }

  // head: inv-norms -> scaled slice GEMMs (P tables) -> fused gather+W2+W3
  k_invnorm<<<(ND + NCN + 3) / 4, 256, 0, stream>>>(xdb[cur], xcb[cur], invd, invc);
  GemmPS ps;
  ps.Bt = W1t;
  ps.j[0] = {xdb[cur], P1a, ND, invd};
  ps.j[1] = {xdb[cur], P1b, ND, invd};
  ps.j[2] = {xcb[cur], P1c, NCN, invc};
  k_gemm_ps<<<dim3(32 * 6, 3), 256, 0, stream>>>(ps);
  k_w2head<<<dim3((NB + 127) / 128, 2), 256, 0, stream>>>(
      P1a, P1b, P1c, b1, drug1, drug2, cellb, W2t, b2, W3, b3, out, NB);
}

// Round 8
// 400.584 us; speedup vs baseline: 1.3622x; 1.0441x over previous
//
#include <hip/hip_runtime.h>
#include <hip/hip_bf16.h>

#define H 128
#define ND 4000
#define NPN 19000
#define NCN 1000
#define NLAYERS 2
#define NB 30000
#define E_DP 200000
#define E_PP 300000
#define E_CP 150000

typedef __bf16 bf16_t;
typedef bf16_t bf16x8 __attribute__((ext_vector_type(8)));
typedef float f32x4 __attribute__((ext_vector_type(4)));
typedef unsigned short u16;

static __device__ __forceinline__ float wred_sum(float v) {
#pragma unroll
  for (int off = 32; off; off >>= 1) v += __shfl_xor(v, off);
  return v;
}
static __device__ __forceinline__ float bflo(unsigned u) { return __uint_as_float(u << 16); }
static __device__ __forceinline__ float bfhi(unsigned u) { return __uint_as_float(u & 0xffff0000u); }
static __device__ __forceinline__ unsigned packbf(float v0, float v1) {
  union { bf16_t b; unsigned short u; } a, b;
  a.b = (bf16_t)v0; b.b = (bf16_t)v1;
  return (unsigned)a.u | ((unsigned)b.u << 16);
}

// async global->LDS, 16B per lane
#define GLDS16(gp, lp) \
  __builtin_amdgcn_global_load_lds((__attribute__((address_space(1))) void*)(gp), \
                                   (__attribute__((address_space(3))) void*)(lp), 16, 0, 0)

// ================= MFMA GEMM core (fills acc; epilogue is per-kernel) =================
__device__ __forceinline__ void mfma_core(
    const bf16_t* __restrict__ A, const bf16_t* __restrict__ Bt,
    int M, int K, int ldb, int m0, int n0, f32x4 (&acc)[4][4])
{
  __shared__ char As[128 * 64];
  __shared__ char Bs[128 * 64];
  const int t = threadIdx.x;
  const int lane = t & 63;
#pragma unroll
  for (int mi = 0; mi < 4; ++mi)
#pragma unroll
    for (int ni = 0; ni < 4; ++ni) acc[mi][ni] = (f32x4){0.f, 0.f, 0.f, 0.f};

  const int wid = t >> 6;
  const int wr = wid >> 1, wc = wid & 1;
  const int sr = t >> 2;
  const int sc = t & 3;
  const int csrc = ((sc ^ ((sr >> 1) & 3)) << 4);
  int ra0 = m0 + sr;      if (ra0 >= M) ra0 = M - 1;
  int ra1 = m0 + 64 + sr; if (ra1 >= M) ra1 = M - 1;
  const char* gA0 = (const char*)A + (size_t)ra0 * K * 2 + csrc;
  const char* gA1 = (const char*)A + (size_t)ra1 * K * 2 + csrc;
  const char* gB0 = (const char*)Bt + (size_t)(n0 + sr) * ldb * 2 + csrc;
  const char* gB1 = (const char*)Bt + (size_t)(n0 + 64 + sr) * ldb * 2 + csrc;
  char* lA0 = As + t * 16;
  char* lA1 = As + 4096 + t * 16;
  char* lB0 = Bs + t * 16;
  char* lB1 = Bs + 4096 + t * 16;

  int aoff[4], boff[4];
#pragma unroll
  for (int mi = 0; mi < 4; ++mi) {
    int r = wr * 64 + mi * 16 + (lane & 15);
    aoff[mi] = r * 64 + ((((lane >> 4)) ^ ((r >> 1) & 3)) << 4);
  }
#pragma unroll
  for (int ni = 0; ni < 4; ++ni) {
    int r = wc * 64 + ni * 16 + (lane & 15);
    boff[ni] = r * 64 + ((((lane >> 4)) ^ ((r >> 1) & 3)) << 4);
  }

  for (int k0 = 0; k0 < K; k0 += 32) {
    const size_t kb = (size_t)k0 * 2;
    __syncthreads();
    GLDS16(gA0 + kb, lA0);
    GLDS16(gA1 + kb, lA1);
    GLDS16(gB0 + kb, lB0);
    GLDS16(gB1 + kb, lB1);
    __syncthreads();
    bf16x8 av[4], bv[4];
#pragma unroll
    for (int mi = 0; mi < 4; ++mi) av[mi] = *(const bf16x8*)(As + aoff[mi]);
#pragma unroll
    for (int ni = 0; ni < 4; ++ni) bv[ni] = *(const bf16x8*)(Bs + boff[ni]);
#pragma unroll
    for (int mi = 0; mi < 4; ++mi)
#pragma unroll
      for (int ni = 0; ni < 4; ++ni)
        acc[mi][ni] = __builtin_amdgcn_mfma_f32_16x16x32_bf16(av[mi], bv[ni], acc[mi][ni], 0, 0, 0);
  }
}

// --- GAT dst-side transform: C = relu(y @ Wt + biases), bf16 out, N=128 ---
struct GJob { const bf16_t* A; const bf16_t* Bt; bf16_t* C; int M; int K;
              const float *b1, *b2, *b3; };
struct Gemm3 { GJob j[3]; };
__global__ __launch_bounds__(256) void k_gemm_g3(Gemm3 g) {
  const GJob& jb = g.j[blockIdx.y];
  int m0 = blockIdx.x * 128;
  if (m0 >= jb.M) return;
  f32x4 acc[4][4];
  mfma_core(jb.A, jb.Bt, jb.M, jb.K, jb.K, m0, 0, acc);
  const int t = threadIdx.x, lane = t & 63, wid = t >> 6;
  const int wr = wid >> 1, wc = wid & 1;
  const int col0 = lane & 15, rsub = (lane >> 4) * 4;
#pragma unroll
  for (int mi = 0; mi < 4; ++mi) {
#pragma unroll
    for (int ni = 0; ni < 4; ++ni) {
      int c = wc * 64 + ni * 16 + col0;
      float bb = jb.b1[c];
      if (jb.b2) bb += jb.b2[c];
      if (jb.b3) bb += jb.b3[c];
#pragma unroll
      for (int rg = 0; rg < 4; ++rg) {
        int r = m0 + wr * 64 + mi * 16 + rsub + rg;
        if (r < jb.M) jb.C[(size_t)r * H + c] = (bf16_t)fmaxf(acc[mi][ni][rg] + bb, 0.f);
      }
    }
  }
}

// --- head slice GEMMs: P = (x @ W1slice) * rowscale + b1/3, bf16 out ---
struct PJob { const bf16_t* A; bf16_t* C; int M; const float* rs; };
struct GemmPS { PJob j[3]; const bf16_t* Bt; const float* b1t; };
__global__ __launch_bounds__(256) void k_gemm_ps(GemmPS g) {
  const PJob& jb = g.j[blockIdx.y];
  int mt = blockIdx.x / 6, nt = blockIdx.x - mt * 6;
  int m0 = mt * 128;
  if (m0 >= jb.M) return;
  int n0 = nt * 128;
  f32x4 acc[4][4];
  mfma_core(jb.A, g.Bt + blockIdx.y * 128, jb.M, 128, 384, m0, n0, acc);
  const int t = threadIdx.x, lane = t & 63, wid = t >> 6;
  const int wr = wid >> 1, wc = wid & 1;
  const int col0 = lane & 15, rsub = (lane >> 4) * 4;
#pragma unroll
  for (int mi = 0; mi < 4; ++mi) {
#pragma unroll
    for (int rg = 0; rg < 4; ++rg) {
      int r = m0 + wr * 64 + mi * 16 + rsub + rg;
      if (r < jb.M) {
        float sc = jb.rs[r];
#pragma unroll
        for (int ni = 0; ni < 4; ++ni) {
          int c = n0 + wc * 64 + ni * 16 + col0;
          jb.C[(size_t)r * 768 + c] = (bf16_t)(acc[mi][ni][rg] * sc + g.b1t[c]);
        }
      }
    }
  }
}

// --- fused head, BN=256 single pass: A-tile = relu(Pa[d1]+Pb[d2]+Pc[ce]) built
//     in-kernel from bf16 tables; GEMM vs all 256 cols of W2t; epilogue fuses
//     relu + W3 -> atomicAdd into out ---
__global__ __launch_bounds__(256) void k_w2head(
    const bf16_t* __restrict__ Pa, const bf16_t* __restrict__ Pb, const bf16_t* __restrict__ Pc,
    const int* __restrict__ d1, const int* __restrict__ d2, const int* __restrict__ ce,
    const bf16_t* __restrict__ W2t, const float* __restrict__ b2,
    const float* __restrict__ W3, const float* __restrict__ b3,
    float* __restrict__ out, int cn)
{
  __shared__ char As[128 * 64];
  __shared__ char Bs[256 * 64];
  const int t = threadIdx.x;
  const int lane = t & 63;
  const int m0 = blockIdx.x * 128;
  if (m0 >= cn) return;
  f32x4 acc[4][8];
#pragma unroll
  for (int mi = 0; mi < 4; ++mi)
#pragma unroll
    for (int ni = 0; ni < 8; ++ni) acc[mi][ni] = (f32x4){0.f, 0.f, 0.f, 0.f};

  // A gather role: row = t>>1 (0..127), half h = t&1 (16 elems)
  const int arow = t >> 1;
  const int ah = t & 1;
  int gr = m0 + arow; if (gr >= cn) gr = cn - 1;
  const bf16_t* pa = Pa + (size_t)d1[gr] * 768 + ah * 16;
  const bf16_t* pb = Pb + (size_t)d2[gr] * 768 + ah * 16;
  const bf16_t* pc = Pc + (size_t)ce[gr] * 768 + ah * 16;
  const int swz = (arow >> 1) & 3;
  char* la0 = As + arow * 64 + (((ah * 2)     ^ swz) << 4);
  char* la1 = As + arow * 64 + (((ah * 2 + 1) ^ swz) << 4);

  // B staging: 256 rows x 32k in 4 quarters (global_load_lds)
  const int sr = t >> 2;
  const int sc = t & 3;
  const int csrc = ((sc ^ ((sr >> 1) & 3)) << 4);
  const char* gB = (const char*)W2t + (size_t)sr * 768 * 2 + csrc;
  const size_t qstep = (size_t)64 * 768 * 2;

  const int wid = t >> 6;
  const int wr = wid >> 1, wc = wid & 1;
  int aoff[4], boff[8];
#pragma unroll
  for (int mi = 0; mi < 4; ++mi) {
    int r = wr * 64 + mi * 16 + (lane & 15);
    aoff[mi] = r * 64 + ((((lane >> 4)) ^ ((r >> 1) & 3)) << 4);
  }
#pragma unroll
  for (int ni = 0; ni < 8; ++ni) {
    int r = wc * 128 + ni * 16 + (lane & 15);
    boff[ni] = r * 64 + ((((lane >> 4)) ^ ((r >> 1) & 3)) << 4);
  }

#define ACC8(U, o) { s[o+0] += bflo(U.x); s[o+1] += bfhi(U.x); s[o+2] += bflo(U.y); s[o+3] += bfhi(U.y); \
                     s[o+4] += bflo(U.z); s[o+5] += bfhi(U.z); s[o+6] += bflo(U.w); s[o+7] += bfhi(U.w); }
  for (int k0 = 0; k0 < 768; k0 += 32) {
    uint4 Ua0 = *(const uint4*)(pa + k0);
    uint4 Ua1 = *(const uint4*)(pa + k0 + 8);
    uint4 Ub0 = *(const uint4*)(pb + k0);
    uint4 Ub1 = *(const uint4*)(pb + k0 + 8);
    uint4 Uc0 = *(const uint4*)(pc + k0);
    uint4 Uc1 = *(const uint4*)(pc + k0 + 8);
    float s[16] = {0.f, 0.f, 0.f, 0.f, 0.f, 0.f, 0.f, 0.f,
                   0.f, 0.f, 0.f, 0.f, 0.f, 0.f, 0.f, 0.f};
    ACC8(Ua0, 0) ACC8(Ua1, 8)
    ACC8(Ub0, 0) ACC8(Ub1, 8)
    ACC8(Uc0, 0) ACC8(Uc1, 8)
    uint4 P0, P1;
    P0.x = packbf(fmaxf(s[0], 0.f),  fmaxf(s[1], 0.f));
    P0.y = packbf(fmaxf(s[2], 0.f),  fmaxf(s[3], 0.f));
    P0.z = packbf(fmaxf(s[4], 0.f),  fmaxf(s[5], 0.f));
    P0.w = packbf(fmaxf(s[6], 0.f),  fmaxf(s[7], 0.f));
    P1.x = packbf(fmaxf(s[8], 0.f),  fmaxf(s[9], 0.f));
    P1.y = packbf(fmaxf(s[10], 0.f), fmaxf(s[11], 0.f));
    P1.z = packbf(fmaxf(s[12], 0.f), fmaxf(s[13], 0.f));
    P1.w = packbf(fmaxf(s[14], 0.f), fmaxf(s[15], 0.f));
    const size_t kb = (size_t)k0 * 2;
    __syncthreads();
    GLDS16(gB + kb,             Bs + t * 16);
    GLDS16(gB + qstep + kb,     Bs + 4096 + t * 16);
    GLDS16(gB + 2 * qstep + kb, Bs + 8192 + t * 16);
    GLDS16(gB + 3 * qstep + kb, Bs + 12288 + t * 16);
    *(uint4*)la0 = P0;
    *(uint4*)la1 = P1;
    __syncthreads();
    bf16x8 av[4], bv[8];
#pragma unroll
    for (int mi = 0; mi < 4; ++mi) av[mi] = *(const bf16x8*)(As + aoff[mi]);
#pragma unroll
    for (int ni = 0; ni < 8; ++ni) bv[ni] = *(const bf16x8*)(Bs + boff[ni]);
#pragma unroll
    for (int mi = 0; mi < 4; ++mi)
#pragma unroll
      for (int ni = 0; ni < 8; ++ni)
        acc[mi][ni] = __builtin_amdgcn_mfma_f32_16x16x32_bf16(av[mi], bv[ni], acc[mi][ni], 0, 0, 0);
  }
#undef ACC8

  const int col0 = lane & 15, rsub = (lane >> 4) * 4;
  float w0[8], w1[8], bb[8];
#pragma unroll
  for (int ni = 0; ni < 8; ++ni) {
    int c = wc * 128 + ni * 16 + col0;
    w0[ni] = W3[2 * c]; w1[ni] = W3[2 * c + 1]; bb[ni] = b2[c];
  }
#pragma unroll
  for (int mi = 0; mi < 4; ++mi) {
#pragma unroll
    for (int rg = 0; rg < 4; ++rg) {
      int r = m0 + wr * 64 + mi * 16 + rsub + rg;
      float p0 = 0.f, p1 = 0.f;
#pragma unroll
      for (int ni = 0; ni < 8; ++ni) {
        float v = fmaxf(acc[mi][ni][rg] + bb[ni], 0.f);
        p0 = fmaf(v, w0[ni], p0);
        p1 = fmaf(v, w1[ni], p1);
      }
#pragma unroll
      for (int off = 1; off < 16; off <<= 1) {
        p0 += __shfl_xor(p0, off);
        p1 += __shfl_xor(p1, off);
      }
      if (col0 == 0 && r < cn) {
        if (wc == 0) { p0 += b3[0]; p1 += b3[1]; }
        atomicAdd(&out[(size_t)r * 2], p0);
        atomicAdd(&out[(size_t)r * 2 + 1], p1);
      }
    }
  }
}

// ================= conversions =================
__global__ __launch_bounds__(256) void k_conv_emb(
    const float* __restrict__ xd, const float* __restrict__ xp, const float* __restrict__ xc,
    bf16_t* __restrict__ od, bf16_t* __restrict__ op, bf16_t* __restrict__ oc)
{
  int i = blockIdx.x * 256 + threadIdx.x;
  const int SD = ND * H, SP = NPN * H, SC = NCN * H;
  if (i < SD) od[i] = (bf16_t)xd[i];
  else if (i < SD + SP) op[i - SD] = (bf16_t)xp[i - SD];
  else if (i < SD + SP + SC) oc[i - SD - SP] = (bf16_t)xc[i - SD - SP];
}

__global__ __launch_bounds__(256) void k_scale3(const float* __restrict__ b1, float* __restrict__ o) {
  int i = blockIdx.x * 256 + threadIdx.x;
  if (i < 768) o[i] = b1[i] * (1.f / 3.f);
}

// LDS-tiled transpose-convert: dst[n*Kfull+koff+k] = bf16(src[k*N+n])
struct TC { const float* src[12]; bf16_t* dst[12]; int Ksub[12]; int N[12]; int Kfull[12]; int koff[12]; };
__global__ __launch_bounds__(256) void k_tconv2(TC a) {
  int m = blockIdx.z;
  int Ks = a.Ksub[m], N = a.N[m];
  int tx = blockIdx.x * 32;
  int ty = blockIdx.y * 32;
  if (tx >= N || ty >= Ks) return;
  __shared__ float tile[32][33];
  int c = threadIdx.x & 31, rr = threadIdx.x >> 5;
#pragma unroll
  for (int kk = rr; kk < 32; kk += 8)
    if (ty + kk < Ks && tx + c < N) tile[kk][c] = a.src[m][(size_t)(ty + kk) * N + tx + c];
  __syncthreads();
  bf16_t* dst = a.dst[m];
  int Kf = a.Kfull[m], ko = a.koff[m];
#pragma unroll
  for (int nn = rr; nn < 32; nn += 8)
    if (tx + nn < N && ty + c < Ks)
      dst[(size_t)(tx + nn) * Kf + ko + ty + c] = (bf16_t)tile[c][nn];
}

// ---------------- wv = W @ a : both layers, 20 matvecs ----------------
struct Wd20 { const float* W[20]; const float* a[20]; float* o[20]; };
__global__ __launch_bounds__(128) void k_wd20(Wd20 g) {
  int m = blockIdx.x;
  int k = threadIdx.x;
  const float* Wp = g.W[m];
  const float* av = g.a[m];
  float s = 0.f;
#pragma unroll 4
  for (int j = 0; j < H; ++j) s = fmaf(Wp[k * H + j], av[j], s);
  g.o[m][k] = s;
}

// ---------------- fused node scores ----------------
struct Sc { const bf16_t* xd; const bf16_t* xp; const bf16_t* xc; const float* wv;
            float* ss[5]; float* sd[5]; };
__global__ __launch_bounds__(256) void k_scores(Sc S) {
  int row = blockIdx.x * 4 + (threadIdx.x >> 6);
  if (row >= ND + NPN + NCN) return;
  int lane = threadIdx.x & 63;
  const bf16_t* x;
  int idx, cls;
  if (row < ND) { x = S.xd; idx = row; cls = 0; }
  else if (row < ND + NPN) { x = S.xp; idx = row - ND; cls = 1; }
  else { x = S.xc; idx = row - ND - NPN; cls = 2; }
  unsigned u = *(const unsigned*)(x + (size_t)idx * H + lane * 2);
  float x0 = bflo(u), x1 = bfhi(u);
  const float* wv = S.wv;
#define DOT(vi, outp) { const float* v = wv + (vi) * H; \
    float s = x0 * v[2 * lane] + x1 * v[2 * lane + 1]; s = wred_sum(s); \
    if (!lane) (outp)[idx] = s; }
  if (cls == 0) {
    DOT(0, S.ss[0]); DOT(8, S.sd[3]);
  } else if (cls == 1) {
    DOT(1, S.ss[1]); DOT(3, S.ss[3]); DOT(4, S.ss[4]);
    DOT(5, S.sd[0]); DOT(6, S.sd[1]); DOT(7, S.sd[2]);
  } else {
    DOT(2, S.ss[2]); DOT(9, S.sd[4]);
  }
#undef DOT
}

// ---------------- CSR build (u16 payload, 4-edge ILP) ----------------
struct CsrArgs {
  const int* src[5]; const int* dst[5];
  int E[5]; int n[5];
  int* cnt[5]; int* cur[5]; int* starts[5]; u16* csr[5];
};
__global__ __launch_bounds__(256) void k_count5(CsrArgs a) {
  int rel = blockIdx.y;
  int E = a.E[rel];
  const int* dst = a.dst[rel];
  int* cnt = a.cnt[rel];
  int e0 = blockIdx.x * 1024 + threadIdx.x;
#pragma unroll
  for (int u = 0; u < 4; ++u) {
    int e = e0 + u * 256;
    if (e < E) atomicAdd(&cnt[dst[e]], 1);
  }
}
__global__ __launch_bounds__(1024) void k_scan5(CsrArgs a) {
  int rel = blockIdx.x;
  int n = a.n[rel];
  const int* cnt = a.cnt[rel];
  int* st = a.starts[rel];
  int* cu = a.cur[rel];
  int t = threadIdx.x;
  int stripe = (n + 1023) / 1024;
  int lo = t * stripe;
  int hi = lo + stripe; if (hi > n) hi = n;
  int s = 0;
  for (int i = lo; i < hi; ++i) s += cnt[i];
  int lane = t & 63, wv = t >> 6;
  int x = s;
#pragma unroll
  for (int off = 1; off < 64; off <<= 1) {
    int y = __shfl_up(x, off);
    if (lane >= off) x += y;
  }
  __shared__ int ws[16];
  if (lane == 63) ws[wv] = x;
  __syncthreads();
  if (t == 0) {
    int run = 0;
#pragma unroll
    for (int i = 0; i < 16; ++i) { int v = ws[i]; ws[i] = run; run += v; }
  }
  __syncthreads();
  int run = ws[wv] + x - s;
  for (int i = lo; i < hi; ++i) { st[i] = run; cu[i] = run; run += cnt[i]; }
  if (t == 1023) st[n] = ws[15] + x;
}
__global__ __launch_bounds__(256) void k_fill5(CsrArgs a) {
  int rel = blockIdx.y;
  int E = a.E[rel];
  const int* dst = a.dst[rel];
  const int* src = a.src[rel];
  int* cur = a.cur[rel];
  u16* csr = a.csr[rel];
  int e0 = blockIdx.x * 1024 + threadIdx.x;
#pragma unroll
  for (int u = 0; u < 4; ++u) {
    int e = e0 + u * 256;
    if (e < E) {
      int pos = atomicAdd(&cur[dst[e]], 1);
      csr[pos] = (u16)src[e];
    }
  }
}

// ---------------- GAT aggregate on RAW x; analytic pp self-loop ----------------
struct Agg5 {
  const u16* csr[5]; const int* starts[5];
  const float* ss[5]; const float* sd[5];
  const bf16_t* xs[5];
  bf16_t* y[5]; int ystride[5]; int ycoff[5]; int ndst[5]; int self[5];
};
__global__ __launch_bounds__(256) void k_agg5(Agg5 a) {
  int rel = blockIdx.y;
  int d = blockIdx.x * 4 + (threadIdx.x >> 6);
  if (d >= a.ndst[rel]) return;
  int lane = threadIdx.x & 63;
  int g = lane >> 4, j16 = lane & 15;
  bf16_t* yrow = a.y[rel] + (size_t)d * a.ystride[rel] + a.ycoff[rel];
  int s0 = a.starts[rel][d];
  int deg = a.starts[rel][d + 1] - s0;
  int selfa = a.self[rel];
  if (!deg && !selfa) {
    if (g == 0) *(uint4*)(yrow + j16 * 8) = make_uint4(0u, 0u, 0u, 0u);
    return;
  }
  const u16* cs = a.csr[rel] + s0;
  const float* ssp = a.ss[rel];
  const bf16_t* xsp = a.xs[rel];
  float sdv = a.sd[rel][d];
  float acc[8] = {0.f, 0.f, 0.f, 0.f, 0.f, 0.f, 0.f, 0.f};
  float ps = 0.f;
  for (int b = 0; b < deg; b += 16) {
#pragma unroll
    for (int u = 0; u < 4; ++u) {
      int i = b + u * 4 + g;
      float p = 0.f;
      uint4 U = make_uint4(0u, 0u, 0u, 0u);
      if (i < deg) {
        int s = cs[i];
        float e = ssp[s] + sdv; e = e > 0.f ? e : 0.2f * e;
        p = __expf(e);
        U = *(const uint4*)(xsp + (size_t)s * H + j16 * 8);
      }
      ps += p;
      acc[0] = fmaf(p, bflo(U.x), acc[0]); acc[1] = fmaf(p, bfhi(U.x), acc[1]);
      acc[2] = fmaf(p, bflo(U.y), acc[2]); acc[3] = fmaf(p, bfhi(U.y), acc[3]);
      acc[4] = fmaf(p, bflo(U.z), acc[4]); acc[5] = fmaf(p, bfhi(U.z), acc[5]);
      acc[6] = fmaf(p, bflo(U.w), acc[6]); acc[7] = fmaf(p, bfhi(U.w), acc[7]);
    }
  }
  if (selfa && g == 0) {
    float e = ssp[d] + sdv; e = e > 0.f ? e : 0.2f * e;
    float p = __expf(e);
    uint4 U = *(const uint4*)(xsp + (size_t)d * H + j16 * 8);
    ps += p;
    acc[0] = fmaf(p, bflo(U.x), acc[0]); acc[1] = fmaf(p, bfhi(U.x), acc[1]);
    acc[2] = fmaf(p, bflo(U.y), acc[2]); acc[3] = fmaf(p, bfhi(U.y), acc[3]);
    acc[4] = fmaf(p, bflo(U.z), acc[4]); acc[5] = fmaf(p, bfhi(U.z), acc[5]);
    acc[6] = fmaf(p, bflo(U.w), acc[6]); acc[7] = fmaf(p, bfhi(U.w), acc[7]);
  }
#pragma unroll
  for (int e = 0; e < 8; ++e) {
    acc[e] += __shfl_xor(acc[e], 16);
    acc[e] += __shfl_xor(acc[e], 32);
  }
  ps += __shfl_xor(ps, 16);
  ps += __shfl_xor(ps, 32);
  if (g == 0) {
    float inv = 1.f / ps;
    uint4 O;
    O.x = packbf(acc[0] * inv, acc[1] * inv);
    O.y = packbf(acc[2] * inv, acc[3] * inv);
    O.z = packbf(acc[4] * inv, acc[5] * inv);
    O.w = packbf(acc[6] * inv, acc[7] * inv);
    *(uint4*)(yrow + j16 * 8) = O;
  }
}

// ---------------- readout ----------------
__global__ __launch_bounds__(256) void k_invnorm(
    const bf16_t* __restrict__ xd, const bf16_t* __restrict__ xc,
    float* __restrict__ invd, float* __restrict__ invc)
{
  int row = blockIdx.x * 4 + (threadIdx.x >> 6);
  if (row >= ND + NCN) return;
  int lane = threadIdx.x & 63;
  const bf16_t* x = (row < ND) ? xd + (size_t)row * H : xc + (size_t)(row - ND) * H;
  unsigned u = ((const unsigned*)x)[lane];
  float av = bflo(u), bv = bfhi(u);
  float s = wred_sum(av * av + bv * bv);
  if (!lane) {
    float nv = fmaxf(sqrtf(s), 1e-12f);
    if (row < ND) invd[row] = 1.f / nv; else invc[row - ND] = 1.f / nv;
  }
}

// ================= host =================
extern "C" void kernel_launch(void* const* d_in, const int* in_sizes, int n_in,
                              void* d_out, int out_size, void* d_ws, size_t ws_size,
                              hipStream_t stream)
{
  (void)in_sizes; (void)n_in;
  const float* drug_emb    = (const float*)d_in[0];
  const float* protein_emb = (const float*)d_in[1];
  const float* cell_emb    = (const float*)d_in[2];
  // internal rel order: 0=dp, 1=pp, 2=cp, 3=rdp, 4=rcp
  const int base_idx[5] = {3, 11, 15, 7, 19};
  const float *W_[5], *as_[5], *ad_[5], *b_[5];
  for (int r = 0; r < 5; ++r) {
    W_[r]  = (const float*)d_in[base_idx[r]];
    as_[r] = (const float*)d_in[base_idx[r] + 1];
    ad_[r] = (const float*)d_in[base_idx[r] + 2];
    b_[r]  = (const float*)d_in[base_idx[r] + 3];
  }
  const float* W1 = (const float*)d_in[23]; const float* b1 = (const float*)d_in[24];
  const float* W2 = (const float*)d_in[25]; const float* b2 = (const float*)d_in[26];
  const float* W3 = (const float*)d_in[27]; const float* b3 = (const float*)d_in[28];
  const int* src_dp = (const int*)d_in[29]; const int* dst_dp = (const int*)d_in[30];
  const int* src_pp = (const int*)d_in[31]; const int* dst_pp = (const int*)d_in[32];
  const int* src_cp = (const int*)d_in[33]; const int* dst_cp = (const int*)d_in[34];
  const int* drug1  = (const int*)d_in[35]; const int* drug2  = (const int*)d_in[36];
  const int* cellb  = (const int*)d_in[37];
  float* out = (float*)d_out;

  char* wsb = (char*)d_ws;
  size_t off = 0;
  auto alloc = [&](size_t bytes) -> void* {
    void* p = wsb + off;
    off += (bytes + 255) & ~(size_t)255;
    return p;
  };
  bf16_t* xdb[2] = {(bf16_t*)alloc((size_t)ND * H * 2),  (bf16_t*)alloc((size_t)ND * H * 2)};
  bf16_t* xpb[2] = {(bf16_t*)alloc((size_t)NPN * H * 2), (bf16_t*)alloc((size_t)NPN * H * 2)};
  bf16_t* xcb[2] = {(bf16_t*)alloc((size_t)NCN * H * 2), (bf16_t*)alloc((size_t)NCN * H * 2)};
  const int Msrc[5] = {ND, NPN, NCN, NPN, NPN};
  const int Mdst[5] = {NPN, NPN, NPN, ND, NCN};
  const int Erel[5] = {E_DP, E_PP, E_CP, E_DP, E_CP};
  bf16_t* yp = (bf16_t*)alloc((size_t)NPN * 384 * 2);
  bf16_t* yd = (bf16_t*)alloc((size_t)ND * H * 2);
  bf16_t* yc = (bf16_t*)alloc((size_t)NCN * H * 2);
  bf16_t* Wtp = (bf16_t*)alloc((size_t)NLAYERS * 128 * 384 * 2);
  bf16_t* Wtd = (bf16_t*)alloc((size_t)NLAYERS * 128 * 128 * 2);
  bf16_t* Wtc = (bf16_t*)alloc((size_t)NLAYERS * 128 * 128 * 2);
  bf16_t* W1t = (bf16_t*)alloc((size_t)768 * 384 * 2);
  bf16_t* W2t = (bf16_t*)alloc((size_t)256 * 768 * 2);
  float* wvb = (float*)alloc(20 * H * 4);
  float* b1t = (float*)alloc(768 * 4);
  float* ssb[5]; for (int r = 0; r < 5; ++r) ssb[r] = (float*)alloc((size_t)Msrc[r] * 4);
  float* sdb[5]; for (int r = 0; r < 5; ++r) sdb[r] = (float*)alloc((size_t)Mdst[r] * 4);
  int* cnt_all = (int*)alloc(62000 * 4);
  int* cur_all = (int*)alloc(62000 * 4);
  int* st_all  = (int*)alloc((62000 + 5) * 4);
  int *cntb[5], *curb[5], *stb[5];
  { int o = 0, o2 = 0;
    for (int r = 0; r < 5; ++r) {
      cntb[r] = cnt_all + o; curb[r] = cur_all + o; stb[r] = st_all + o2;
      o += Mdst[r]; o2 += Mdst[r] + 1;
    } }
  u16* csrb[5]; for (int r = 0; r < 5; ++r) csrb[r] = (u16*)alloc((size_t)Erel[r] * 2);
  float* invd = (float*)alloc(ND * 4);
  float* invc = (float*)alloc(NCN * 4);
  bf16_t* P1a = (bf16_t*)alloc((size_t)ND * 768 * 2);
  bf16_t* P1b = (bf16_t*)alloc((size_t)ND * 768 * 2);
  bf16_t* P1c = (bf16_t*)alloc((size_t)NCN * 768 * 2);
  (void)ws_size;

  // zero the output (fused head accumulates into it)
  hipMemsetAsync(out, 0, (size_t)out_size * 4, stream);

  // conversions
  k_conv_emb<<<(ND * H + NPN * H + NCN * H + 255) / 256, 256, 0, stream>>>(
      drug_emb, protein_emb, cell_emb, xdb[0], xpb[0], xcb[0]);
  k_scale3<<<3, 256, 0, stream>>>(b1, b1t);
  TC tc;
  for (int l = 0; l < 2; ++l) {
    for (int r = 0; r < 3; ++r) {
      int m = l * 3 + r;
      tc.src[m] = W_[r] + (size_t)l * H * H;
      tc.dst[m] = Wtp + (size_t)l * 128 * 384;
      tc.Ksub[m] = 128; tc.N[m] = 128; tc.Kfull[m] = 384; tc.koff[m] = r * 128;
    }
    tc.src[6 + l] = W_[3] + (size_t)l * H * H; tc.dst[6 + l] = Wtd + (size_t)l * 128 * 128;
    tc.Ksub[6 + l] = 128; tc.N[6 + l] = 128; tc.Kfull[6 + l] = 128; tc.koff[6 + l] = 0;
    tc.src[8 + l] = W_[4] + (size_t)l * H * H; tc.dst[8 + l] = Wtc + (size_t)l * 128 * 128;
    tc.Ksub[8 + l] = 128; tc.N[8 + l] = 128; tc.Kfull[8 + l] = 128; tc.koff[8 + l] = 0;
  }
  tc.src[10] = W1; tc.dst[10] = W1t; tc.Ksub[10] = 384; tc.N[10] = 768; tc.Kfull[10] = 384; tc.koff[10] = 0;
  tc.src[11] = W2; tc.dst[11] = W2t; tc.Ksub[11] = 768; tc.N[11] = 256; tc.Kfull[11] = 768; tc.koff[11] = 0;
  k_tconv2<<<dim3(24, 24, 12), 256, 0, stream>>>(tc);

  // wv for both layers
  Wd20 wg;
  for (int l = 0; l < 2; ++l)
    for (int r = 0; r < 5; ++r) {
      int m = l * 10 + r;
      wg.W[m] = W_[r] + (size_t)l * H * H; wg.a[m] = as_[r] + l * H; wg.o[m] = wvb + m * H;
      int m2 = l * 10 + 5 + r;
      wg.W[m2] = W_[r] + (size_t)l * H * H; wg.a[m2] = ad_[r] + l * H; wg.o[m2] = wvb + m2 * H;
    }
  k_wd20<<<20, 128, 0, stream>>>(wg);

  // CSR build (u16; pp WITHOUT self-loops — handled analytically in agg)
  hipMemsetAsync(cnt_all, 0, 62000 * 4, stream);
  CsrArgs ca;
  const int* srcA[5] = {src_dp, src_pp, src_cp, dst_dp, dst_cp};
  const int* dstA[5] = {dst_dp, dst_pp, dst_cp, src_dp, src_cp};
  for (int r = 0; r < 5; ++r) {
    ca.src[r] = srcA[r]; ca.dst[r] = dstA[r]; ca.E[r] = Erel[r]; ca.n[r] = Mdst[r];
    ca.cnt[r] = cntb[r]; ca.cur[r] = curb[r]; ca.starts[r] = stb[r]; ca.csr[r] = csrb[r];
  }
  dim3 egrid((E_PP + 1023) / 1024, 5);
  k_count5<<<egrid, 256, 0, stream>>>(ca);
  k_scan5<<<5, 1024, 0, stream>>>(ca);
  k_fill5<<<egrid, 256, 0, stream>>>(ca);

  int cur = 0;
  for (int l = 0; l < NLAYERS; ++l) {
    int nxt = 1 - cur;
    const bf16_t* xsrc[5] = {xdb[cur], xpb[cur], xcb[cur], xpb[cur], xpb[cur]};
    Sc sc;
    sc.xd = xdb[cur]; sc.xp = xpb[cur]; sc.xc = xcb[cur]; sc.wv = wvb + l * 10 * H;
    for (int r = 0; r < 5; ++r) { sc.ss[r] = ssb[r]; sc.sd[r] = sdb[r]; }
    k_scores<<<(ND + NPN + NCN + 3) / 4, 256, 0, stream>>>(sc);
    Agg5 aa;
    bf16_t* yptr[5] = {yp, yp, yp, yd, yc};
    const int ystr[5] = {384, 384, 384, 128, 128};
    const int ycof[5] = {0, 128, 256, 0, 0};
    const int selfs[5] = {0, 1, 0, 0, 0};
    for (int r = 0; r < 5; ++r) {
      aa.csr[r] = csrb[r]; aa.starts[r] = stb[r]; aa.ss[r] = ssb[r]; aa.sd[r] = sdb[r];
      aa.xs[r] = xsrc[r]; aa.y[r] = yptr[r]; aa.ystride[r] = ystr[r]; aa.ycoff[r] = ycof[r];
      aa.ndst[r] = Mdst[r]; aa.self[r] = selfs[r];
    }
    k_agg5<<<dim3((NPN + 3) / 4, 5), 256, 0, stream>>>(aa);
    Gemm3 g3;
    g3.j[0] = {yp, Wtp + (size_t)l * 128 * 384, xpb[nxt], NPN, 384,
               b_[0] + l * H, b_[1] + l * H, b_[2] + l * H};
    g3.j[1] = {yd, Wtd + (size_t)l * 128 * 128, xdb[nxt], ND, 128,
               b_[3] + l * H, nullptr, nullptr};
    g3.j[2] = {yc, Wtc + (size_t)l * 128 * 128, xcb[nxt], NCN, 128,
               b_[4] + l * H, nullptr, nullptr};
    k_gemm_g3<<<dim3((NPN + 127) / 128, 3), 256, 0, stream>>>(g3);
    cur = nxt;
  }

  // head: inv-norms -> scaled slice GEMMs (bf16 P tables, b1/3 baked) -> fused gather+W2+W3
  k_invnorm<<<(ND + NCN + 3) / 4, 256, 0, stream>>>(xdb[cur], xcb[cur], invd, invc);
  GemmPS ps;
  ps.Bt = W1t; ps.b1t = b1t;
  ps.j[0] = {xdb[cur], P1a, ND, invd};
  ps.j[1] = {xdb[cur], P1b, ND, invd};
  ps.j[2] = {xcb[cur], P1c, NCN, invc};
  k_gemm_ps<<<dim3(32 * 6, 3), 256, 0, stream>>>(ps);
  k_w2head<<<(NB + 127) / 128, 256, 0, stream>>>(
      P1a, P1b, P1c, drug1, drug2, cellb, W2t, b2, W3, b3, out, NB);
}